// Round 10
// baseline (225.885 us; speedup 1.0000x reference)
//
#include <hip/hip_runtime.h>
#include <math.h>

#define HEADS 4
#define NEG_SLOPE 0.2f

// ---------------- workspace layout (bytes) ----------------
static constexpr size_t OFF_H1B  = 0;
static constexpr size_t OFF_H2B  = 0;
static constexpr size_t OFF_OUT2 = 6400000;
static constexpr size_t OFF_XHI  = 25600000;
static constexpr size_t OFF_XLO  = 38400000;
static constexpr size_t OFF_O1HI = 25600000;   // aliases xhi/xlo (dead by then)
static constexpr size_t OFF_O1LO = 51200000;
static constexpr size_t OFF_W1TH = 76800000;   // 256x128 bf16 = 64KB
static constexpr size_t OFF_W1TL = 76865536;
static constexpr size_t OFF_W2TH = 76931072;   // 64x256 bf16 = 32KB
static constexpr size_t OFF_W2TL = 76963840;
static constexpr size_t OFF_AS   = 77000000;   // 800,000
static constexpr size_t OFF_AD   = 77800000;   // 800,000
static constexpr size_t OFF_RP   = 78600064;   // (2N+1) ints
static constexpr size_t OFF_CUR  = 79000128;
static constexpr size_t OFF_CNT  = 79400128;
static constexpr size_t OFF_CSR  = 79800128;   // 2E ints
static constexpr size_t OFF_STRT = 83000128;
static constexpr size_t OFF_BSUM = 83000448;
static constexpr size_t OFF_BOFF = 83001472;

typedef __attribute__((ext_vector_type(8))) short short8;
typedef __attribute__((ext_vector_type(4))) float f32x4;

// ---------------- helpers ----------------
__device__ __forceinline__ float4 f4add(float4 a, float4 b) {
    return make_float4(a.x + b.x, a.y + b.y, a.z + b.z, a.w + b.w);
}
__device__ __forceinline__ float lrelu(float x) { return x > 0.f ? x : NEG_SLOPE * x; }
__device__ __forceinline__ float4 f4lrelu(float4 a) {
    return make_float4(lrelu(a.x), lrelu(a.y), lrelu(a.z), lrelu(a.w));
}
__device__ __forceinline__ float4 f4exp(float4 a) {
    return make_float4(__expf(a.x), __expf(a.y), __expf(a.z), __expf(a.w));
}
__device__ __forceinline__ float pickh(float4 v, int head) {
    float r = v.x;
    r = head == 1 ? v.y : r;
    r = head == 2 ? v.z : r;
    r = head == 3 ? v.w : r;
    return r;
}
__device__ __forceinline__ unsigned short bfr(float x) {
    union { float f; unsigned u; } c; c.f = x;
    unsigned r = c.u + 0x7FFFu + ((c.u >> 16) & 1u);
    return (unsigned short)(r >> 16);
}
__device__ __forceinline__ float bf2f(unsigned short h) {
    union { unsigned u; float f; } c; c.u = ((unsigned)h) << 16;
    return c.f;
}
__device__ __forceinline__ float2 bfpair(unsigned u) {
    union { unsigned a; float f; } lo, hi;
    lo.a = u << 16;
    hi.a = u & 0xffff0000u;
    return make_float2(lo.f, hi.f);
}

// ---------------- split kernels ----------------
__global__ void split_kernel(const float* __restrict__ in, unsigned short* __restrict__ hi,
                             unsigned short* __restrict__ lo, int n4)
{
    int i = blockIdx.x * 256 + threadIdx.x;
    const int stride = gridDim.x * 256;
    for (; i < n4; i += stride) {
        float4 v = ((const float4*)in)[i];
        unsigned short h0 = bfr(v.x), h1 = bfr(v.y), h2 = bfr(v.z), h3 = bfr(v.w);
        unsigned short l0 = bfr(v.x - bf2f(h0)), l1 = bfr(v.y - bf2f(h1));
        unsigned short l2 = bfr(v.z - bf2f(h2)), l3 = bfr(v.w - bf2f(h3));
        ((uint2*)hi)[i] = make_uint2((unsigned)h0 | ((unsigned)h1 << 16),
                                     (unsigned)h2 | ((unsigned)h3 << 16));
        ((uint2*)lo)[i] = make_uint2((unsigned)l0 | ((unsigned)l1 << 16),
                                     (unsigned)l2 | ((unsigned)l3 << 16));
    }
}

__global__ void wsplit_kernel(const float* __restrict__ W, unsigned short* __restrict__ hiT,
                              unsigned short* __restrict__ loT, int K, int N)
{
    int idx = blockIdx.x * 256 + threadIdx.x;
    if (idx >= K * N) return;
    int k = idx / N, n = idx - k * N;
    float v = W[idx];
    unsigned short h = bfr(v);
    hiT[(size_t)n * K + k] = h;
    loT[(size_t)n * K + k] = bfr(v - bf2f(h));
}

// ---------------- MFMA GEMM with GAT-alpha epilogue ----------------
template<int BM, int BN, int KDIM, int WR, int WC, int CPH>
__global__ __launch_bounds__(256, 2)
void mfma_gemm_gat(const unsigned short* __restrict__ Ahi, const unsigned short* __restrict__ Alo,
                   const unsigned short* __restrict__ BThi, const unsigned short* __restrict__ BTlo,
                   unsigned short* __restrict__ Cb,
                   const float* __restrict__ avec_s, const float* __restrict__ avec_d,
                   float* __restrict__ alpha_s, float* __restrict__ alpha_d,
                   int M, int N)
{
    constexpr int BK    = 32;
    constexpr int WROWS = BM / WR;
    constexpr int WCOLS = BN / WC;
    constexpr int FR    = WROWS / 16;
    constexpr int FC    = WCOLS / 16;
    constexpr int AP    = (BM * (BK / 8)) / 256;
    constexpr int BP    = (BN * (BK / 8)) / 256;
    static_assert(AP >= 1 && BP >= 1, "tile too small");

    __shared__ short As_hi[BM * BK], As_lo[BM * BK];
    __shared__ short Bs_hi[BN * BK], Bs_lo[BN * BK];

    const int tid  = threadIdx.x;
    const int w    = tid >> 6, lane = tid & 63;
    const int wr   = w / WC, wc = w % WC;
    const int lrow = lane & 15, lk = lane >> 4;
    const int m0   = blockIdx.x * BM, n0 = blockIdx.y * BN;

    f32x4 acc[FR][FC];
#pragma unroll
    for (int i = 0; i < FR; ++i)
#pragma unroll
        for (int j = 0; j < FC; ++j) acc[i][j] = (f32x4){0.f, 0.f, 0.f, 0.f};

    short8 rAh[AP], rAl[AP], rBh[BP], rBl[BP];

    auto LOAD = [&](int kb) {
#pragma unroll
        for (int p = 0; p < AP; ++p) {
            int id = p * 256 + tid;
            int r = id >> 2, c = id & 3;
            int row = m0 + r; row = row < M ? row : M - 1;
            size_t off = (size_t)row * KDIM + kb + c * 8;
            rAh[p] = *(const short8*)(Ahi + off);
            rAl[p] = *(const short8*)(Alo + off);
        }
#pragma unroll
        for (int p = 0; p < BP; ++p) {
            int id = p * 256 + tid;
            int r = id >> 2, c = id & 3;
            size_t off = (size_t)(n0 + r) * KDIM + kb + c * 8;
            rBh[p] = *(const short8*)(BThi + off);
            rBl[p] = *(const short8*)(BTlo + off);
        }
    };
    auto STORE = [&]() {
#pragma unroll
        for (int p = 0; p < AP; ++p) {
            int id = p * 256 + tid;
            int r = id >> 2, c = id & 3;
            *(short8*)(&As_hi[r * BK + c * 8]) = rAh[p];
            *(short8*)(&As_lo[r * BK + c * 8]) = rAl[p];
        }
#pragma unroll
        for (int p = 0; p < BP; ++p) {
            int id = p * 256 + tid;
            int r = id >> 2, c = id & 3;
            *(short8*)(&Bs_hi[r * BK + c * 8]) = rBh[p];
            *(short8*)(&Bs_lo[r * BK + c * 8]) = rBl[p];
        }
    };

    constexpr int NT = KDIM / BK;
    LOAD(0);
    for (int t = 0; t < NT; ++t) {
        STORE();
        __syncthreads();
        if (t + 1 < NT) LOAD((t + 1) * BK);

        short8 afh[FR], afl[FR], bfh[FC], bfl[FC];
#pragma unroll
        for (int fr = 0; fr < FR; ++fr) {
            int r = wr * WROWS + fr * 16 + lrow;
            afh[fr] = *(const short8*)(&As_hi[r * BK + lk * 8]);
            afl[fr] = *(const short8*)(&As_lo[r * BK + lk * 8]);
        }
#pragma unroll
        for (int fc = 0; fc < FC; ++fc) {
            int r = wc * WCOLS + fc * 16 + lrow;
            bfh[fc] = *(const short8*)(&Bs_hi[r * BK + lk * 8]);
            bfl[fc] = *(const short8*)(&Bs_lo[r * BK + lk * 8]);
        }
#pragma unroll
        for (int fr = 0; fr < FR; ++fr)
#pragma unroll
            for (int fc = 0; fc < FC; ++fc) {
                acc[fr][fc] = __builtin_amdgcn_mfma_f32_16x16x32_bf16(afh[fr], bfh[fc], acc[fr][fc], 0, 0, 0);
                acc[fr][fc] = __builtin_amdgcn_mfma_f32_16x16x32_bf16(afh[fr], bfl[fc], acc[fr][fc], 0, 0, 0);
                acc[fr][fc] = __builtin_amdgcn_mfma_f32_16x16x32_bf16(afl[fr], bfh[fc], acc[fr][fc], 0, 0, 0);
            }
        __syncthreads();
    }

#pragma unroll
    for (int fr = 0; fr < FR; ++fr) {
        const int rbase = m0 + wr * WROWS + fr * 16 + lk * 4;
        float ps[4] = {0.f, 0.f, 0.f, 0.f}, pd[4] = {0.f, 0.f, 0.f, 0.f};
#pragma unroll
        for (int fc = 0; fc < FC; ++fc) {
            const int gc   = n0 + wc * WCOLS + fc * 16 + lrow;
            const int head = gc / CPH, ci = gc % CPH;
            const float asv = avec_s[head * CPH + ci];
            const float adv = avec_d[head * CPH + ci];
#pragma unroll
            for (int rg = 0; rg < 4; ++rg) {
                int row = rbase + rg;
                float v = acc[fr][fc][rg];
                if (row < M) Cb[(size_t)row * N + gc] = bfr(v);
                ps[rg] += v * asv;
                pd[rg] += v * adv;
            }
            if constexpr (CPH == 16) {
#pragma unroll
                for (int rg = 0; rg < 4; ++rg) {
                    float s = ps[rg], d = pd[rg];
#pragma unroll
                    for (int m = 1; m <= 8; m <<= 1) {
                        s += __shfl_xor(s, m);
                        d += __shfl_xor(d, m);
                    }
                    if (lrow == 0 && rbase + rg < M) {
                        alpha_s[(size_t)(rbase + rg) * HEADS + head] = s;
                        alpha_d[(size_t)(rbase + rg) * HEADS + head] = d;
                    }
                    ps[rg] = 0.f; pd[rg] = 0.f;
                }
            }
        }
        if constexpr (CPH != 16) {
            const int head = (n0 + wc * WCOLS) / CPH;
#pragma unroll
            for (int rg = 0; rg < 4; ++rg) {
                float s = ps[rg], d = pd[rg];
#pragma unroll
                for (int m = 1; m <= 8; m <<= 1) {
                    s += __shfl_xor(s, m);
                    d += __shfl_xor(d, m);
                }
                if (lrow == 0 && rbase + rg < M) {
                    alpha_s[(size_t)(rbase + rg) * HEADS + head] = s;
                    alpha_d[(size_t)(rbase + rg) * HEADS + head] = d;
                }
            }
        }
    }
}

// ---------------- fused 2-layer CSR build (8 edges/thread for MLP) ----------------
__global__ void count2_kernel(const int* __restrict__ dst1, const int* __restrict__ dst2,
                              int* __restrict__ counts, int N, int E)
{
    const int base = blockIdx.x * 2048 + threadIdx.x;
#pragma unroll
    for (int k = 0; k < 8; ++k) {
        int e = base + k * 256;
        if (e < E)          atomicAdd(&counts[dst1[e]], 1);
        else if (e < 2 * E) atomicAdd(&counts[N + dst2[e - E]], 1);
    }
}

// phase-split: 8 independent (load,atomic) chains in flight, then 8 stores
__global__ void scatter2_kernel(const int* __restrict__ src1, const int* __restrict__ dst1,
                                const int* __restrict__ src2, const int* __restrict__ dst2,
                                int* __restrict__ cursor, int* __restrict__ csr, int N, int E)
{
    const int base = blockIdx.x * 2048 + threadIdx.x;
    int srcv[8], pos[8];
    bool valid[8];
#pragma unroll
    for (int k = 0; k < 8; ++k) {
        int e = base + k * 256;
        valid[k] = (e < 2 * E);
        srcv[k] = 0; pos[k] = 0;
        if (e < E) {
            srcv[k] = src1[e];
            pos[k]  = atomicAdd(&cursor[dst1[e]], 1);
        } else if (e < 2 * E) {
            srcv[k] = src2[e - E];
            pos[k]  = atomicAdd(&cursor[N + dst2[e - E]], 1);
        }
    }
#pragma unroll
    for (int k = 0; k < 8; ++k)
        if (valid[k]) csr[pos[k]] = srcv[k];
}

// ---------------- parallel scan (3 kernels) ----------------
__global__ __launch_bounds__(1024)
void scan_block_kernel(const int* __restrict__ counts, int* __restrict__ excl_out,
                       int* __restrict__ bsum, int n)
{
    __shared__ int wsum[16];
    const int t = threadIdx.x, lane = t & 63, w = t >> 6;
    const int i = blockIdx.x * 1024 + t;
    int v = (i < n) ? counts[i] : 0;
    int x = v;
#pragma unroll
    for (int d = 1; d < 64; d <<= 1) {
        int y = __shfl_up(x, d);
        if (lane >= d) x += y;
    }
    if (lane == 63) wsum[w] = x;
    __syncthreads();
    if (t < 16) {
        int s = wsum[t];
#pragma unroll
        for (int d = 1; d < 16; d <<= 1) {
            int y = __shfl_up(s, d);
            if (t >= d) s += y;
        }
        wsum[t] = s;
    }
    __syncthreads();
    int wbase = (w > 0) ? wsum[w - 1] : 0;
    if (i < n) excl_out[i] = wbase + x - v;
    if (t == 1023) bsum[blockIdx.x] = wsum[15];
}

__global__ __launch_bounds__(256)
void scan_tops_kernel(const int* __restrict__ bsum, int* __restrict__ boff,
                      int* __restrict__ row_ptr, int nb, int ntot)
{
    __shared__ int wtot[4];
    const int t = threadIdx.x, lane = t & 63, w = t >> 6;
    int v = (t < nb) ? bsum[t] : 0;
    int x = v;
#pragma unroll
    for (int d = 1; d < 64; d <<= 1) {
        int y = __shfl_up(x, d);
        if (lane >= d) x += y;
    }
    if (lane == 63) wtot[w] = x;
    __syncthreads();
    int wbase = 0;
    for (int k = 0; k < w; ++k) wbase += wtot[k];
    if (t < nb) boff[t] = wbase + x - v;
    if (t == 255) row_ptr[ntot] = wbase + x;
}

__global__ __launch_bounds__(1024)
void scan_add_kernel(const int* __restrict__ boff, int* __restrict__ row_ptr,
                     int* __restrict__ cursor, int n)
{
    const int i = blockIdx.x * 1024 + threadIdx.x;
    if (i < n) {
        int r = row_ptr[i] + boff[blockIdx.x];
        row_ptr[i] = r;
        cursor[i]  = r;
    }
}

// ---------------- GAT softmax + aggregation ----------------
// S lanes per node (subgroup); 8-deep unrolled gather with zero-weight padding.
template<int CH, int S>
__global__ __launch_bounds__(256)
void gat_agg(const unsigned short* __restrict__ hb, const float* __restrict__ alpha_s,
             const float* __restrict__ alpha_d, const int* __restrict__ row_ptr,
             const int* __restrict__ csr_src, const float* __restrict__ bias,
             float* __restrict__ out, unsigned short* __restrict__ out_hi,
             unsigned short* __restrict__ out_lo, int n)
{
    constexpr int CPL = CH / S;
    constexpr int NSG = 256 / S;
    __shared__ float wls[NSG][S * 5];
    const int tid    = threadIdx.x;
    const int sub    = tid / S;
    const int i      = tid % S;
    const int lane64 = tid & 63;
    const int base   = lane64 & ~(S - 1);
    const int node   = blockIdx.x * NSG + sub;
    if (node >= n) return;
    const int head = (i * CPL) / (CH / 4);
    const int p0 = row_ptr[node], p1 = row_ptr[node + 1];
    const int deg = p1 - p0;

    const float4 asn = *(const float4*)(alpha_s + (size_t)node * 4);
    const float4 adn = *(const float4*)(alpha_d + (size_t)node * 4);
    float4 den = f4exp(f4lrelu(f4add(asn, adn)));
    const float wse = pickh(den, head);

    float acc[CPL];
    if constexpr (CPL == 8) {
        uint4 hv = *(const uint4*)(hb + (size_t)node * CH + i * 8);
        float2 q0 = bfpair(hv.x), q1 = bfpair(hv.y), q2 = bfpair(hv.z), q3 = bfpair(hv.w);
        acc[0] = wse * q0.x; acc[1] = wse * q0.y; acc[2] = wse * q1.x; acc[3] = wse * q1.y;
        acc[4] = wse * q2.x; acc[5] = wse * q2.y; acc[6] = wse * q3.x; acc[7] = wse * q3.y;
    } else {
        uint2 hv = *(const uint2*)(hb + (size_t)node * CH + i * 4);
        float2 q0 = bfpair(hv.x), q1 = bfpair(hv.y);
        acc[0] = wse * q0.x; acc[1] = wse * q0.y; acc[2] = wse * q1.x; acc[3] = wse * q1.y;
    }

    for (int ch = 0; ch < deg; ch += S) {
        const int cnt = min(S, deg - ch);
        float4 w4 = make_float4(0.f, 0.f, 0.f, 0.f);
        int sl = 0;
        if (i < cnt) {
            sl = csr_src[p0 + ch + i];
            float4 al = *(const float4*)(alpha_s + (size_t)sl * 4);
            w4 = f4exp(f4lrelu(f4add(al, adn)));
        }
        float4 t = w4;
#pragma unroll
        for (int d = S / 2; d >= 1; d >>= 1) {
            t.x += __shfl_xor(t.x, d);
            t.y += __shfl_xor(t.y, d);
            t.z += __shfl_xor(t.z, d);
            t.w += __shfl_xor(t.w, d);
        }
        den = f4add(den, t);
        wls[sub][i * 5 + 0] = w4.x;
        wls[sub][i * 5 + 1] = w4.y;
        wls[sub][i * 5 + 2] = w4.z;
        wls[sub][i * 5 + 3] = w4.w;

        const int padded = (cnt + 7) & ~7;
        for (int j = 0; j < padded; j += 8) {
            int   sk[8];
            float wk[8];
#pragma unroll
            for (int k = 0; k < 8; ++k) {
                sk[k] = __shfl(sl, base + j + k);
                wk[k] = wls[sub][(j + k) * 5 + head];
            }
            if constexpr (CPL == 8) {
                uint4 v[8];
#pragma unroll
                for (int k = 0; k < 8; ++k)
                    v[k] = *(const uint4*)(hb + (size_t)sk[k] * CH + i * 8);
#pragma unroll
                for (int k = 0; k < 8; ++k) {
                    float2 q0 = bfpair(v[k].x), q1 = bfpair(v[k].y);
                    float2 q2 = bfpair(v[k].z), q3 = bfpair(v[k].w);
                    acc[0] += wk[k] * q0.x; acc[1] += wk[k] * q0.y;
                    acc[2] += wk[k] * q1.x; acc[3] += wk[k] * q1.y;
                    acc[4] += wk[k] * q2.x; acc[5] += wk[k] * q2.y;
                    acc[6] += wk[k] * q3.x; acc[7] += wk[k] * q3.y;
                }
            } else {
                uint2 v[8];
#pragma unroll
                for (int k = 0; k < 8; ++k)
                    v[k] = *(const uint2*)(hb + (size_t)sk[k] * CH + i * 4);
#pragma unroll
                for (int k = 0; k < 8; ++k) {
                    float2 q0 = bfpair(v[k].x), q1 = bfpair(v[k].y);
                    acc[0] += wk[k] * q0.x; acc[1] += wk[k] * q0.y;
                    acc[2] += wk[k] * q1.x; acc[3] += wk[k] * q1.y;
                }
            }
        }
    }

    const float invd = 1.0f / (pickh(den, head) + 1e-16f);
    const int c0 = i * CPL;
    if constexpr (CPL == 8) {
        float o[8];
        unsigned short oh[8], ol[8];
#pragma unroll
        for (int k = 0; k < 8; ++k) {
            o[k] = fmaxf(acc[k] * invd + bias[c0 + k], 0.f);
            oh[k] = bfr(o[k]);
            ol[k] = bfr(o[k] - bf2f(oh[k]));
        }
        uint4 ph, pl;
        ph.x = (unsigned)oh[0] | ((unsigned)oh[1] << 16);
        ph.y = (unsigned)oh[2] | ((unsigned)oh[3] << 16);
        ph.z = (unsigned)oh[4] | ((unsigned)oh[5] << 16);
        ph.w = (unsigned)oh[6] | ((unsigned)oh[7] << 16);
        pl.x = (unsigned)ol[0] | ((unsigned)ol[1] << 16);
        pl.y = (unsigned)ol[2] | ((unsigned)ol[3] << 16);
        pl.z = (unsigned)ol[4] | ((unsigned)ol[5] << 16);
        pl.w = (unsigned)ol[6] | ((unsigned)ol[7] << 16);
        *(uint4*)(out_hi + (size_t)node * CH + c0) = ph;
        *(uint4*)(out_lo + (size_t)node * CH + c0) = pl;
    } else {
        float4 o;
        o.x = fmaxf(acc[0] * invd + bias[c0 + 0], 0.f);
        o.y = fmaxf(acc[1] * invd + bias[c0 + 1], 0.f);
        o.z = fmaxf(acc[2] * invd + bias[c0 + 2], 0.f);
        o.w = fmaxf(acc[3] * invd + bias[c0 + 3], 0.f);
        *(float4*)(out + (size_t)node * CH + c0) = o;
    }
}

// ---------------- graph boundaries + fused mean-pool/FC ----------------
__global__ void graph_starts_kernel(const int* __restrict__ batch, int* __restrict__ starts,
                                    int n, int ngraphs)
{
    int g = threadIdx.x;
    if (g > ngraphs) return;
    int lo = 0, hi = n;
    while (lo < hi) {
        int mid = (lo + hi) >> 1;
        if (batch[mid] < g) lo = mid + 1; else hi = mid;
    }
    starts[g] = lo;
}

__global__ __launch_bounds__(256)
void pool_fc_kernel(const float* __restrict__ feat, const int* __restrict__ starts,
                    const float* __restrict__ Wfc, const float* __restrict__ bfc,
                    float* __restrict__ out)
{
    __shared__ float4 part[16][16];
    __shared__ float pooled[64];
    const int g = blockIdx.x;
    const int t = threadIdx.x;
    const int q = t & 15, ns = t >> 4;
    const int s0 = starts[g], s1 = starts[g + 1];
    float4 acc = make_float4(0.f, 0.f, 0.f, 0.f);
    for (int i = s0 + ns; i < s1; i += 16)
        acc = f4add(acc, *(const float4*)(feat + (size_t)i * 64 + q * 4));
    part[ns][q] = acc;
    __syncthreads();
    if (t < 16) {
        float4 s = part[0][t];
#pragma unroll
        for (int k = 1; k < 16; ++k) s = f4add(s, part[k][t]);
        float inv = 1.0f / fmaxf((float)(s1 - s0), 1.0f);
        pooled[t * 4 + 0] = s.x * inv;
        pooled[t * 4 + 1] = s.y * inv;
        pooled[t * 4 + 2] = s.z * inv;
        pooled[t * 4 + 3] = s.w * inv;
    }
    __syncthreads();
    if (t < 2) {
        float a = bfc[t];
        for (int c = 0; c < 64; ++c) a += pooled[c] * Wfc[c * 2 + t];
        out[g * 2 + t] = a;
    }
}

// ---------------- launch ----------------
extern "C" void kernel_launch(void* const* d_in, const int* in_sizes, int n_in,
                              void* d_out, int out_size, void* d_ws, size_t ws_size,
                              hipStream_t stream)
{
    const float* x    = (const float*)d_in[0];
    const int*   ei   = (const int*)d_in[1];
    const int*   batch= (const int*)d_in[2];
    const float* W1   = (const float*)d_in[3];
    const float* as1  = (const float*)d_in[4];
    const float* ad1  = (const float*)d_in[5];
    const float* b1   = (const float*)d_in[6];
    const float* W2   = (const float*)d_in[7];
    const float* as2  = (const float*)d_in[8];
    const float* ad2  = (const float*)d_in[9];
    const float* b2   = (const float*)d_in[10];
    const float* Wfc  = (const float*)d_in[11];
    const float* bfc  = (const float*)d_in[12];
    float* out = (float*)d_out;

    const int N = in_sizes[2];          // 50000 nodes
    const int E = in_sizes[1] / 27;     // 400000 edges
    const int F = in_sizes[0] / N;      // 128

    char* ws = (char*)d_ws;
    unsigned short* h1b   = (unsigned short*)(ws + OFF_H1B);
    unsigned short* h2b   = (unsigned short*)(ws + OFF_H2B);
    float*          out2  = (float*)(ws + OFF_OUT2);
    unsigned short* xhi   = (unsigned short*)(ws + OFF_XHI);
    unsigned short* xlo   = (unsigned short*)(ws + OFF_XLO);
    unsigned short* o1hi  = (unsigned short*)(ws + OFF_O1HI);
    unsigned short* o1lo  = (unsigned short*)(ws + OFF_O1LO);
    unsigned short* w1th  = (unsigned short*)(ws + OFF_W1TH);
    unsigned short* w1tl  = (unsigned short*)(ws + OFF_W1TL);
    unsigned short* w2th  = (unsigned short*)(ws + OFF_W2TH);
    unsigned short* w2tl  = (unsigned short*)(ws + OFF_W2TL);
    float* al_s  = (float*)(ws + OFF_AS);
    float* al_d  = (float*)(ws + OFF_AD);
    int*   rp    = (int*)(ws + OFF_RP);     // (2N+1) entries; layer2 view = rp+N
    int*   cur   = (int*)(ws + OFF_CUR);    // 2N
    int*   cnt   = (int*)(ws + OFF_CNT);    // 2N
    int*   csr   = (int*)(ws + OFF_CSR);    // 2E (global positions)
    int*   strt  = (int*)(ws + OFF_STRT);
    int*   bsum  = (int*)(ws + OFF_BSUM);
    int*   boff  = (int*)(ws + OFF_BOFF);

    const int e2grid8 = (2 * E + 2047) / 2048;   // 8 edges/thread
    const int NB2     = (2 * N + 1023) / 1024;   // 98 blocks

    // ---- splits ----
    split_kernel<<<2048, 256, 0, stream>>>(x, xhi, xlo, N * F / 4);
    wsplit_kernel<<<(F * HEADS * 64 + 255) / 256, 256, 0, stream>>>(W1, w1th, w1tl, F, HEADS * 64);
    wsplit_kernel<<<(HEADS * 64 * HEADS * 16 + 255) / 256, 256, 0, stream>>>(W2, w2th, w2tl, HEADS * 64, HEADS * 16);

    // ---- fused CSR build for both layers ----
    hipMemsetAsync(cnt, 0, (size_t)2 * N * sizeof(int), stream);
    count2_kernel<<<e2grid8, 256, 0, stream>>>(ei + 26 * (size_t)E, ei + 16 * (size_t)E, cnt, N, E);
    scan_block_kernel<<<NB2, 1024, 0, stream>>>(cnt, rp, bsum, 2 * N);
    scan_tops_kernel<<<1, 256, 0, stream>>>(bsum, boff, rp, NB2, 2 * N);
    scan_add_kernel<<<NB2, 1024, 0, stream>>>(boff, rp, cur, 2 * N);
    scatter2_kernel<<<e2grid8, 256, 0, stream>>>(ei + 17 * (size_t)E, ei + 26 * (size_t)E,
                                                 ei + 15 * (size_t)E, ei + 16 * (size_t)E,
                                                 cur, csr, N, E);

    // ---- layer 1: MFMA GEMM (M=50000, K=128, Ncols=256) -> bf16 h1 ----
    {
        dim3 g((N + 127) / 128, 2);
        mfma_gemm_gat<128, 128, 128, 2, 2, 64><<<g, 256, 0, stream>>>(
            xhi, xlo, w1th, w1tl, h1b, as1, ad1, al_s, al_d, N, HEADS * 64);
    }
    gat_agg<256, 32><<<(N + 7) / 8, 256, 0, stream>>>(h1b, al_s, al_d, rp, csr, b1,
                                                      nullptr, o1hi, o1lo, N);

    // ---- layer 2: MFMA GEMM (M=50000, K=256, Ncols=64) -> bf16 h2 ----
    {
        dim3 g((N + 63) / 64, 1);
        mfma_gemm_gat<64, 64, 256, 2, 2, 16><<<g, 256, 0, stream>>>(
            o1hi, o1lo, w2th, w2tl, h2b, as2, ad2, al_s, al_d, N, HEADS * 16);
    }
    gat_agg<64, 16><<<(N + 15) / 16, 256, 0, stream>>>(h2b, al_s, al_d, rp + N, csr, b2,
                                                       out2, nullptr, nullptr, N);

    // ---- pool + fc ----
    graph_starts_kernel<<<1, 65, 0, stream>>>(batch, strt, N, 64);
    pool_fc_kernel<<<64, 256, 0, stream>>>(out2, strt, Wfc, bfc, out);
}

// Round 12
// 217.179 us; speedup vs baseline: 1.0401x; 1.0401x over previous
//
#include <hip/hip_runtime.h>
#include <math.h>

#define HEADS 4
#define NEG_SLOPE 0.2f

// ---------------- workspace layout (bytes) ----------------
static constexpr size_t OFF_H1B  = 0;
static constexpr size_t OFF_H2B  = 0;
static constexpr size_t OFF_OUT2 = 6400000;
static constexpr size_t OFF_XHI  = 25600000;
static constexpr size_t OFF_XLO  = 38400000;
static constexpr size_t OFF_O1HI = 25600000;   // aliases xhi/xlo (dead by then)
static constexpr size_t OFF_O1LO = 51200000;
static constexpr size_t OFF_W1TH = 76800000;   // 256x128 bf16 = 64KB
static constexpr size_t OFF_W1TL = 76865536;
static constexpr size_t OFF_W2TH = 76931072;   // 64x256 bf16 = 32KB
static constexpr size_t OFF_W2TL = 76963840;
static constexpr size_t OFF_AS   = 77000000;   // 800,000
static constexpr size_t OFF_AD   = 77800000;   // 800,000
static constexpr size_t OFF_RP   = 78600064;   // (2N+1) ints
static constexpr size_t OFF_CUR  = 79000128;
static constexpr size_t OFF_CNT  = 79400128;
static constexpr size_t OFF_CSR  = 79800128;   // 2E ints
static constexpr size_t OFF_BSUM = 83000448;
static constexpr size_t OFF_BOFF = 83001472;

typedef __attribute__((ext_vector_type(8))) short short8;
typedef __attribute__((ext_vector_type(4))) float f32x4;

// ---------------- helpers ----------------
__device__ __forceinline__ float4 f4add(float4 a, float4 b) {
    return make_float4(a.x + b.x, a.y + b.y, a.z + b.z, a.w + b.w);
}
__device__ __forceinline__ float lrelu(float x) { return x > 0.f ? x : NEG_SLOPE * x; }
__device__ __forceinline__ float4 f4lrelu(float4 a) {
    return make_float4(lrelu(a.x), lrelu(a.y), lrelu(a.z), lrelu(a.w));
}
__device__ __forceinline__ float4 f4exp(float4 a) {
    return make_float4(__expf(a.x), __expf(a.y), __expf(a.z), __expf(a.w));
}
__device__ __forceinline__ float pickh(float4 v, int head) {
    float r = v.x;
    r = head == 1 ? v.y : r;
    r = head == 2 ? v.z : r;
    r = head == 3 ? v.w : r;
    return r;
}
__device__ __forceinline__ unsigned short bfr(float x) {
    union { float f; unsigned u; } c; c.f = x;
    unsigned r = c.u + 0x7FFFu + ((c.u >> 16) & 1u);
    return (unsigned short)(r >> 16);
}
__device__ __forceinline__ float bf2f(unsigned short h) {
    union { unsigned u; float f; } c; c.u = ((unsigned)h) << 16;
    return c.f;
}
__device__ __forceinline__ float2 bfpair(unsigned u) {
    union { unsigned a; float f; } lo, hi;
    lo.a = u << 16;
    hi.a = u & 0xffff0000u;
    return make_float2(lo.f, hi.f);
}

// ---------------- fused prep: x-split + W1T/W2T-split + cnt zero ----------------
// blocks [0,1024): split x; [1024,1152): W1; [1152,1216): W2; [1216,1216+98): zero cnt
__global__ void prep_kernel(const float* __restrict__ x, unsigned short* __restrict__ xhi,
                            unsigned short* __restrict__ xlo, int n4,
                            const float* __restrict__ W1, unsigned short* __restrict__ w1th,
                            unsigned short* __restrict__ w1tl,
                            const float* __restrict__ W2, unsigned short* __restrict__ w2th,
                            unsigned short* __restrict__ w2tl,
                            int* __restrict__ cnt, int n2)
{
    const int b = blockIdx.x, t = threadIdx.x;
    if (b < 1024) {
        for (int i = b * 256 + t; i < n4; i += 1024 * 256) {
            float4 v = ((const float4*)x)[i];
            unsigned short h0 = bfr(v.x), h1 = bfr(v.y), h2 = bfr(v.z), h3 = bfr(v.w);
            unsigned short l0 = bfr(v.x - bf2f(h0)), l1 = bfr(v.y - bf2f(h1));
            unsigned short l2 = bfr(v.z - bf2f(h2)), l3 = bfr(v.w - bf2f(h3));
            ((uint2*)xhi)[i] = make_uint2((unsigned)h0 | ((unsigned)h1 << 16),
                                          (unsigned)h2 | ((unsigned)h3 << 16));
            ((uint2*)xlo)[i] = make_uint2((unsigned)l0 | ((unsigned)l1 << 16),
                                          (unsigned)l2 | ((unsigned)l3 << 16));
        }
    } else if (b < 1024 + 128) {
        int idx = (b - 1024) * 256 + t;          // W1: K=128, N=256 -> 32768 elems
        const int K = 128, Nc = 256;
        int k = idx / Nc, n = idx - k * Nc;
        float v = W1[idx];
        unsigned short h = bfr(v);
        w1th[(size_t)n * K + k] = h;
        w1tl[(size_t)n * K + k] = bfr(v - bf2f(h));
    } else if (b < 1024 + 128 + 64) {
        int idx = (b - 1152) * 256 + t;          // W2: K=256, N=64 -> 16384 elems
        const int K = 256, Nc = 64;
        int k = idx / Nc, n = idx - k * Nc;
        float v = W2[idx];
        unsigned short h = bfr(v);
        w2th[(size_t)n * K + k] = h;
        w2tl[(size_t)n * K + k] = bfr(v - bf2f(h));
    } else {
        int idx = (b - 1216) * 256 + t;          // zero cnt[2N] via int4
        if (idx < (n2 >> 2)) ((int4*)cnt)[idx] = make_int4(0, 0, 0, 0);
    }
}

// ---------------- fused 2-layer CSR build (8 edges/thread for MLP) ----------------
__global__ void count2_kernel(const int* __restrict__ dst1, const int* __restrict__ dst2,
                              int* __restrict__ counts, int N, int E)
{
    const int base = blockIdx.x * 2048 + threadIdx.x;
#pragma unroll
    for (int k = 0; k < 8; ++k) {
        int e = base + k * 256;
        if (e < E)          atomicAdd(&counts[dst1[e]], 1);
        else if (e < 2 * E) atomicAdd(&counts[N + dst2[e - E]], 1);
    }
}

__global__ void scatter2_kernel(const int* __restrict__ src1, const int* __restrict__ dst1,
                                const int* __restrict__ src2, const int* __restrict__ dst2,
                                int* __restrict__ cursor, int* __restrict__ csr, int N, int E)
{
    const int base = blockIdx.x * 2048 + threadIdx.x;
    int srcv[8], pos[8];
    bool valid[8];
#pragma unroll
    for (int k = 0; k < 8; ++k) {
        int e = base + k * 256;
        valid[k] = (e < 2 * E);
        srcv[k] = 0; pos[k] = 0;
        if (e < E) {
            srcv[k] = src1[e];
            pos[k]  = atomicAdd(&cursor[dst1[e]], 1);
        } else if (e < 2 * E) {
            srcv[k] = src2[e - E];
            pos[k]  = atomicAdd(&cursor[N + dst2[e - E]], 1);
        }
    }
#pragma unroll
    for (int k = 0; k < 8; ++k)
        if (valid[k]) csr[pos[k]] = srcv[k];
}

// ---------------- parallel scan (2 kernels) ----------------
__global__ __launch_bounds__(1024)
void scan_block_kernel(const int* __restrict__ counts, int* __restrict__ excl_out,
                       int* __restrict__ bsum, int n)
{
    __shared__ int wsum[16];
    const int t = threadIdx.x, lane = t & 63, w = t >> 6;
    const int i = blockIdx.x * 1024 + t;
    int v = (i < n) ? counts[i] : 0;
    int x = v;
#pragma unroll
    for (int d = 1; d < 64; d <<= 1) {
        int y = __shfl_up(x, d);
        if (lane >= d) x += y;
    }
    if (lane == 63) wsum[w] = x;
    __syncthreads();
    if (t < 16) {
        int s = wsum[t];
#pragma unroll
        for (int d = 1; d < 16; d <<= 1) {
            int y = __shfl_up(s, d);
            if (t >= d) s += y;
        }
        wsum[t] = s;
    }
    __syncthreads();
    int wbase = (w > 0) ? wsum[w - 1] : 0;
    if (i < n) excl_out[i] = wbase + x - v;
    if (t == 1023) bsum[blockIdx.x] = wsum[15];
}

// each block redundantly reduces bsum[0..nb) for its own offset (no extra launch)
__global__ __launch_bounds__(1024)
void scan_add2_kernel(const int* __restrict__ bsum, int* __restrict__ row_ptr,
                      int* __restrict__ cursor, int n, int nb, int total)
{
    __shared__ int red[16];
    __shared__ int sboff;
    const int t = threadIdx.x, b = blockIdx.x;
    const int lane = t & 63, w = t >> 6;
    int vlt = (t < nb && t < b) ? bsum[t] : 0;
#pragma unroll
    for (int d = 32; d >= 1; d >>= 1) vlt += __shfl_xor(vlt, d);
    if (lane == 0) red[w] = vlt;
    __syncthreads();
    if (t == 0) {
        int a = 0;
#pragma unroll
        for (int k = 0; k < 16; ++k) a += red[k];
        sboff = a;
    }
    __syncthreads();
    const int i = b * 1024 + t;
    if (i < n) {
        int r = row_ptr[i] + sboff;
        row_ptr[i] = r;
        cursor[i]  = r;
    }
    if (b == 0 && t == 0) row_ptr[n] = total;
}

// ---------------- MFMA GEMM with GAT-alpha epilogue ----------------
template<int BM, int BN, int KDIM, int WR, int WC, int CPH>
__global__ __launch_bounds__(256, 2)
void mfma_gemm_gat(const unsigned short* __restrict__ Ahi, const unsigned short* __restrict__ Alo,
                   const unsigned short* __restrict__ BThi, const unsigned short* __restrict__ BTlo,
                   unsigned short* __restrict__ Cb,
                   const float* __restrict__ avec_s, const float* __restrict__ avec_d,
                   float* __restrict__ alpha_s, float* __restrict__ alpha_d,
                   int M, int N)
{
    constexpr int BK    = 32;
    constexpr int WROWS = BM / WR;
    constexpr int WCOLS = BN / WC;
    constexpr int FR    = WROWS / 16;
    constexpr int FC    = WCOLS / 16;
    constexpr int AP    = (BM * (BK / 8)) / 256;
    constexpr int BP    = (BN * (BK / 8)) / 256;
    static_assert(AP >= 1 && BP >= 1, "tile too small");

    __shared__ short As_hi[BM * BK], As_lo[BM * BK];
    __shared__ short Bs_hi[BN * BK], Bs_lo[BN * BK];

    const int tid  = threadIdx.x;
    const int w    = tid >> 6, lane = tid & 63;
    const int wr   = w / WC, wc = w % WC;
    const int lrow = lane & 15, lk = lane >> 4;
    const int m0   = blockIdx.x * BM, n0 = blockIdx.y * BN;

    f32x4 acc[FR][FC];
#pragma unroll
    for (int i = 0; i < FR; ++i)
#pragma unroll
        for (int j = 0; j < FC; ++j) acc[i][j] = (f32x4){0.f, 0.f, 0.f, 0.f};

    short8 rAh[AP], rAl[AP], rBh[BP], rBl[BP];

    auto LOAD = [&](int kb) {
#pragma unroll
        for (int p = 0; p < AP; ++p) {
            int id = p * 256 + tid;
            int r = id >> 2, c = id & 3;
            int row = m0 + r; row = row < M ? row : M - 1;
            size_t off = (size_t)row * KDIM + kb + c * 8;
            rAh[p] = *(const short8*)(Ahi + off);
            rAl[p] = *(const short8*)(Alo + off);
        }
#pragma unroll
        for (int p = 0; p < BP; ++p) {
            int id = p * 256 + tid;
            int r = id >> 2, c = id & 3;
            size_t off = (size_t)(n0 + r) * KDIM + kb + c * 8;
            rBh[p] = *(const short8*)(BThi + off);
            rBl[p] = *(const short8*)(BTlo + off);
        }
    };
    auto STORE = [&]() {
#pragma unroll
        for (int p = 0; p < AP; ++p) {
            int id = p * 256 + tid;
            int r = id >> 2, c = id & 3;
            *(short8*)(&As_hi[r * BK + c * 8]) = rAh[p];
            *(short8*)(&As_lo[r * BK + c * 8]) = rAl[p];
        }
#pragma unroll
        for (int p = 0; p < BP; ++p) {
            int id = p * 256 + tid;
            int r = id >> 2, c = id & 3;
            *(short8*)(&Bs_hi[r * BK + c * 8]) = rBh[p];
            *(short8*)(&Bs_lo[r * BK + c * 8]) = rBl[p];
        }
    };

    constexpr int NT = KDIM / BK;
    LOAD(0);
    for (int t = 0; t < NT; ++t) {
        STORE();
        __syncthreads();
        if (t + 1 < NT) LOAD((t + 1) * BK);

        short8 afh[FR], afl[FR], bfh[FC], bfl[FC];
#pragma unroll
        for (int fr = 0; fr < FR; ++fr) {
            int r = wr * WROWS + fr * 16 + lrow;
            afh[fr] = *(const short8*)(&As_hi[r * BK + lk * 8]);
            afl[fr] = *(const short8*)(&As_lo[r * BK + lk * 8]);
        }
#pragma unroll
        for (int fc = 0; fc < FC; ++fc) {
            int r = wc * WCOLS + fc * 16 + lrow;
            bfh[fc] = *(const short8*)(&Bs_hi[r * BK + lk * 8]);
            bfl[fc] = *(const short8*)(&Bs_lo[r * BK + lk * 8]);
        }
#pragma unroll
        for (int fr = 0; fr < FR; ++fr)
#pragma unroll
            for (int fc = 0; fc < FC; ++fc) {
                acc[fr][fc] = __builtin_amdgcn_mfma_f32_16x16x32_bf16(afh[fr], bfh[fc], acc[fr][fc], 0, 0, 0);
                acc[fr][fc] = __builtin_amdgcn_mfma_f32_16x16x32_bf16(afh[fr], bfl[fc], acc[fr][fc], 0, 0, 0);
                acc[fr][fc] = __builtin_amdgcn_mfma_f32_16x16x32_bf16(afl[fr], bfh[fc], acc[fr][fc], 0, 0, 0);
            }
        __syncthreads();
    }

#pragma unroll
    for (int fr = 0; fr < FR; ++fr) {
        const int rbase = m0 + wr * WROWS + fr * 16 + lk * 4;
        float ps[4] = {0.f, 0.f, 0.f, 0.f}, pd[4] = {0.f, 0.f, 0.f, 0.f};
#pragma unroll
        for (int fc = 0; fc < FC; ++fc) {
            const int gc   = n0 + wc * WCOLS + fc * 16 + lrow;
            const int head = gc / CPH, ci = gc % CPH;
            const float asv = avec_s[head * CPH + ci];
            const float adv = avec_d[head * CPH + ci];
#pragma unroll
            for (int rg = 0; rg < 4; ++rg) {
                int row = rbase + rg;
                float v = acc[fr][fc][rg];
                if (row < M) Cb[(size_t)row * N + gc] = bfr(v);
                ps[rg] += v * asv;
                pd[rg] += v * adv;
            }
            if constexpr (CPH == 16) {
#pragma unroll
                for (int rg = 0; rg < 4; ++rg) {
                    float s = ps[rg], d = pd[rg];
#pragma unroll
                    for (int m = 1; m <= 8; m <<= 1) {
                        s += __shfl_xor(s, m);
                        d += __shfl_xor(d, m);
                    }
                    if (lrow == 0 && rbase + rg < M) {
                        alpha_s[(size_t)(rbase + rg) * HEADS + head] = s;
                        alpha_d[(size_t)(rbase + rg) * HEADS + head] = d;
                    }
                    ps[rg] = 0.f; pd[rg] = 0.f;
                }
            }
        }
        if constexpr (CPH != 16) {
            const int head = (n0 + wc * WCOLS) / CPH;
#pragma unroll
            for (int rg = 0; rg < 4; ++rg) {
                float s = ps[rg], d = pd[rg];
#pragma unroll
                for (int m = 1; m <= 8; m <<= 1) {
                    s += __shfl_xor(s, m);
                    d += __shfl_xor(d, m);
                }
                if (lrow == 0 && rbase + rg < M) {
                    alpha_s[(size_t)(rbase + rg) * HEADS + head] = s;
                    alpha_d[(size_t)(rbase + rg) * HEADS + head] = d;
                }
            }
        }
    }
}

// ---------------- GAT softmax + aggregation ----------------
template<int CH, int S>
__global__ __launch_bounds__(256)
void gat_agg(const unsigned short* __restrict__ hb, const float* __restrict__ alpha_s,
             const float* __restrict__ alpha_d, const int* __restrict__ row_ptr,
             const int* __restrict__ csr_src, const float* __restrict__ bias,
             float* __restrict__ out, unsigned short* __restrict__ out_hi,
             unsigned short* __restrict__ out_lo, int n)
{
    constexpr int CPL = CH / S;
    constexpr int NSG = 256 / S;
    __shared__ float wls[NSG][S * 5];
    const int tid    = threadIdx.x;
    const int sub    = tid / S;
    const int i      = tid % S;
    const int lane64 = tid & 63;
    const int base   = lane64 & ~(S - 1);
    const int node   = blockIdx.x * NSG + sub;
    if (node >= n) return;
    const int head = (i * CPL) / (CH / 4);
    const int p0 = row_ptr[node], p1 = row_ptr[node + 1];
    const int deg = p1 - p0;

    const float4 asn = *(const float4*)(alpha_s + (size_t)node * 4);
    const float4 adn = *(const float4*)(alpha_d + (size_t)node * 4);
    float4 den = f4exp(f4lrelu(f4add(asn, adn)));
    const float wse = pickh(den, head);

    float acc[CPL];
    if constexpr (CPL == 8) {
        uint4 hv = *(const uint4*)(hb + (size_t)node * CH + i * 8);
        float2 q0 = bfpair(hv.x), q1 = bfpair(hv.y), q2 = bfpair(hv.z), q3 = bfpair(hv.w);
        acc[0] = wse * q0.x; acc[1] = wse * q0.y; acc[2] = wse * q1.x; acc[3] = wse * q1.y;
        acc[4] = wse * q2.x; acc[5] = wse * q2.y; acc[6] = wse * q3.x; acc[7] = wse * q3.y;
    } else {
        uint2 hv = *(const uint2*)(hb + (size_t)node * CH + i * 4);
        float2 q0 = bfpair(hv.x), q1 = bfpair(hv.y);
        acc[0] = wse * q0.x; acc[1] = wse * q0.y; acc[2] = wse * q1.x; acc[3] = wse * q1.y;
    }

    for (int ch = 0; ch < deg; ch += S) {
        const int cnt = min(S, deg - ch);
        float4 w4 = make_float4(0.f, 0.f, 0.f, 0.f);
        int sl = 0;
        if (i < cnt) {
            sl = csr_src[p0 + ch + i];
            float4 al = *(const float4*)(alpha_s + (size_t)sl * 4);
            w4 = f4exp(f4lrelu(f4add(al, adn)));
        }
        float4 t = w4;
#pragma unroll
        for (int d = S / 2; d >= 1; d >>= 1) {
            t.x += __shfl_xor(t.x, d);
            t.y += __shfl_xor(t.y, d);
            t.z += __shfl_xor(t.z, d);
            t.w += __shfl_xor(t.w, d);
        }
        den = f4add(den, t);
        wls[sub][i * 5 + 0] = w4.x;
        wls[sub][i * 5 + 1] = w4.y;
        wls[sub][i * 5 + 2] = w4.z;
        wls[sub][i * 5 + 3] = w4.w;

        const int padded = (cnt + 7) & ~7;
        for (int j = 0; j < padded; j += 8) {
            int   sk[8];
            float wk[8];
#pragma unroll
            for (int k = 0; k < 8; ++k) {
                sk[k] = __shfl(sl, base + j + k);
                wk[k] = wls[sub][(j + k) * 5 + head];
            }
            if constexpr (CPL == 8) {
                uint4 v[8];
#pragma unroll
                for (int k = 0; k < 8; ++k)
                    v[k] = *(const uint4*)(hb + (size_t)sk[k] * CH + i * 8);
#pragma unroll
                for (int k = 0; k < 8; ++k) {
                    float2 q0 = bfpair(v[k].x), q1 = bfpair(v[k].y);
                    float2 q2 = bfpair(v[k].z), q3 = bfpair(v[k].w);
                    acc[0] += wk[k] * q0.x; acc[1] += wk[k] * q0.y;
                    acc[2] += wk[k] * q1.x; acc[3] += wk[k] * q1.y;
                    acc[4] += wk[k] * q2.x; acc[5] += wk[k] * q2.y;
                    acc[6] += wk[k] * q3.x; acc[7] += wk[k] * q3.y;
                }
            } else {
                uint2 v[8];
#pragma unroll
                for (int k = 0; k < 8; ++k)
                    v[k] = *(const uint2*)(hb + (size_t)sk[k] * CH + i * 4);
#pragma unroll
                for (int k = 0; k < 8; ++k) {
                    float2 q0 = bfpair(v[k].x), q1 = bfpair(v[k].y);
                    acc[0] += wk[k] * q0.x; acc[1] += wk[k] * q0.y;
                    acc[2] += wk[k] * q1.x; acc[3] += wk[k] * q1.y;
                }
            }
        }
    }

    const float invd = 1.0f / (pickh(den, head) + 1e-16f);
    const int c0 = i * CPL;
    if constexpr (CPL == 8) {
        float o[8];
        unsigned short oh[8], ol[8];
#pragma unroll
        for (int k = 0; k < 8; ++k) {
            o[k] = fmaxf(acc[k] * invd + bias[c0 + k], 0.f);
            oh[k] = bfr(o[k]);
            ol[k] = bfr(o[k] - bf2f(oh[k]));
        }
        uint4 ph, pl;
        ph.x = (unsigned)oh[0] | ((unsigned)oh[1] << 16);
        ph.y = (unsigned)oh[2] | ((unsigned)oh[3] << 16);
        ph.z = (unsigned)oh[4] | ((unsigned)oh[5] << 16);
        ph.w = (unsigned)oh[6] | ((unsigned)oh[7] << 16);
        pl.x = (unsigned)ol[0] | ((unsigned)ol[1] << 16);
        pl.y = (unsigned)ol[2] | ((unsigned)ol[3] << 16);
        pl.z = (unsigned)ol[4] | ((unsigned)ol[5] << 16);
        pl.w = (unsigned)ol[6] | ((unsigned)ol[7] << 16);
        *(uint4*)(out_hi + (size_t)node * CH + c0) = ph;
        *(uint4*)(out_lo + (size_t)node * CH + c0) = pl;
    } else {
        float4 o;
        o.x = fmaxf(acc[0] * invd + bias[c0 + 0], 0.f);
        o.y = fmaxf(acc[1] * invd + bias[c0 + 1], 0.f);
        o.z = fmaxf(acc[2] * invd + bias[c0 + 2], 0.f);
        o.w = fmaxf(acc[3] * invd + bias[c0 + 3], 0.f);
        *(float4*)(out + (size_t)node * CH + c0) = o;
    }
}

// ---------------- fused mean-pool/FC (per-block binary search) ----------------
__global__ __launch_bounds__(256)
void pool_fc_kernel(const float* __restrict__ feat, const int* __restrict__ batch,
                    const float* __restrict__ Wfc, const float* __restrict__ bfc,
                    float* __restrict__ out, int n)
{
    __shared__ float4 part[16][16];
    __shared__ float pooled[64];
    __shared__ int sb[2];
    const int g = blockIdx.x;
    const int t = threadIdx.x;
    if (t < 2) {
        int target = g + t;
        int lo = 0, hi = n;
        while (lo < hi) {
            int mid = (lo + hi) >> 1;
            if (batch[mid] < target) lo = mid + 1; else hi = mid;
        }
        sb[t] = lo;
    }
    __syncthreads();
    const int s0 = sb[0], s1 = sb[1];
    const int q = t & 15, ns = t >> 4;
    float4 acc = make_float4(0.f, 0.f, 0.f, 0.f);
    for (int i = s0 + ns; i < s1; i += 16)
        acc = f4add(acc, *(const float4*)(feat + (size_t)i * 64 + q * 4));
    part[ns][q] = acc;
    __syncthreads();
    if (t < 16) {
        float4 s = part[0][t];
#pragma unroll
        for (int k = 1; k < 16; ++k) s = f4add(s, part[k][t]);
        float inv = 1.0f / fmaxf((float)(s1 - s0), 1.0f);
        pooled[t * 4 + 0] = s.x * inv;
        pooled[t * 4 + 1] = s.y * inv;
        pooled[t * 4 + 2] = s.z * inv;
        pooled[t * 4 + 3] = s.w * inv;
    }
    __syncthreads();
    if (t < 2) {
        float a = bfc[t];
        for (int c = 0; c < 64; ++c) a += pooled[c] * Wfc[c * 2 + t];
        out[g * 2 + t] = a;
    }
}

// ---------------- launch ----------------
extern "C" void kernel_launch(void* const* d_in, const int* in_sizes, int n_in,
                              void* d_out, int out_size, void* d_ws, size_t ws_size,
                              hipStream_t stream)
{
    const float* x    = (const float*)d_in[0];
    const int*   ei   = (const int*)d_in[1];
    const int*   batch= (const int*)d_in[2];
    const float* W1   = (const float*)d_in[3];
    const float* as1  = (const float*)d_in[4];
    const float* ad1  = (const float*)d_in[5];
    const float* b1   = (const float*)d_in[6];
    const float* W2   = (const float*)d_in[7];
    const float* as2  = (const float*)d_in[8];
    const float* ad2  = (const float*)d_in[9];
    const float* b2   = (const float*)d_in[10];
    const float* Wfc  = (const float*)d_in[11];
    const float* bfc  = (const float*)d_in[12];
    float* out = (float*)d_out;

    const int N = in_sizes[2];          // 50000 nodes
    const int E = in_sizes[1] / 27;     // 400000 edges
    const int F = in_sizes[0] / N;      // 128

    char* ws = (char*)d_ws;
    unsigned short* h1b   = (unsigned short*)(ws + OFF_H1B);
    unsigned short* h2b   = (unsigned short*)(ws + OFF_H2B);
    float*          out2  = (float*)(ws + OFF_OUT2);
    unsigned short* xhi   = (unsigned short*)(ws + OFF_XHI);
    unsigned short* xlo   = (unsigned short*)(ws + OFF_XLO);
    unsigned short* o1hi  = (unsigned short*)(ws + OFF_O1HI);
    unsigned short* o1lo  = (unsigned short*)(ws + OFF_O1LO);
    unsigned short* w1th  = (unsigned short*)(ws + OFF_W1TH);
    unsigned short* w1tl  = (unsigned short*)(ws + OFF_W1TL);
    unsigned short* w2th  = (unsigned short*)(ws + OFF_W2TH);
    unsigned short* w2tl  = (unsigned short*)(ws + OFF_W2TL);
    float* al_s  = (float*)(ws + OFF_AS);
    float* al_d  = (float*)(ws + OFF_AD);
    int*   rp    = (int*)(ws + OFF_RP);     // (2N+1) entries; layer2 view = rp+N
    int*   cur   = (int*)(ws + OFF_CUR);    // 2N
    int*   cnt   = (int*)(ws + OFF_CNT);    // 2N
    int*   csr   = (int*)(ws + OFF_CSR);    // 2E (global positions)
    int*   bsum  = (int*)(ws + OFF_BSUM);
    int*   boff  = (int*)(ws + OFF_BOFF);
    (void)boff;

    const int e2grid8 = (2 * E + 2047) / 2048;   // 391 blocks (8 edges/thread)
    const int NB2     = (2 * N + 1023) / 1024;   // 98 blocks
    const int ZB      = ((2 * N / 4) + 255) / 256; // 98 zero-blocks in prep

    // ---- 1: fused prep (x split + W splits + cnt zero) ----
    prep_kernel<<<1216 + ZB, 256, 0, stream>>>(x, xhi, xlo, N * F / 4,
                                               W1, w1th, w1tl, W2, w2th, w2tl,
                                               cnt, 2 * N);

    // ---- 2-5: CSR build (count, scan, add+cursor, scatter) ----
    count2_kernel<<<e2grid8, 256, 0, stream>>>(ei + 26 * (size_t)E, ei + 16 * (size_t)E, cnt, N, E);
    scan_block_kernel<<<NB2, 1024, 0, stream>>>(cnt, rp, bsum, 2 * N);
    scan_add2_kernel<<<NB2, 1024, 0, stream>>>(bsum, rp, cur, 2 * N, NB2, 2 * E);
    scatter2_kernel<<<e2grid8, 256, 0, stream>>>(ei + 17 * (size_t)E, ei + 26 * (size_t)E,
                                                 ei + 15 * (size_t)E, ei + 16 * (size_t)E,
                                                 cur, csr, N, E);

    // ---- 6: layer-1 MFMA GEMM -> bf16 h1 ----
    {
        dim3 g((N + 127) / 128, 2);
        mfma_gemm_gat<128, 128, 128, 2, 2, 64><<<g, 256, 0, stream>>>(
            xhi, xlo, w1th, w1tl, h1b, as1, ad1, al_s, al_d, N, HEADS * 64);
    }
    // ---- 7: layer-1 aggregation ----
    gat_agg<256, 32><<<(N + 7) / 8, 256, 0, stream>>>(h1b, al_s, al_d, rp, csr, b1,
                                                      nullptr, o1hi, o1lo, N);

    // ---- 8: layer-2 MFMA GEMM -> bf16 h2 ----
    {
        dim3 g((N + 63) / 64, 1);
        mfma_gemm_gat<64, 64, 256, 2, 2, 16><<<g, 256, 0, stream>>>(
            o1hi, o1lo, w2th, w2tl, h2b, as2, ad2, al_s, al_d, N, HEADS * 16);
    }
    // ---- 9: layer-2 aggregation ----
    gat_agg<64, 16><<<(N + 15) / 16, 256, 0, stream>>>(h2b, al_s, al_d, rp + N, csr, b2,
                                                       out2, nullptr, nullptr, N);

    // ---- 10: fused mean-pool + FC ----
    pool_fc_kernel<<<64, 256, 0, stream>>>(out2, batch, Wfc, bfc, out, N);
}

// Round 13
// 209.740 us; speedup vs baseline: 1.0770x; 1.0355x over previous
//
#include <hip/hip_runtime.h>
#include <math.h>

#define HEADS 4
#define NEG_SLOPE 0.2f

// ---------------- workspace layout (bytes) ----------------
static constexpr size_t OFF_H1B  = 0;
static constexpr size_t OFF_H2B  = 0;
static constexpr size_t OFF_OUT2 = 6400000;
static constexpr size_t OFF_XHI  = 25600000;
static constexpr size_t OFF_XLO  = 38400000;
static constexpr size_t OFF_O1HI = 25600000;   // aliases xhi/xlo (dead by then)
static constexpr size_t OFF_W1TH = 76800000;   // 256x128 bf16 = 64KB
static constexpr size_t OFF_W1TL = 76865536;
static constexpr size_t OFF_W2TH = 76931072;   // 64x256 bf16 = 32KB
static constexpr size_t OFF_W2TL = 76963840;
static constexpr size_t OFF_AS   = 77000000;   // 800,000
static constexpr size_t OFF_AD   = 77800000;   // 800,000
static constexpr size_t OFF_RP   = 78600064;   // (2N+1) ints
static constexpr size_t OFF_CUR  = 79000128;
static constexpr size_t OFF_CNT  = 79400128;
static constexpr size_t OFF_CSR  = 79800128;   // 2E ints
static constexpr size_t OFF_BSUM = 83000448;

typedef __attribute__((ext_vector_type(8))) short short8;
typedef __attribute__((ext_vector_type(4))) float f32x4;

// ---------------- helpers ----------------
__device__ __forceinline__ float4 f4add(float4 a, float4 b) {
    return make_float4(a.x + b.x, a.y + b.y, a.z + b.z, a.w + b.w);
}
__device__ __forceinline__ float lrelu(float x) { return x > 0.f ? x : NEG_SLOPE * x; }
__device__ __forceinline__ float4 f4lrelu(float4 a) {
    return make_float4(lrelu(a.x), lrelu(a.y), lrelu(a.z), lrelu(a.w));
}
__device__ __forceinline__ float4 f4exp(float4 a) {
    return make_float4(__expf(a.x), __expf(a.y), __expf(a.z), __expf(a.w));
}
__device__ __forceinline__ float pickh(float4 v, int head) {
    float r = v.x;
    r = head == 1 ? v.y : r;
    r = head == 2 ? v.z : r;
    r = head == 3 ? v.w : r;
    return r;
}
__device__ __forceinline__ unsigned short bfr(float x) {
    union { float f; unsigned u; } c; c.f = x;
    unsigned r = c.u + 0x7FFFu + ((c.u >> 16) & 1u);
    return (unsigned short)(r >> 16);
}
__device__ __forceinline__ float bf2f(unsigned short h) {
    union { unsigned u; float f; } c; c.u = ((unsigned)h) << 16;
    return c.f;
}
__device__ __forceinline__ float2 bfpair(unsigned u) {
    union { unsigned a; float f; } lo, hi;
    lo.a = u << 16;
    hi.a = u & 0xffff0000u;
    return make_float2(lo.f, hi.f);
}

// ---------------- fused prep: x-split + W1T/W2T-split + cnt zero ----------------
__global__ void prep_kernel(const float* __restrict__ x, unsigned short* __restrict__ xhi,
                            unsigned short* __restrict__ xlo, int n4,
                            const float* __restrict__ W1, unsigned short* __restrict__ w1th,
                            unsigned short* __restrict__ w1tl,
                            const float* __restrict__ W2, unsigned short* __restrict__ w2th,
                            unsigned short* __restrict__ w2tl,
                            int* __restrict__ cnt, int n2)
{
    const int b = blockIdx.x, t = threadIdx.x;
    if (b < 1024) {
        for (int i = b * 256 + t; i < n4; i += 1024 * 256) {
            float4 v = ((const float4*)x)[i];
            unsigned short h0 = bfr(v.x), h1 = bfr(v.y), h2 = bfr(v.z), h3 = bfr(v.w);
            unsigned short l0 = bfr(v.x - bf2f(h0)), l1 = bfr(v.y - bf2f(h1));
            unsigned short l2 = bfr(v.z - bf2f(h2)), l3 = bfr(v.w - bf2f(h3));
            ((uint2*)xhi)[i] = make_uint2((unsigned)h0 | ((unsigned)h1 << 16),
                                          (unsigned)h2 | ((unsigned)h3 << 16));
            ((uint2*)xlo)[i] = make_uint2((unsigned)l0 | ((unsigned)l1 << 16),
                                          (unsigned)l2 | ((unsigned)l3 << 16));
        }
    } else if (b < 1024 + 128) {
        int idx = (b - 1024) * 256 + t;          // W1: K=128, N=256
        const int K = 128, Nc = 256;
        int k = idx / Nc, n = idx - k * Nc;
        float v = W1[idx];
        unsigned short h = bfr(v);
        w1th[(size_t)n * K + k] = h;
        w1tl[(size_t)n * K + k] = bfr(v - bf2f(h));
    } else if (b < 1024 + 128 + 64) {
        int idx = (b - 1152) * 256 + t;          // W2: K=256, N=64
        const int K = 256, Nc = 64;
        int k = idx / Nc, n = idx - k * Nc;
        float v = W2[idx];
        unsigned short h = bfr(v);
        w2th[(size_t)n * K + k] = h;
        w2tl[(size_t)n * K + k] = bfr(v - bf2f(h));
    } else {
        int idx = (b - 1216) * 256 + t;          // zero cnt[2N] via int4
        if (idx < (n2 >> 2)) ((int4*)cnt)[idx] = make_int4(0, 0, 0, 0);
    }
}

// ---------------- fused 2-layer CSR build (8 edges/thread for MLP) ----------------
__global__ void count2_kernel(const int* __restrict__ dst1, const int* __restrict__ dst2,
                              int* __restrict__ counts, int N, int E)
{
    const int base = blockIdx.x * 2048 + threadIdx.x;
#pragma unroll
    for (int k = 0; k < 8; ++k) {
        int e = base + k * 256;
        if (e < E)          atomicAdd(&counts[dst1[e]], 1);
        else if (e < 2 * E) atomicAdd(&counts[N + dst2[e - E]], 1);
    }
}

__global__ void scatter2_kernel(const int* __restrict__ src1, const int* __restrict__ dst1,
                                const int* __restrict__ src2, const int* __restrict__ dst2,
                                int* __restrict__ cursor, int* __restrict__ csr, int N, int E)
{
    const int base = blockIdx.x * 2048 + threadIdx.x;
    int srcv[8], pos[8];
    bool valid[8];
#pragma unroll
    for (int k = 0; k < 8; ++k) {
        int e = base + k * 256;
        valid[k] = (e < 2 * E);
        srcv[k] = 0; pos[k] = 0;
        if (e < E) {
            srcv[k] = src1[e];
            pos[k]  = atomicAdd(&cursor[dst1[e]], 1);
        } else if (e < 2 * E) {
            srcv[k] = src2[e - E];
            pos[k]  = atomicAdd(&cursor[N + dst2[e - E]], 1);
        }
    }
#pragma unroll
    for (int k = 0; k < 8; ++k)
        if (valid[k]) csr[pos[k]] = srcv[k];
}

// ---------------- parallel scan (2 kernels) ----------------
__global__ __launch_bounds__(1024)
void scan_block_kernel(const int* __restrict__ counts, int* __restrict__ excl_out,
                       int* __restrict__ bsum, int n)
{
    __shared__ int wsum[16];
    const int t = threadIdx.x, lane = t & 63, w = t >> 6;
    const int i = blockIdx.x * 1024 + t;
    int v = (i < n) ? counts[i] : 0;
    int x = v;
#pragma unroll
    for (int d = 1; d < 64; d <<= 1) {
        int y = __shfl_up(x, d);
        if (lane >= d) x += y;
    }
    if (lane == 63) wsum[w] = x;
    __syncthreads();
    if (t < 16) {
        int s = wsum[t];
#pragma unroll
        for (int d = 1; d < 16; d <<= 1) {
            int y = __shfl_up(s, d);
            if (t >= d) s += y;
        }
        wsum[t] = s;
    }
    __syncthreads();
    int wbase = (w > 0) ? wsum[w - 1] : 0;
    if (i < n) excl_out[i] = wbase + x - v;
    if (t == 1023) bsum[blockIdx.x] = wsum[15];
}

// each block redundantly reduces bsum[0..nb) for its own offset (no extra launch)
__global__ __launch_bounds__(1024)
void scan_add2_kernel(const int* __restrict__ bsum, int* __restrict__ row_ptr,
                      int* __restrict__ cursor, int n, int nb, int total)
{
    __shared__ int red[16];
    __shared__ int sboff;
    const int t = threadIdx.x, b = blockIdx.x;
    const int lane = t & 63, w = t >> 6;
    int vlt = (t < nb && t < b) ? bsum[t] : 0;
#pragma unroll
    for (int d = 32; d >= 1; d >>= 1) vlt += __shfl_xor(vlt, d);
    if (lane == 0) red[w] = vlt;
    __syncthreads();
    if (t == 0) {
        int a = 0;
#pragma unroll
        for (int k = 0; k < 16; ++k) a += red[k];
        sboff = a;
    }
    __syncthreads();
    const int i = b * 1024 + t;
    if (i < n) {
        int r = row_ptr[i] + sboff;
        row_ptr[i] = r;
        cursor[i]  = r;
    }
    if (b == 0 && t == 0) row_ptr[n] = total;
}

// ---------------- MFMA GEMM with GAT-alpha epilogue ----------------
// ALO=true: 3-pass split-bf16 (AhiBhi + AhiBlo + AloBhi), f32-exact A.
// ALO=false: A is plain bf16; 2-pass (AhiBhi + AhiBlo). Halves A fetch + LDS.
template<int BM, int BN, int KDIM, int WR, int WC, int CPH, bool ALO>
__global__ __launch_bounds__(256, 2)
void mfma_gemm_gat(const unsigned short* __restrict__ Ahi, const unsigned short* __restrict__ Alo,
                   const unsigned short* __restrict__ BThi, const unsigned short* __restrict__ BTlo,
                   unsigned short* __restrict__ Cb,
                   const float* __restrict__ avec_s, const float* __restrict__ avec_d,
                   float* __restrict__ alpha_s, float* __restrict__ alpha_d,
                   int M, int N)
{
    constexpr int BK    = 32;
    constexpr int WROWS = BM / WR;
    constexpr int WCOLS = BN / WC;
    constexpr int FR    = WROWS / 16;
    constexpr int FC    = WCOLS / 16;
    constexpr int AP    = (BM * (BK / 8)) / 256;
    constexpr int BP    = (BN * (BK / 8)) / 256;
    static_assert(AP >= 1 && BP >= 1, "tile too small");

    __shared__ short As_hi[BM * BK], As_lo[ALO ? BM * BK : 64];
    __shared__ short Bs_hi[BN * BK], Bs_lo[BN * BK];

    const int tid  = threadIdx.x;
    const int w    = tid >> 6, lane = tid & 63;
    const int wr   = w / WC, wc = w % WC;
    const int lrow = lane & 15, lk = lane >> 4;
    const int m0   = blockIdx.x * BM, n0 = blockIdx.y * BN;

    f32x4 acc[FR][FC];
#pragma unroll
    for (int i = 0; i < FR; ++i)
#pragma unroll
        for (int j = 0; j < FC; ++j) acc[i][j] = (f32x4){0.f, 0.f, 0.f, 0.f};

    short8 rAh[AP], rAl[AP], rBh[BP], rBl[BP];

    auto LOAD = [&](int kb) {
#pragma unroll
        for (int p = 0; p < AP; ++p) {
            int id = p * 256 + tid;
            int r = id >> 2, c = id & 3;
            int row = m0 + r; row = row < M ? row : M - 1;
            size_t off = (size_t)row * KDIM + kb + c * 8;
            rAh[p] = *(const short8*)(Ahi + off);
            if constexpr (ALO) rAl[p] = *(const short8*)(Alo + off);
        }
#pragma unroll
        for (int p = 0; p < BP; ++p) {
            int id = p * 256 + tid;
            int r = id >> 2, c = id & 3;
            size_t off = (size_t)(n0 + r) * KDIM + kb + c * 8;
            rBh[p] = *(const short8*)(BThi + off);
            rBl[p] = *(const short8*)(BTlo + off);
        }
    };
    auto STORE = [&]() {
#pragma unroll
        for (int p = 0; p < AP; ++p) {
            int id = p * 256 + tid;
            int r = id >> 2, c = id & 3;
            *(short8*)(&As_hi[r * BK + c * 8]) = rAh[p];
            if constexpr (ALO) *(short8*)(&As_lo[r * BK + c * 8]) = rAl[p];
        }
#pragma unroll
        for (int p = 0; p < BP; ++p) {
            int id = p * 256 + tid;
            int r = id >> 2, c = id & 3;
            *(short8*)(&Bs_hi[r * BK + c * 8]) = rBh[p];
            *(short8*)(&Bs_lo[r * BK + c * 8]) = rBl[p];
        }
    };

    constexpr int NT = KDIM / BK;
    LOAD(0);
    for (int t = 0; t < NT; ++t) {
        STORE();
        __syncthreads();
        if (t + 1 < NT) LOAD((t + 1) * BK);

        short8 afh[FR], afl[FR], bfh[FC], bfl[FC];
#pragma unroll
        for (int fr = 0; fr < FR; ++fr) {
            int r = wr * WROWS + fr * 16 + lrow;
            afh[fr] = *(const short8*)(&As_hi[r * BK + lk * 8]);
            if constexpr (ALO) afl[fr] = *(const short8*)(&As_lo[r * BK + lk * 8]);
        }
#pragma unroll
        for (int fc = 0; fc < FC; ++fc) {
            int r = wc * WCOLS + fc * 16 + lrow;
            bfh[fc] = *(const short8*)(&Bs_hi[r * BK + lk * 8]);
            bfl[fc] = *(const short8*)(&Bs_lo[r * BK + lk * 8]);
        }
#pragma unroll
        for (int fr = 0; fr < FR; ++fr)
#pragma unroll
            for (int fc = 0; fc < FC; ++fc) {
                acc[fr][fc] = __builtin_amdgcn_mfma_f32_16x16x32_bf16(afh[fr], bfh[fc], acc[fr][fc], 0, 0, 0);
                acc[fr][fc] = __builtin_amdgcn_mfma_f32_16x16x32_bf16(afh[fr], bfl[fc], acc[fr][fc], 0, 0, 0);
                if constexpr (ALO)
                    acc[fr][fc] = __builtin_amdgcn_mfma_f32_16x16x32_bf16(afl[fr], bfh[fc], acc[fr][fc], 0, 0, 0);
            }
        __syncthreads();
    }

#pragma unroll
    for (int fr = 0; fr < FR; ++fr) {
        const int rbase = m0 + wr * WROWS + fr * 16 + lk * 4;
        float ps[4] = {0.f, 0.f, 0.f, 0.f}, pd[4] = {0.f, 0.f, 0.f, 0.f};
#pragma unroll
        for (int fc = 0; fc < FC; ++fc) {
            const int gc   = n0 + wc * WCOLS + fc * 16 + lrow;
            const int head = gc / CPH, ci = gc % CPH;
            const float asv = avec_s[head * CPH + ci];
            const float adv = avec_d[head * CPH + ci];
#pragma unroll
            for (int rg = 0; rg < 4; ++rg) {
                int row = rbase + rg;
                float v = acc[fr][fc][rg];
                if (row < M) Cb[(size_t)row * N + gc] = bfr(v);
                ps[rg] += v * asv;
                pd[rg] += v * adv;
            }
            if constexpr (CPH == 16) {
#pragma unroll
                for (int rg = 0; rg < 4; ++rg) {
                    float s = ps[rg], d = pd[rg];
#pragma unroll
                    for (int m = 1; m <= 8; m <<= 1) {
                        s += __shfl_xor(s, m);
                        d += __shfl_xor(d, m);
                    }
                    if (lrow == 0 && rbase + rg < M) {
                        alpha_s[(size_t)(rbase + rg) * HEADS + head] = s;
                        alpha_d[(size_t)(rbase + rg) * HEADS + head] = d;
                    }
                    ps[rg] = 0.f; pd[rg] = 0.f;
                }
            }
        }
        if constexpr (CPH != 16) {
            const int head = (n0 + wc * WCOLS) / CPH;
#pragma unroll
            for (int rg = 0; rg < 4; ++rg) {
                float s = ps[rg], d = pd[rg];
#pragma unroll
                for (int m = 1; m <= 8; m <<= 1) {
                    s += __shfl_xor(s, m);
                    d += __shfl_xor(d, m);
                }
                if (lrow == 0 && rbase + rg < M) {
                    alpha_s[(size_t)(rbase + rg) * HEADS + head] = s;
                    alpha_d[(size_t)(rbase + rg) * HEADS + head] = d;
                }
            }
        }
    }
}

// ---------------- GAT softmax + aggregation ----------------
// S lanes per node; 8-deep unrolled gather with zero-weight padding.
// CPL==8 writes bf16 hi only (GEMM2's A is plain bf16).
template<int CH, int S>
__global__ __launch_bounds__(256)
void gat_agg(const unsigned short* __restrict__ hb, const float* __restrict__ alpha_s,
             const float* __restrict__ alpha_d, const int* __restrict__ row_ptr,
             const int* __restrict__ csr_src, const float* __restrict__ bias,
             float* __restrict__ out, unsigned short* __restrict__ out_hi, int n)
{
    constexpr int CPL = CH / S;
    constexpr int NSG = 256 / S;
    __shared__ float wls[NSG][S * 5];
    const int tid    = threadIdx.x;
    const int sub    = tid / S;
    const int i      = tid % S;
    const int lane64 = tid & 63;
    const int base   = lane64 & ~(S - 1);
    const int node   = blockIdx.x * NSG + sub;
    if (node >= n) return;
    const int head = (i * CPL) / (CH / 4);
    const int p0 = row_ptr[node], p1 = row_ptr[node + 1];
    const int deg = p1 - p0;

    const float4 asn = *(const float4*)(alpha_s + (size_t)node * 4);
    const float4 adn = *(const float4*)(alpha_d + (size_t)node * 4);
    float4 den = f4exp(f4lrelu(f4add(asn, adn)));
    const float wse = pickh(den, head);

    float acc[CPL];
    if constexpr (CPL == 8) {
        uint4 hv = *(const uint4*)(hb + (size_t)node * CH + i * 8);
        float2 q0 = bfpair(hv.x), q1 = bfpair(hv.y), q2 = bfpair(hv.z), q3 = bfpair(hv.w);
        acc[0] = wse * q0.x; acc[1] = wse * q0.y; acc[2] = wse * q1.x; acc[3] = wse * q1.y;
        acc[4] = wse * q2.x; acc[5] = wse * q2.y; acc[6] = wse * q3.x; acc[7] = wse * q3.y;
    } else {
        uint2 hv = *(const uint2*)(hb + (size_t)node * CH + i * 4);
        float2 q0 = bfpair(hv.x), q1 = bfpair(hv.y);
        acc[0] = wse * q0.x; acc[1] = wse * q0.y; acc[2] = wse * q1.x; acc[3] = wse * q1.y;
    }

    for (int ch = 0; ch < deg; ch += S) {
        const int cnt = min(S, deg - ch);
        float4 w4 = make_float4(0.f, 0.f, 0.f, 0.f);
        int sl = 0;
        if (i < cnt) {
            sl = csr_src[p0 + ch + i];
            float4 al = *(const float4*)(alpha_s + (size_t)sl * 4);
            w4 = f4exp(f4lrelu(f4add(al, adn)));
        }
        float4 t = w4;
#pragma unroll
        for (int d = S / 2; d >= 1; d >>= 1) {
            t.x += __shfl_xor(t.x, d);
            t.y += __shfl_xor(t.y, d);
            t.z += __shfl_xor(t.z, d);
            t.w += __shfl_xor(t.w, d);
        }
        den = f4add(den, t);
        wls[sub][i * 5 + 0] = w4.x;
        wls[sub][i * 5 + 1] = w4.y;
        wls[sub][i * 5 + 2] = w4.z;
        wls[sub][i * 5 + 3] = w4.w;

        const int padded = (cnt + 7) & ~7;
        for (int j = 0; j < padded; j += 8) {
            int   sk[8];
            float wk[8];
#pragma unroll
            for (int k = 0; k < 8; ++k) {
                sk[k] = __shfl(sl, base + j + k);
                wk[k] = wls[sub][(j + k) * 5 + head];
            }
            if constexpr (CPL == 8) {
                uint4 v[8];
#pragma unroll
                for (int k = 0; k < 8; ++k)
                    v[k] = *(const uint4*)(hb + (size_t)sk[k] * CH + i * 8);
#pragma unroll
                for (int k = 0; k < 8; ++k) {
                    float2 q0 = bfpair(v[k].x), q1 = bfpair(v[k].y);
                    float2 q2 = bfpair(v[k].z), q3 = bfpair(v[k].w);
                    acc[0] += wk[k] * q0.x; acc[1] += wk[k] * q0.y;
                    acc[2] += wk[k] * q1.x; acc[3] += wk[k] * q1.y;
                    acc[4] += wk[k] * q2.x; acc[5] += wk[k] * q2.y;
                    acc[6] += wk[k] * q3.x; acc[7] += wk[k] * q3.y;
                }
            } else {
                uint2 v[8];
#pragma unroll
                for (int k = 0; k < 8; ++k)
                    v[k] = *(const uint2*)(hb + (size_t)sk[k] * CH + i * 4);
#pragma unroll
                for (int k = 0; k < 8; ++k) {
                    float2 q0 = bfpair(v[k].x), q1 = bfpair(v[k].y);
                    acc[0] += wk[k] * q0.x; acc[1] += wk[k] * q0.y;
                    acc[2] += wk[k] * q1.x; acc[3] += wk[k] * q1.y;
                }
            }
        }
    }

    const float invd = 1.0f / (pickh(den, head) + 1e-16f);
    const int c0 = i * CPL;
    if constexpr (CPL == 8) {
        float o[8];
        unsigned short oh[8];
#pragma unroll
        for (int k = 0; k < 8; ++k) {
            o[k] = fmaxf(acc[k] * invd + bias[c0 + k], 0.f);
            oh[k] = bfr(o[k]);
        }
        uint4 ph;
        ph.x = (unsigned)oh[0] | ((unsigned)oh[1] << 16);
        ph.y = (unsigned)oh[2] | ((unsigned)oh[3] << 16);
        ph.z = (unsigned)oh[4] | ((unsigned)oh[5] << 16);
        ph.w = (unsigned)oh[6] | ((unsigned)oh[7] << 16);
        *(uint4*)(out_hi + (size_t)node * CH + c0) = ph;
    } else {
        float4 o;
        o.x = fmaxf(acc[0] * invd + bias[c0 + 0], 0.f);
        o.y = fmaxf(acc[1] * invd + bias[c0 + 1], 0.f);
        o.z = fmaxf(acc[2] * invd + bias[c0 + 2], 0.f);
        o.w = fmaxf(acc[3] * invd + bias[c0 + 3], 0.f);
        *(float4*)(out + (size_t)node * CH + c0) = o;
    }
}

// ---------------- fused mean-pool/FC (per-block binary search) ----------------
__global__ __launch_bounds__(256)
void pool_fc_kernel(const float* __restrict__ feat, const int* __restrict__ batch,
                    const float* __restrict__ Wfc, const float* __restrict__ bfc,
                    float* __restrict__ out, int n)
{
    __shared__ float4 part[16][16];
    __shared__ float pooled[64];
    __shared__ int sb[2];
    const int g = blockIdx.x;
    const int t = threadIdx.x;
    if (t < 2) {
        int target = g + t;
        int lo = 0, hi = n;
        while (lo < hi) {
            int mid = (lo + hi) >> 1;
            if (batch[mid] < target) lo = mid + 1; else hi = mid;
        }
        sb[t] = lo;
    }
    __syncthreads();
    const int s0 = sb[0], s1 = sb[1];
    const int q = t & 15, ns = t >> 4;
    float4 acc = make_float4(0.f, 0.f, 0.f, 0.f);
    for (int i = s0 + ns; i < s1; i += 16)
        acc = f4add(acc, *(const float4*)(feat + (size_t)i * 64 + q * 4));
    part[ns][q] = acc;
    __syncthreads();
    if (t < 16) {
        float4 s = part[0][t];
#pragma unroll
        for (int k = 1; k < 16; ++k) s = f4add(s, part[k][t]);
        float inv = 1.0f / fmaxf((float)(s1 - s0), 1.0f);
        pooled[t * 4 + 0] = s.x * inv;
        pooled[t * 4 + 1] = s.y * inv;
        pooled[t * 4 + 2] = s.z * inv;
        pooled[t * 4 + 3] = s.w * inv;
    }
    __syncthreads();
    if (t < 2) {
        float a = bfc[t];
        for (int c = 0; c < 64; ++c) a += pooled[c] * Wfc[c * 2 + t];
        out[g * 2 + t] = a;
    }
}

// ---------------- launch ----------------
extern "C" void kernel_launch(void* const* d_in, const int* in_sizes, int n_in,
                              void* d_out, int out_size, void* d_ws, size_t ws_size,
                              hipStream_t stream)
{
    const float* x    = (const float*)d_in[0];
    const int*   ei   = (const int*)d_in[1];
    const int*   batch= (const int*)d_in[2];
    const float* W1   = (const float*)d_in[3];
    const float* as1  = (const float*)d_in[4];
    const float* ad1  = (const float*)d_in[5];
    const float* b1   = (const float*)d_in[6];
    const float* W2   = (const float*)d_in[7];
    const float* as2  = (const float*)d_in[8];
    const float* ad2  = (const float*)d_in[9];
    const float* b2   = (const float*)d_in[10];
    const float* Wfc  = (const float*)d_in[11];
    const float* bfc  = (const float*)d_in[12];
    float* out = (float*)d_out;

    const int N = in_sizes[2];          // 50000 nodes
    const int E = in_sizes[1] / 27;     // 400000 edges
    const int F = in_sizes[0] / N;      // 128

    char* ws = (char*)d_ws;
    unsigned short* h1b   = (unsigned short*)(ws + OFF_H1B);
    unsigned short* h2b   = (unsigned short*)(ws + OFF_H2B);
    float*          out2  = (float*)(ws + OFF_OUT2);
    unsigned short* xhi   = (unsigned short*)(ws + OFF_XHI);
    unsigned short* xlo   = (unsigned short*)(ws + OFF_XLO);
    unsigned short* o1hi  = (unsigned short*)(ws + OFF_O1HI);
    unsigned short* w1th  = (unsigned short*)(ws + OFF_W1TH);
    unsigned short* w1tl  = (unsigned short*)(ws + OFF_W1TL);
    unsigned short* w2th  = (unsigned short*)(ws + OFF_W2TH);
    unsigned short* w2tl  = (unsigned short*)(ws + OFF_W2TL);
    float* al_s  = (float*)(ws + OFF_AS);
    float* al_d  = (float*)(ws + OFF_AD);
    int*   rp    = (int*)(ws + OFF_RP);     // (2N+1) entries; layer2 view = rp+N
    int*   cur   = (int*)(ws + OFF_CUR);    // 2N
    int*   cnt   = (int*)(ws + OFF_CNT);    // 2N
    int*   csr   = (int*)(ws + OFF_CSR);    // 2E (global positions)
    int*   bsum  = (int*)(ws + OFF_BSUM);

    const int e2grid8 = (2 * E + 2047) / 2048;     // 391 blocks (8 edges/thread)
    const int NB2     = (2 * N + 1023) / 1024;     // 98 blocks
    const int ZB      = ((2 * N / 4) + 255) / 256; // 98 zero-blocks in prep

    // ---- 1: fused prep (x split + W splits + cnt zero) ----
    prep_kernel<<<1216 + ZB, 256, 0, stream>>>(x, xhi, xlo, N * F / 4,
                                               W1, w1th, w1tl, W2, w2th, w2tl,
                                               cnt, 2 * N);

    // ---- 2-5: CSR build (count, scan, add+cursor, scatter) ----
    count2_kernel<<<e2grid8, 256, 0, stream>>>(ei + 26 * (size_t)E, ei + 16 * (size_t)E, cnt, N, E);
    scan_block_kernel<<<NB2, 1024, 0, stream>>>(cnt, rp, bsum, 2 * N);
    scan_add2_kernel<<<NB2, 1024, 0, stream>>>(bsum, rp, cur, 2 * N, NB2, 2 * E);
    scatter2_kernel<<<e2grid8, 256, 0, stream>>>(ei + 17 * (size_t)E, ei + 26 * (size_t)E,
                                                 ei + 15 * (size_t)E, ei + 16 * (size_t)E,
                                                 cur, csr, N, E);

    // ---- 6: layer-1 MFMA GEMM (split-bf16 A, 3-pass) -> bf16 h1 ----
    {
        dim3 g((N + 127) / 128, 2);
        mfma_gemm_gat<128, 128, 128, 2, 2, 64, true><<<g, 256, 0, stream>>>(
            xhi, xlo, w1th, w1tl, h1b, as1, ad1, al_s, al_d, N, HEADS * 64);
    }
    // ---- 7: layer-1 aggregation (writes bf16 hi only) ----
    gat_agg<256, 32><<<(N + 7) / 8, 256, 0, stream>>>(h1b, al_s, al_d, rp, csr, b1,
                                                      nullptr, o1hi, N);

    // ---- 8: layer-2 MFMA GEMM (bf16 A, 2-pass) -> bf16 h2 ----
    {
        dim3 g((N + 63) / 64, 1);
        mfma_gemm_gat<64, 64, 256, 2, 2, 16, false><<<g, 256, 0, stream>>>(
            o1hi, nullptr, w2th, w2tl, h2b, as2, ad2, al_s, al_d, N, HEADS * 16);
    }
    // ---- 9: layer-2 aggregation ----
    gat_agg<64, 16><<<(N + 15) / 16, 256, 0, stream>>>(h2b, al_s, al_d, rp + N, csr, b2,
                                                       out2, nullptr, N);

    // ---- 10: fused mean-pool + FC ----
    pool_fc_kernel<<<64, 256, 0, stream>>>(out2, batch, Wfc, bfc, out, N);
}

// Round 14
// 209.635 us; speedup vs baseline: 1.0775x; 1.0005x over previous
//
#include <hip/hip_runtime.h>
#include <math.h>

#define HEADS 4
#define NEG_SLOPE 0.2f

// ---------------- workspace layout (bytes) ----------------
static constexpr size_t OFF_H1B  = 0;
static constexpr size_t OFF_H2B  = 0;
static constexpr size_t OFF_OUT2 = 6400000;
static constexpr size_t OFF_XHI  = 25600000;
static constexpr size_t OFF_XLO  = 38400000;
static constexpr size_t OFF_O1HI = 25600000;   // aliases xhi/xlo (dead by then)
static constexpr size_t OFF_W1TH = 76800000;   // 256x128 bf16 = 64KB
static constexpr size_t OFF_W1TL = 76865536;
static constexpr size_t OFF_W2TH = 76931072;   // 64x256 bf16 = 32KB
static constexpr size_t OFF_W2TL = 76963840;
static constexpr size_t OFF_AS   = 77000000;   // 800,000
static constexpr size_t OFF_AD   = 77800000;   // 800,000
static constexpr size_t OFF_RP   = 78600064;   // (2N+1) ints
static constexpr size_t OFF_CUR  = 79000128;
static constexpr size_t OFF_CNT  = 79400128;
static constexpr size_t OFF_CSR  = 79800128;   // 2E ints
static constexpr size_t OFF_BSUM = 83000448;

typedef __attribute__((ext_vector_type(8))) short short8;
typedef __attribute__((ext_vector_type(4))) float f32x4;

// ---------------- helpers ----------------
__device__ __forceinline__ float4 f4add(float4 a, float4 b) {
    return make_float4(a.x + b.x, a.y + b.y, a.z + b.z, a.w + b.w);
}
__device__ __forceinline__ float lrelu(float x) { return x > 0.f ? x : NEG_SLOPE * x; }
__device__ __forceinline__ float4 f4lrelu(float4 a) {
    return make_float4(lrelu(a.x), lrelu(a.y), lrelu(a.z), lrelu(a.w));
}
__device__ __forceinline__ float4 f4exp(float4 a) {
    return make_float4(__expf(a.x), __expf(a.y), __expf(a.z), __expf(a.w));
}
__device__ __forceinline__ float pickh(float4 v, int head) {
    float r = v.x;
    r = head == 1 ? v.y : r;
    r = head == 2 ? v.z : r;
    r = head == 3 ? v.w : r;
    return r;
}
__device__ __forceinline__ unsigned short bfr(float x) {
    union { float f; unsigned u; } c; c.f = x;
    unsigned r = c.u + 0x7FFFu + ((c.u >> 16) & 1u);
    return (unsigned short)(r >> 16);
}
__device__ __forceinline__ float bf2f(unsigned short h) {
    union { unsigned u; float f; } c; c.u = ((unsigned)h) << 16;
    return c.f;
}
__device__ __forceinline__ float2 bfpair(unsigned u) {
    union { unsigned a; float f; } lo, hi;
    lo.a = u << 16;
    hi.a = u & 0xffff0000u;
    return make_float2(lo.f, hi.f);
}

// ---------------- fused prep: x-split + W1T/W2T-split + cnt zero ----------------
__global__ void prep_kernel(const float* __restrict__ x, unsigned short* __restrict__ xhi,
                            unsigned short* __restrict__ xlo, int n4,
                            const float* __restrict__ W1, unsigned short* __restrict__ w1th,
                            unsigned short* __restrict__ w1tl,
                            const float* __restrict__ W2, unsigned short* __restrict__ w2th,
                            unsigned short* __restrict__ w2tl,
                            int* __restrict__ cnt, int n2)
{
    const int b = blockIdx.x, t = threadIdx.x;
    if (b < 1024) {
        for (int i = b * 256 + t; i < n4; i += 1024 * 256) {
            float4 v = ((const float4*)x)[i];
            unsigned short h0 = bfr(v.x), h1 = bfr(v.y), h2 = bfr(v.z), h3 = bfr(v.w);
            unsigned short l0 = bfr(v.x - bf2f(h0)), l1 = bfr(v.y - bf2f(h1));
            unsigned short l2 = bfr(v.z - bf2f(h2)), l3 = bfr(v.w - bf2f(h3));
            ((uint2*)xhi)[i] = make_uint2((unsigned)h0 | ((unsigned)h1 << 16),
                                          (unsigned)h2 | ((unsigned)h3 << 16));
            ((uint2*)xlo)[i] = make_uint2((unsigned)l0 | ((unsigned)l1 << 16),
                                          (unsigned)l2 | ((unsigned)l3 << 16));
        }
    } else if (b < 1024 + 128) {
        int idx = (b - 1024) * 256 + t;          // W1: K=128, N=256
        const int K = 128, Nc = 256;
        int k = idx / Nc, n = idx - k * Nc;
        float v = W1[idx];
        unsigned short h = bfr(v);
        w1th[(size_t)n * K + k] = h;
        w1tl[(size_t)n * K + k] = bfr(v - bf2f(h));
    } else if (b < 1024 + 128 + 64) {
        int idx = (b - 1152) * 256 + t;          // W2: K=256, N=64
        const int K = 256, Nc = 64;
        int k = idx / Nc, n = idx - k * Nc;
        float v = W2[idx];
        unsigned short h = bfr(v);
        w2th[(size_t)n * K + k] = h;
        w2tl[(size_t)n * K + k] = bfr(v - bf2f(h));
    } else {
        int idx = (b - 1216) * 256 + t;          // zero cnt[2N] via int4
        if (idx < (n2 >> 2)) ((int4*)cnt)[idx] = make_int4(0, 0, 0, 0);
    }
}

// ---------------- fused 2-layer CSR build (4 edges/thread, 782 blocks) ----------
__global__ void count2_kernel(const int* __restrict__ dst1, const int* __restrict__ dst2,
                              int* __restrict__ counts, int N, int E)
{
    const int base = blockIdx.x * 1024 + threadIdx.x;
#pragma unroll
    for (int k = 0; k < 4; ++k) {
        int e = base + k * 256;
        if (e < E)          atomicAdd(&counts[dst1[e]], 1);
        else if (e < 2 * E) atomicAdd(&counts[N + dst2[e - E]], 1);
    }
}

__global__ void scatter2_kernel(const int* __restrict__ src1, const int* __restrict__ dst1,
                                const int* __restrict__ src2, const int* __restrict__ dst2,
                                int* __restrict__ cursor, int* __restrict__ csr, int N, int E)
{
    const int base = blockIdx.x * 1024 + threadIdx.x;
    int srcv[4], pos[4];
    bool valid[4];
#pragma unroll
    for (int k = 0; k < 4; ++k) {
        int e = base + k * 256;
        valid[k] = (e < 2 * E);
        srcv[k] = 0; pos[k] = 0;
        if (e < E) {
            srcv[k] = src1[e];
            pos[k]  = atomicAdd(&cursor[dst1[e]], 1);
        } else if (e < 2 * E) {
            srcv[k] = src2[e - E];
            pos[k]  = atomicAdd(&cursor[N + dst2[e - E]], 1);
        }
    }
#pragma unroll
    for (int k = 0; k < 4; ++k)
        if (valid[k]) csr[pos[k]] = srcv[k];
}

// ---------------- parallel scan (2 kernels) ----------------
__global__ __launch_bounds__(1024)
void scan_block_kernel(const int* __restrict__ counts, int* __restrict__ excl_out,
                       int* __restrict__ bsum, int n)
{
    __shared__ int wsum[16];
    const int t = threadIdx.x, lane = t & 63, w = t >> 6;
    const int i = blockIdx.x * 1024 + t;
    int v = (i < n) ? counts[i] : 0;
    int x = v;
#pragma unroll
    for (int d = 1; d < 64; d <<= 1) {
        int y = __shfl_up(x, d);
        if (lane >= d) x += y;
    }
    if (lane == 63) wsum[w] = x;
    __syncthreads();
    if (t < 16) {
        int s = wsum[t];
#pragma unroll
        for (int d = 1; d < 16; d <<= 1) {
            int y = __shfl_up(s, d);
            if (t >= d) s += y;
        }
        wsum[t] = s;
    }
    __syncthreads();
    int wbase = (w > 0) ? wsum[w - 1] : 0;
    if (i < n) excl_out[i] = wbase + x - v;
    if (t == 1023) bsum[blockIdx.x] = wsum[15];
}

// each block redundantly reduces bsum[0..nb) for its own offset
__global__ __launch_bounds__(1024)
void scan_add2_kernel(const int* __restrict__ bsum, int* __restrict__ row_ptr,
                      int* __restrict__ cursor, int n, int nb, int total)
{
    __shared__ int red[16];
    __shared__ int sboff;
    const int t = threadIdx.x, b = blockIdx.x;
    const int lane = t & 63, w = t >> 6;
    int vlt = (t < nb && t < b) ? bsum[t] : 0;
#pragma unroll
    for (int d = 32; d >= 1; d >>= 1) vlt += __shfl_xor(vlt, d);
    if (lane == 0) red[w] = vlt;
    __syncthreads();
    if (t == 0) {
        int a = 0;
#pragma unroll
        for (int k = 0; k < 16; ++k) a += red[k];
        sboff = a;
    }
    __syncthreads();
    const int i = b * 1024 + t;
    if (i < n) {
        int r = row_ptr[i] + sboff;
        row_ptr[i] = r;
        cursor[i]  = r;
    }
    if (b == 0 && t == 0) row_ptr[n] = total;
}

// ---------------- MFMA GEMM with GAT-alpha epilogue ----------------
// ALO=true: 3-pass split-bf16; ALO=false: plain bf16 A, 2-pass.
// C stored bf16, pairwise-packed: lanes lrow/lrow^1 hold adjacent columns;
// shfl_xor packs 2 bf16 -> one uint store by even lanes (halves store count).
template<int BM, int BN, int KDIM, int WR, int WC, int CPH, bool ALO>
__global__ __launch_bounds__(256, 2)
void mfma_gemm_gat(const unsigned short* __restrict__ Ahi, const unsigned short* __restrict__ Alo,
                   const unsigned short* __restrict__ BThi, const unsigned short* __restrict__ BTlo,
                   unsigned short* __restrict__ Cb,
                   const float* __restrict__ avec_s, const float* __restrict__ avec_d,
                   float* __restrict__ alpha_s, float* __restrict__ alpha_d,
                   int M, int N)
{
    constexpr int BK    = 32;
    constexpr int WROWS = BM / WR;
    constexpr int WCOLS = BN / WC;
    constexpr int FR    = WROWS / 16;
    constexpr int FC    = WCOLS / 16;
    constexpr int AP    = (BM * (BK / 8)) / 256;
    constexpr int BP    = (BN * (BK / 8)) / 256;
    static_assert(AP >= 1 && BP >= 1, "tile too small");

    __shared__ short As_hi[BM * BK], As_lo[ALO ? BM * BK : 64];
    __shared__ short Bs_hi[BN * BK], Bs_lo[BN * BK];

    const int tid  = threadIdx.x;
    const int w    = tid >> 6, lane = tid & 63;
    const int wr   = w / WC, wc = w % WC;
    const int lrow = lane & 15, lk = lane >> 4;
    const int m0   = blockIdx.x * BM, n0 = blockIdx.y * BN;

    f32x4 acc[FR][FC];
#pragma unroll
    for (int i = 0; i < FR; ++i)
#pragma unroll
        for (int j = 0; j < FC; ++j) acc[i][j] = (f32x4){0.f, 0.f, 0.f, 0.f};

    short8 rAh[AP], rAl[AP], rBh[BP], rBl[BP];

    auto LOAD = [&](int kb) {
#pragma unroll
        for (int p = 0; p < AP; ++p) {
            int id = p * 256 + tid;
            int r = id >> 2, c = id & 3;
            int row = m0 + r; row = row < M ? row : M - 1;
            size_t off = (size_t)row * KDIM + kb + c * 8;
            rAh[p] = *(const short8*)(Ahi + off);
            if constexpr (ALO) rAl[p] = *(const short8*)(Alo + off);
        }
#pragma unroll
        for (int p = 0; p < BP; ++p) {
            int id = p * 256 + tid;
            int r = id >> 2, c = id & 3;
            size_t off = (size_t)(n0 + r) * KDIM + kb + c * 8;
            rBh[p] = *(const short8*)(BThi + off);
            rBl[p] = *(const short8*)(BTlo + off);
        }
    };
    auto STORE = [&]() {
#pragma unroll
        for (int p = 0; p < AP; ++p) {
            int id = p * 256 + tid;
            int r = id >> 2, c = id & 3;
            *(short8*)(&As_hi[r * BK + c * 8]) = rAh[p];
            if constexpr (ALO) *(short8*)(&As_lo[r * BK + c * 8]) = rAl[p];
        }
#pragma unroll
        for (int p = 0; p < BP; ++p) {
            int id = p * 256 + tid;
            int r = id >> 2, c = id & 3;
            *(short8*)(&Bs_hi[r * BK + c * 8]) = rBh[p];
            *(short8*)(&Bs_lo[r * BK + c * 8]) = rBl[p];
        }
    };

    constexpr int NT = KDIM / BK;
    LOAD(0);
    for (int t = 0; t < NT; ++t) {
        STORE();
        __syncthreads();
        if (t + 1 < NT) LOAD((t + 1) * BK);

        short8 afh[FR], afl[FR], bfh[FC], bfl[FC];
#pragma unroll
        for (int fr = 0; fr < FR; ++fr) {
            int r = wr * WROWS + fr * 16 + lrow;
            afh[fr] = *(const short8*)(&As_hi[r * BK + lk * 8]);
            if constexpr (ALO) afl[fr] = *(const short8*)(&As_lo[r * BK + lk * 8]);
        }
#pragma unroll
        for (int fc = 0; fc < FC; ++fc) {
            int r = wc * WCOLS + fc * 16 + lrow;
            bfh[fc] = *(const short8*)(&Bs_hi[r * BK + lk * 8]);
            bfl[fc] = *(const short8*)(&Bs_lo[r * BK + lk * 8]);
        }
#pragma unroll
        for (int fr = 0; fr < FR; ++fr)
#pragma unroll
            for (int fc = 0; fc < FC; ++fc) {
                acc[fr][fc] = __builtin_amdgcn_mfma_f32_16x16x32_bf16(afh[fr], bfh[fc], acc[fr][fc], 0, 0, 0);
                acc[fr][fc] = __builtin_amdgcn_mfma_f32_16x16x32_bf16(afh[fr], bfl[fc], acc[fr][fc], 0, 0, 0);
                if constexpr (ALO)
                    acc[fr][fc] = __builtin_amdgcn_mfma_f32_16x16x32_bf16(afl[fr], bfh[fc], acc[fr][fc], 0, 0, 0);
            }
        __syncthreads();
    }

#pragma unroll
    for (int fr = 0; fr < FR; ++fr) {
        const int rbase = m0 + wr * WROWS + fr * 16 + lk * 4;
        float ps[4] = {0.f, 0.f, 0.f, 0.f}, pd[4] = {0.f, 0.f, 0.f, 0.f};
#pragma unroll
        for (int fc = 0; fc < FC; ++fc) {
            const int gc   = n0 + wc * WCOLS + fc * 16 + lrow;
            const int head = gc / CPH, ci = gc % CPH;
            const float asv = avec_s[head * CPH + ci];
            const float adv = avec_d[head * CPH + ci];
#pragma unroll
            for (int rg = 0; rg < 4; ++rg) {
                int row = rbase + rg;
                float v = acc[fr][fc][rg];
                unsigned short uh = bfr(v);
                unsigned up = (unsigned)__shfl_xor((int)(unsigned)uh, 1);
                if (!(lrow & 1) && row < M)
                    *(unsigned*)(Cb + (size_t)row * N + gc) = (unsigned)uh | (up << 16);
                ps[rg] += v * asv;
                pd[rg] += v * adv;
            }
            if constexpr (CPH == 16) {
#pragma unroll
                for (int rg = 0; rg < 4; ++rg) {
                    float s = ps[rg], d = pd[rg];
#pragma unroll
                    for (int m = 1; m <= 8; m <<= 1) {
                        s += __shfl_xor(s, m);
                        d += __shfl_xor(d, m);
                    }
                    if (lrow == 0 && rbase + rg < M) {
                        alpha_s[(size_t)(rbase + rg) * HEADS + head] = s;
                        alpha_d[(size_t)(rbase + rg) * HEADS + head] = d;
                    }
                    ps[rg] = 0.f; pd[rg] = 0.f;
                }
            }
        }
        if constexpr (CPH != 16) {
            const int head = (n0 + wc * WCOLS) / CPH;
#pragma unroll
            for (int rg = 0; rg < 4; ++rg) {
                float s = ps[rg], d = pd[rg];
#pragma unroll
                for (int m = 1; m <= 8; m <<= 1) {
                    s += __shfl_xor(s, m);
                    d += __shfl_xor(d, m);
                }
                if (lrow == 0 && rbase + rg < M) {
                    alpha_s[(size_t)(rbase + rg) * HEADS + head] = s;
                    alpha_d[(size_t)(rbase + rg) * HEADS + head] = d;
                }
            }
        }
    }
}

// ---------------- GAT softmax + aggregation ----------------
template<int CH, int S>
__global__ __launch_bounds__(256)
void gat_agg(const unsigned short* __restrict__ hb, const float* __restrict__ alpha_s,
             const float* __restrict__ alpha_d, const int* __restrict__ row_ptr,
             const int* __restrict__ csr_src, const float* __restrict__ bias,
             float* __restrict__ out, unsigned short* __restrict__ out_hi, int n)
{
    constexpr int CPL = CH / S;
    constexpr int NSG = 256 / S;
    __shared__ float wls[NSG][S * 5];
    const int tid    = threadIdx.x;
    const int sub    = tid / S;
    const int i      = tid % S;
    const int lane64 = tid & 63;
    const int base   = lane64 & ~(S - 1);
    const int node   = blockIdx.x * NSG + sub;
    if (node >= n) return;
    const int head = (i * CPL) / (CH / 4);
    const int p0 = row_ptr[node], p1 = row_ptr[node + 1];
    const int deg = p1 - p0;

    const float4 asn = *(const float4*)(alpha_s + (size_t)node * 4);
    const float4 adn = *(const float4*)(alpha_d + (size_t)node * 4);
    float4 den = f4exp(f4lrelu(f4add(asn, adn)));
    const float wse = pickh(den, head);

    float acc[CPL];
    if constexpr (CPL == 8) {
        uint4 hv = *(const uint4*)(hb + (size_t)node * CH + i * 8);
        float2 q0 = bfpair(hv.x), q1 = bfpair(hv.y), q2 = bfpair(hv.z), q3 = bfpair(hv.w);
        acc[0] = wse * q0.x; acc[1] = wse * q0.y; acc[2] = wse * q1.x; acc[3] = wse * q1.y;
        acc[4] = wse * q2.x; acc[5] = wse * q2.y; acc[6] = wse * q3.x; acc[7] = wse * q3.y;
    } else {
        uint2 hv = *(const uint2*)(hb + (size_t)node * CH + i * 4);
        float2 q0 = bfpair(hv.x), q1 = bfpair(hv.y);
        acc[0] = wse * q0.x; acc[1] = wse * q0.y; acc[2] = wse * q1.x; acc[3] = wse * q1.y;
    }

    for (int ch = 0; ch < deg; ch += S) {
        const int cnt = min(S, deg - ch);
        float4 w4 = make_float4(0.f, 0.f, 0.f, 0.f);
        int sl = 0;
        if (i < cnt) {
            sl = csr_src[p0 + ch + i];
            float4 al = *(const float4*)(alpha_s + (size_t)sl * 4);
            w4 = f4exp(f4lrelu(f4add(al, adn)));
        }
        float4 t = w4;
#pragma unroll
        for (int d = S / 2; d >= 1; d >>= 1) {
            t.x += __shfl_xor(t.x, d);
            t.y += __shfl_xor(t.y, d);
            t.z += __shfl_xor(t.z, d);
            t.w += __shfl_xor(t.w, d);
        }
        den = f4add(den, t);
        wls[sub][i * 5 + 0] = w4.x;
        wls[sub][i * 5 + 1] = w4.y;
        wls[sub][i * 5 + 2] = w4.z;
        wls[sub][i * 5 + 3] = w4.w;

        const int padded = (cnt + 7) & ~7;
        for (int j = 0; j < padded; j += 8) {
            int   sk[8];
            float wk[8];
#pragma unroll
            for (int k = 0; k < 8; ++k) {
                sk[k] = __shfl(sl, base + j + k);
                wk[k] = wls[sub][(j + k) * 5 + head];
            }
            if constexpr (CPL == 8) {
                uint4 v[8];
#pragma unroll
                for (int k = 0; k < 8; ++k)
                    v[k] = *(const uint4*)(hb + (size_t)sk[k] * CH + i * 8);
#pragma unroll
                for (int k = 0; k < 8; ++k) {
                    float2 q0 = bfpair(v[k].x), q1 = bfpair(v[k].y);
                    float2 q2 = bfpair(v[k].z), q3 = bfpair(v[k].w);
                    acc[0] += wk[k] * q0.x; acc[1] += wk[k] * q0.y;
                    acc[2] += wk[k] * q1.x; acc[3] += wk[k] * q1.y;
                    acc[4] += wk[k] * q2.x; acc[5] += wk[k] * q2.y;
                    acc[6] += wk[k] * q3.x; acc[7] += wk[k] * q3.y;
                }
            } else {
                uint2 v[8];
#pragma unroll
                for (int k = 0; k < 8; ++k)
                    v[k] = *(const uint2*)(hb + (size_t)sk[k] * CH + i * 4);
#pragma unroll
                for (int k = 0; k < 8; ++k) {
                    float2 q0 = bfpair(v[k].x), q1 = bfpair(v[k].y);
                    acc[0] += wk[k] * q0.x; acc[1] += wk[k] * q0.y;
                    acc[2] += wk[k] * q1.x; acc[3] += wk[k] * q1.y;
                }
            }
        }
    }

    const float invd = 1.0f / (pickh(den, head) + 1e-16f);
    const int c0 = i * CPL;
    if constexpr (CPL == 8) {
        float o[8];
        unsigned short oh[8];
#pragma unroll
        for (int k = 0; k < 8; ++k) {
            o[k] = fmaxf(acc[k] * invd + bias[c0 + k], 0.f);
            oh[k] = bfr(o[k]);
        }
        uint4 ph;
        ph.x = (unsigned)oh[0] | ((unsigned)oh[1] << 16);
        ph.y = (unsigned)oh[2] | ((unsigned)oh[3] << 16);
        ph.z = (unsigned)oh[4] | ((unsigned)oh[5] << 16);
        ph.w = (unsigned)oh[6] | ((unsigned)oh[7] << 16);
        *(uint4*)(out_hi + (size_t)node * CH + c0) = ph;
    } else {
        float4 o;
        o.x = fmaxf(acc[0] * invd + bias[c0 + 0], 0.f);
        o.y = fmaxf(acc[1] * invd + bias[c0 + 1], 0.f);
        o.z = fmaxf(acc[2] * invd + bias[c0 + 2], 0.f);
        o.w = fmaxf(acc[3] * invd + bias[c0 + 3], 0.f);
        *(float4*)(out + (size_t)node * CH + c0) = o;
    }
}

// ---------------- fused mean-pool/FC (per-block binary search) ----------------
__global__ __launch_bounds__(256)
void pool_fc_kernel(const float* __restrict__ feat, const int* __restrict__ batch,
                    const float* __restrict__ Wfc, const float* __restrict__ bfc,
                    float* __restrict__ out, int n)
{
    __shared__ float4 part[16][16];
    __shared__ float pooled[64];
    __shared__ int sb[2];
    const int g = blockIdx.x;
    const int t = threadIdx.x;
    if (t < 2) {
        int target = g + t;
        int lo = 0, hi = n;
        while (lo < hi) {
            int mid = (lo + hi) >> 1;
            if (batch[mid] < target) lo = mid + 1; else hi = mid;
        }
        sb[t] = lo;
    }
    __syncthreads();
    const int s0 = sb[0], s1 = sb[1];
    const int q = t & 15, ns = t >> 4;
    float4 acc = make_float4(0.f, 0.f, 0.f, 0.f);
    for (int i = s0 + ns; i < s1; i += 16)
        acc = f4add(acc, *(const float4*)(feat + (size_t)i * 64 + q * 4));
    part[ns][q] = acc;
    __syncthreads();
    if (t < 16) {
        float4 s = part[0][t];
#pragma unroll
        for (int k = 1; k < 16; ++k) s = f4add(s, part[k][t]);
        float inv = 1.0f / fmaxf((float)(s1 - s0), 1.0f);
        pooled[t * 4 + 0] = s.x * inv;
        pooled[t * 4 + 1] = s.y * inv;
        pooled[t * 4 + 2] = s.z * inv;
        pooled[t * 4 + 3] = s.w * inv;
    }
    __syncthreads();
    if (t < 2) {
        float a = bfc[t];
        for (int c = 0; c < 64; ++c) a += pooled[c] * Wfc[c * 2 + t];
        out[g * 2 + t] = a;
    }
}

// ---------------- launch ----------------
extern "C" void kernel_launch(void* const* d_in, const int* in_sizes, int n_in,
                              void* d_out, int out_size, void* d_ws, size_t ws_size,
                              hipStream_t stream)
{
    const float* x    = (const float*)d_in[0];
    const int*   ei   = (const int*)d_in[1];
    const int*   batch= (const int*)d_in[2];
    const float* W1   = (const float*)d_in[3];
    const float* as1  = (const float*)d_in[4];
    const float* ad1  = (const float*)d_in[5];
    const float* b1   = (const float*)d_in[6];
    const float* W2   = (const float*)d_in[7];
    const float* as2  = (const float*)d_in[8];
    const float* ad2  = (const float*)d_in[9];
    const float* b2   = (const float*)d_in[10];
    const float* Wfc  = (const float*)d_in[11];
    const float* bfc  = (const float*)d_in[12];
    float* out = (float*)d_out;

    const int N = in_sizes[2];          // 50000 nodes
    const int E = in_sizes[1] / 27;     // 400000 edges
    const int F = in_sizes[0] / N;      // 128

    char* ws = (char*)d_ws;
    unsigned short* h1b   = (unsigned short*)(ws + OFF_H1B);
    unsigned short* h2b   = (unsigned short*)(ws + OFF_H2B);
    float*          out2  = (float*)(ws + OFF_OUT2);
    unsigned short* xhi   = (unsigned short*)(ws + OFF_XHI);
    unsigned short* xlo   = (unsigned short*)(ws + OFF_XLO);
    unsigned short* o1hi  = (unsigned short*)(ws + OFF_O1HI);
    unsigned short* w1th  = (unsigned short*)(ws + OFF_W1TH);
    unsigned short* w1tl  = (unsigned short*)(ws + OFF_W1TL);
    unsigned short* w2th  = (unsigned short*)(ws + OFF_W2TH);
    unsigned short* w2tl  = (unsigned short*)(ws + OFF_W2TL);
    float* al_s  = (float*)(ws + OFF_AS);
    float* al_d  = (float*)(ws + OFF_AD);
    int*   rp    = (int*)(ws + OFF_RP);     // (2N+1) entries; layer2 view = rp+N
    int*   cur   = (int*)(ws + OFF_CUR);    // 2N
    int*   cnt   = (int*)(ws + OFF_CNT);    // 2N
    int*   csr   = (int*)(ws + OFF_CSR);    // 2E (global positions)
    int*   bsum  = (int*)(ws + OFF_BSUM);

    const int e2grid4 = (2 * E + 1023) / 1024;     // 782 blocks (4 edges/thread)
    const int NB2     = (2 * N + 1023) / 1024;     // 98 blocks
    const int ZB      = ((2 * N / 4) + 255) / 256; // 98 zero-blocks in prep

    // ---- 1: fused prep (x split + W splits + cnt zero) ----
    prep_kernel<<<1216 + ZB, 256, 0, stream>>>(x, xhi, xlo, N * F / 4,
                                               W1, w1th, w1tl, W2, w2th, w2tl,
                                               cnt, 2 * N);

    // ---- 2-5: CSR build (count, scan, add+cursor, scatter) ----
    count2_kernel<<<e2grid4, 256, 0, stream>>>(ei + 26 * (size_t)E, ei + 16 * (size_t)E, cnt, N, E);
    scan_block_kernel<<<NB2, 1024, 0, stream>>>(cnt, rp, bsum, 2 * N);
    scan_add2_kernel<<<NB2, 1024, 0, stream>>>(bsum, rp, cur, 2 * N, NB2, 2 * E);
    scatter2_kernel<<<e2grid4, 256, 0, stream>>>(ei + 17 * (size_t)E, ei + 26 * (size_t)E,
                                                 ei + 15 * (size_t)E, ei + 16 * (size_t)E,
                                                 cur, csr, N, E);

    // ---- 6: layer-1 MFMA GEMM (split-bf16 A, 3-pass, BM=64) -> bf16 h1 ----
    {
        dim3 g((N + 63) / 64, 2);
        mfma_gemm_gat<64, 128, 128, 2, 2, 64, true><<<g, 256, 0, stream>>>(
            xhi, xlo, w1th, w1tl, h1b, as1, ad1, al_s, al_d, N, HEADS * 64);
    }
    // ---- 7: layer-1 aggregation (writes bf16 hi only) ----
    gat_agg<256, 32><<<(N + 7) / 8, 256, 0, stream>>>(h1b, al_s, al_d, rp, csr, b1,
                                                      nullptr, o1hi, N);

    // ---- 8: layer-2 MFMA GEMM (bf16 A, 2-pass) -> bf16 h2 ----
    {
        dim3 g((N + 63) / 64, 1);
        mfma_gemm_gat<64, 64, 256, 2, 2, 16, false><<<g, 256, 0, stream>>>(
            o1hi, nullptr, w2th, w2tl, h2b, as2, ad2, al_s, al_d, N, HEADS * 16);
    }
    // ---- 9: layer-2 aggregation ----
    gat_agg<64, 16><<<(N + 15) / 16, 256, 0, stream>>>(h2b, al_s, al_d, rp + N, csr, b2,
                                                       out2, nullptr, N);

    // ---- 10: fused mean-pool + FC ----
    pool_fc_kernel<<<64, 256, 0, stream>>>(out2, batch, Wfc, bfc, out, N);
}

// Round 15
// 208.820 us; speedup vs baseline: 1.0817x; 1.0039x over previous
//
#include <hip/hip_runtime.h>
#include <math.h>

#define HEADS 4
#define NEG_SLOPE 0.2f

// ---------------- workspace layout (bytes) ----------------
static constexpr size_t OFF_H1B  = 0;
static constexpr size_t OFF_H2B  = 0;
static constexpr size_t OFF_OUT2 = 6400000;
static constexpr size_t OFF_XHI  = 25600000;
static constexpr size_t OFF_XLO  = 38400000;
static constexpr size_t OFF_O1HI = 25600000;   // aliases xhi/xlo (dead by then)
static constexpr size_t OFF_W1TH = 76800000;   // 256x128 bf16 = 64KB
static constexpr size_t OFF_W1TL = 76865536;
static constexpr size_t OFF_W2TH = 76931072;   // 64x256 bf16 = 32KB
static constexpr size_t OFF_W2TL = 76963840;
static constexpr size_t OFF_AS   = 77000000;   // 800,000
static constexpr size_t OFF_AD   = 77800000;   // 800,000
static constexpr size_t OFF_RP   = 78600064;   // (2N+1) ints
static constexpr size_t OFF_CUR  = 79000128;
static constexpr size_t OFF_CNT  = 79400128;
static constexpr size_t OFF_CSR  = 79800128;   // 2E ints
static constexpr size_t OFF_BSUM = 83000448;

typedef __attribute__((ext_vector_type(8))) short short8;
typedef __attribute__((ext_vector_type(4))) float f32x4;

// ---------------- helpers ----------------
__device__ __forceinline__ float4 f4add(float4 a, float4 b) {
    return make_float4(a.x + b.x, a.y + b.y, a.z + b.z, a.w + b.w);
}
__device__ __forceinline__ float lrelu(float x) { return x > 0.f ? x : NEG_SLOPE * x; }
__device__ __forceinline__ float4 f4lrelu(float4 a) {
    return make_float4(lrelu(a.x), lrelu(a.y), lrelu(a.z), lrelu(a.w));
}
__device__ __forceinline__ float4 f4exp(float4 a) {
    return make_float4(__expf(a.x), __expf(a.y), __expf(a.z), __expf(a.w));
}
__device__ __forceinline__ float pickh(float4 v, int head) {
    float r = v.x;
    r = head == 1 ? v.y : r;
    r = head == 2 ? v.z : r;
    r = head == 3 ? v.w : r;
    return r;
}
__device__ __forceinline__ unsigned short bfr(float x) {
    union { float f; unsigned u; } c; c.f = x;
    unsigned r = c.u + 0x7FFFu + ((c.u >> 16) & 1u);
    return (unsigned short)(r >> 16);
}
__device__ __forceinline__ float bf2f(unsigned short h) {
    union { unsigned u; float f; } c; c.u = ((unsigned)h) << 16;
    return c.f;
}
__device__ __forceinline__ float2 bfpair(unsigned u) {
    union { unsigned a; float f; } lo, hi;
    lo.a = u << 16;
    hi.a = u & 0xffff0000u;
    return make_float2(lo.f, hi.f);
}

// ---------------- fused prep: x-split + W1T/W2T-split + cnt zero ----------------
__global__ void prep_kernel(const float* __restrict__ x, unsigned short* __restrict__ xhi,
                            unsigned short* __restrict__ xlo, int n4,
                            const float* __restrict__ W1, unsigned short* __restrict__ w1th,
                            unsigned short* __restrict__ w1tl,
                            const float* __restrict__ W2, unsigned short* __restrict__ w2th,
                            unsigned short* __restrict__ w2tl,
                            int* __restrict__ cnt, int n2)
{
    const int b = blockIdx.x, t = threadIdx.x;
    if (b < 1024) {
        for (int i = b * 256 + t; i < n4; i += 1024 * 256) {
            float4 v = ((const float4*)x)[i];
            unsigned short h0 = bfr(v.x), h1 = bfr(v.y), h2 = bfr(v.z), h3 = bfr(v.w);
            unsigned short l0 = bfr(v.x - bf2f(h0)), l1 = bfr(v.y - bf2f(h1));
            unsigned short l2 = bfr(v.z - bf2f(h2)), l3 = bfr(v.w - bf2f(h3));
            ((uint2*)xhi)[i] = make_uint2((unsigned)h0 | ((unsigned)h1 << 16),
                                          (unsigned)h2 | ((unsigned)h3 << 16));
            ((uint2*)xlo)[i] = make_uint2((unsigned)l0 | ((unsigned)l1 << 16),
                                          (unsigned)l2 | ((unsigned)l3 << 16));
        }
    } else if (b < 1024 + 128) {
        int idx = (b - 1024) * 256 + t;          // W1: K=128, N=256
        const int K = 128, Nc = 256;
        int k = idx / Nc, n = idx - k * Nc;
        float v = W1[idx];
        unsigned short h = bfr(v);
        w1th[(size_t)n * K + k] = h;
        w1tl[(size_t)n * K + k] = bfr(v - bf2f(h));
    } else if (b < 1024 + 128 + 64) {
        int idx = (b - 1152) * 256 + t;          // W2: K=256, N=64
        const int K = 256, Nc = 64;
        int k = idx / Nc, n = idx - k * Nc;
        float v = W2[idx];
        unsigned short h = bfr(v);
        w2th[(size_t)n * K + k] = h;
        w2tl[(size_t)n * K + k] = bfr(v - bf2f(h));
    } else {
        int idx = (b - 1216) * 256 + t;          // zero cnt[2N] via int4
        if (idx < (n2 >> 2)) ((int4*)cnt)[idx] = make_int4(0, 0, 0, 0);
    }
}

// ---------------- fused 2-layer CSR build (4 edges/thread, 782 blocks) ----------
__global__ void count2_kernel(const int* __restrict__ dst1, const int* __restrict__ dst2,
                              int* __restrict__ counts, int N, int E)
{
    const int base = blockIdx.x * 1024 + threadIdx.x;
#pragma unroll
    for (int k = 0; k < 4; ++k) {
        int e = base + k * 256;
        if (e < E)          atomicAdd(&counts[dst1[e]], 1);
        else if (e < 2 * E) atomicAdd(&counts[N + dst2[e - E]], 1);
    }
}

__global__ void scatter2_kernel(const int* __restrict__ src1, const int* __restrict__ dst1,
                                const int* __restrict__ src2, const int* __restrict__ dst2,
                                int* __restrict__ cursor, int* __restrict__ csr, int N, int E)
{
    const int base = blockIdx.x * 1024 + threadIdx.x;
    int srcv[4], pos[4];
    bool valid[4];
#pragma unroll
    for (int k = 0; k < 4; ++k) {
        int e = base + k * 256;
        valid[k] = (e < 2 * E);
        srcv[k] = 0; pos[k] = 0;
        if (e < E) {
            srcv[k] = src1[e];
            pos[k]  = atomicAdd(&cursor[dst1[e]], 1);
        } else if (e < 2 * E) {
            srcv[k] = src2[e - E];
            pos[k]  = atomicAdd(&cursor[N + dst2[e - E]], 1);
        }
    }
#pragma unroll
    for (int k = 0; k < 4; ++k)
        if (valid[k]) csr[pos[k]] = srcv[k];
}

// ---------------- parallel scan (2 kernels) ----------------
__global__ __launch_bounds__(1024)
void scan_block_kernel(const int* __restrict__ counts, int* __restrict__ excl_out,
                       int* __restrict__ bsum, int n)
{
    __shared__ int wsum[16];
    const int t = threadIdx.x, lane = t & 63, w = t >> 6;
    const int i = blockIdx.x * 1024 + t;
    int v = (i < n) ? counts[i] : 0;
    int x = v;
#pragma unroll
    for (int d = 1; d < 64; d <<= 1) {
        int y = __shfl_up(x, d);
        if (lane >= d) x += y;
    }
    if (lane == 63) wsum[w] = x;
    __syncthreads();
    if (t < 16) {
        int s = wsum[t];
#pragma unroll
        for (int d = 1; d < 16; d <<= 1) {
            int y = __shfl_up(s, d);
            if (t >= d) s += y;
        }
        wsum[t] = s;
    }
    __syncthreads();
    int wbase = (w > 0) ? wsum[w - 1] : 0;
    if (i < n) excl_out[i] = wbase + x - v;
    if (t == 1023) bsum[blockIdx.x] = wsum[15];
}

// each block redundantly reduces bsum[0..nb) for its own offset
__global__ __launch_bounds__(1024)
void scan_add2_kernel(const int* __restrict__ bsum, int* __restrict__ row_ptr,
                      int* __restrict__ cursor, int n, int nb, int total)
{
    __shared__ int red[16];
    __shared__ int sboff;
    const int t = threadIdx.x, b = blockIdx.x;
    const int lane = t & 63, w = t >> 6;
    int vlt = (t < nb && t < b) ? bsum[t] : 0;
#pragma unroll
    for (int d = 32; d >= 1; d >>= 1) vlt += __shfl_xor(vlt, d);
    if (lane == 0) red[w] = vlt;
    __syncthreads();
    if (t == 0) {
        int a = 0;
#pragma unroll
        for (int k = 0; k < 16; ++k) a += red[k];
        sboff = a;
    }
    __syncthreads();
    const int i = b * 1024 + t;
    if (i < n) {
        int r = row_ptr[i] + sboff;
        row_ptr[i] = r;
        cursor[i]  = r;
    }
    if (b == 0 && t == 0) row_ptr[n] = total;
}

// ---------------- MFMA GEMM with GAT-alpha epilogue ----------------
// ALO=true: 3-pass split-bf16; ALO=false: plain bf16 A, 2-pass.
// C stored bf16, pairwise-packed via shfl_xor (even lanes store 4B).
template<int BM, int BN, int KDIM, int WR, int WC, int CPH, bool ALO>
__global__ __launch_bounds__(256, 2)
void mfma_gemm_gat(const unsigned short* __restrict__ Ahi, const unsigned short* __restrict__ Alo,
                   const unsigned short* __restrict__ BThi, const unsigned short* __restrict__ BTlo,
                   unsigned short* __restrict__ Cb,
                   const float* __restrict__ avec_s, const float* __restrict__ avec_d,
                   float* __restrict__ alpha_s, float* __restrict__ alpha_d,
                   int M, int N)
{
    constexpr int BK    = 32;
    constexpr int WROWS = BM / WR;
    constexpr int WCOLS = BN / WC;
    constexpr int FR    = WROWS / 16;
    constexpr int FC    = WCOLS / 16;
    constexpr int AP    = (BM * (BK / 8)) / 256;
    constexpr int BP    = (BN * (BK / 8)) / 256;
    static_assert(AP >= 1 && BP >= 1, "tile too small");

    __shared__ short As_hi[BM * BK], As_lo[ALO ? BM * BK : 64];
    __shared__ short Bs_hi[BN * BK], Bs_lo[BN * BK];

    const int tid  = threadIdx.x;
    const int w    = tid >> 6, lane = tid & 63;
    const int wr   = w / WC, wc = w % WC;
    const int lrow = lane & 15, lk = lane >> 4;
    const int m0   = blockIdx.x * BM, n0 = blockIdx.y * BN;

    f32x4 acc[FR][FC];
#pragma unroll
    for (int i = 0; i < FR; ++i)
#pragma unroll
        for (int j = 0; j < FC; ++j) acc[i][j] = (f32x4){0.f, 0.f, 0.f, 0.f};

    short8 rAh[AP], rAl[AP], rBh[BP], rBl[BP];

    auto LOAD = [&](int kb) {
#pragma unroll
        for (int p = 0; p < AP; ++p) {
            int id = p * 256 + tid;
            int r = id >> 2, c = id & 3;
            int row = m0 + r; row = row < M ? row : M - 1;
            size_t off = (size_t)row * KDIM + kb + c * 8;
            rAh[p] = *(const short8*)(Ahi + off);
            if constexpr (ALO) rAl[p] = *(const short8*)(Alo + off);
        }
#pragma unroll
        for (int p = 0; p < BP; ++p) {
            int id = p * 256 + tid;
            int r = id >> 2, c = id & 3;
            size_t off = (size_t)(n0 + r) * KDIM + kb + c * 8;
            rBh[p] = *(const short8*)(BThi + off);
            rBl[p] = *(const short8*)(BTlo + off);
        }
    };
    auto STORE = [&]() {
#pragma unroll
        for (int p = 0; p < AP; ++p) {
            int id = p * 256 + tid;
            int r = id >> 2, c = id & 3;
            *(short8*)(&As_hi[r * BK + c * 8]) = rAh[p];
            if constexpr (ALO) *(short8*)(&As_lo[r * BK + c * 8]) = rAl[p];
        }
#pragma unroll
        for (int p = 0; p < BP; ++p) {
            int id = p * 256 + tid;
            int r = id >> 2, c = id & 3;
            *(short8*)(&Bs_hi[r * BK + c * 8]) = rBh[p];
            *(short8*)(&Bs_lo[r * BK + c * 8]) = rBl[p];
        }
    };

    constexpr int NT = KDIM / BK;
    LOAD(0);
    for (int t = 0; t < NT; ++t) {
        STORE();
        __syncthreads();
        if (t + 1 < NT) LOAD((t + 1) * BK);

        short8 afh[FR], afl[FR], bfh[FC], bfl[FC];
#pragma unroll
        for (int fr = 0; fr < FR; ++fr) {
            int r = wr * WROWS + fr * 16 + lrow;
            afh[fr] = *(const short8*)(&As_hi[r * BK + lk * 8]);
            if constexpr (ALO) afl[fr] = *(const short8*)(&As_lo[r * BK + lk * 8]);
        }
#pragma unroll
        for (int fc = 0; fc < FC; ++fc) {
            int r = wc * WCOLS + fc * 16 + lrow;
            bfh[fc] = *(const short8*)(&Bs_hi[r * BK + lk * 8]);
            bfl[fc] = *(const short8*)(&Bs_lo[r * BK + lk * 8]);
        }
#pragma unroll
        for (int fr = 0; fr < FR; ++fr)
#pragma unroll
            for (int fc = 0; fc < FC; ++fc) {
                acc[fr][fc] = __builtin_amdgcn_mfma_f32_16x16x32_bf16(afh[fr], bfh[fc], acc[fr][fc], 0, 0, 0);
                acc[fr][fc] = __builtin_amdgcn_mfma_f32_16x16x32_bf16(afh[fr], bfl[fc], acc[fr][fc], 0, 0, 0);
                if constexpr (ALO)
                    acc[fr][fc] = __builtin_amdgcn_mfma_f32_16x16x32_bf16(afl[fr], bfh[fc], acc[fr][fc], 0, 0, 0);
            }
        __syncthreads();
    }

#pragma unroll
    for (int fr = 0; fr < FR; ++fr) {
        const int rbase = m0 + wr * WROWS + fr * 16 + lk * 4;
        float ps[4] = {0.f, 0.f, 0.f, 0.f}, pd[4] = {0.f, 0.f, 0.f, 0.f};
#pragma unroll
        for (int fc = 0; fc < FC; ++fc) {
            const int gc   = n0 + wc * WCOLS + fc * 16 + lrow;
            const int head = gc / CPH, ci = gc % CPH;
            const float asv = avec_s[head * CPH + ci];
            const float adv = avec_d[head * CPH + ci];
#pragma unroll
            for (int rg = 0; rg < 4; ++rg) {
                int row = rbase + rg;
                float v = acc[fr][fc][rg];
                unsigned short uh = bfr(v);
                unsigned up = (unsigned)__shfl_xor((int)(unsigned)uh, 1);
                if (!(lrow & 1) && row < M)
                    *(unsigned*)(Cb + (size_t)row * N + gc) = (unsigned)uh | (up << 16);
                ps[rg] += v * asv;
                pd[rg] += v * adv;
            }
            if constexpr (CPH == 16) {
#pragma unroll
                for (int rg = 0; rg < 4; ++rg) {
                    float s = ps[rg], d = pd[rg];
#pragma unroll
                    for (int m = 1; m <= 8; m <<= 1) {
                        s += __shfl_xor(s, m);
                        d += __shfl_xor(d, m);
                    }
                    if (lrow == 0 && rbase + rg < M) {
                        alpha_s[(size_t)(rbase + rg) * HEADS + head] = s;
                        alpha_d[(size_t)(rbase + rg) * HEADS + head] = d;
                    }
                    ps[rg] = 0.f; pd[rg] = 0.f;
                }
            }
        }
        if constexpr (CPH != 16) {
            const int head = (n0 + wc * WCOLS) / CPH;
#pragma unroll
            for (int rg = 0; rg < 4; ++rg) {
                float s = ps[rg], d = pd[rg];
#pragma unroll
                for (int m = 1; m <= 8; m <<= 1) {
                    s += __shfl_xor(s, m);
                    d += __shfl_xor(d, m);
                }
                if (lrow == 0 && rbase + rg < M) {
                    alpha_s[(size_t)(rbase + rg) * HEADS + head] = s;
                    alpha_d[(size_t)(rbase + rg) * HEADS + head] = d;
                }
            }
        }
    }
}

// ---------------- GAT softmax + aggregation ----------------
// S lanes per node (subgroup), CPL = CH/S = 8 always: every lane gathers one
// 16B uint4. 8-deep unrolled gather with zero-weight padding.
// OUTF32=false: write bf16 hi (layer 1); OUTF32=true: write f32 (layer 2).
template<int CH, int S, bool OUTF32>
__global__ __launch_bounds__(256)
void gat_agg(const unsigned short* __restrict__ hb, const float* __restrict__ alpha_s,
             const float* __restrict__ alpha_d, const int* __restrict__ row_ptr,
             const int* __restrict__ csr_src, const float* __restrict__ bias,
             float* __restrict__ out, unsigned short* __restrict__ out_hi, int n)
{
    constexpr int CPL = CH / S;
    constexpr int NSG = 256 / S;
    static_assert(CPL == 8, "lane owns one uint4");
    __shared__ float wls[NSG][S * 5];
    const int tid    = threadIdx.x;
    const int sub    = tid / S;
    const int i      = tid % S;
    const int lane64 = tid & 63;
    const int base   = lane64 & ~(S - 1);
    const int node   = blockIdx.x * NSG + sub;
    if (node >= n) return;
    const int head = (i * CPL) / (CH / 4);
    const int p0 = row_ptr[node], p1 = row_ptr[node + 1];
    const int deg = p1 - p0;

    const float4 asn = *(const float4*)(alpha_s + (size_t)node * 4);
    const float4 adn = *(const float4*)(alpha_d + (size_t)node * 4);
    float4 den = f4exp(f4lrelu(f4add(asn, adn)));
    const float wse = pickh(den, head);

    float acc[8];
    {
        uint4 hv = *(const uint4*)(hb + (size_t)node * CH + i * 8);
        float2 q0 = bfpair(hv.x), q1 = bfpair(hv.y), q2 = bfpair(hv.z), q3 = bfpair(hv.w);
        acc[0] = wse * q0.x; acc[1] = wse * q0.y; acc[2] = wse * q1.x; acc[3] = wse * q1.y;
        acc[4] = wse * q2.x; acc[5] = wse * q2.y; acc[6] = wse * q3.x; acc[7] = wse * q3.y;
    }

    for (int ch = 0; ch < deg; ch += S) {
        const int cnt = min(S, deg - ch);
        float4 w4 = make_float4(0.f, 0.f, 0.f, 0.f);
        int sl = 0;
        if (i < cnt) {
            sl = csr_src[p0 + ch + i];
            float4 al = *(const float4*)(alpha_s + (size_t)sl * 4);
            w4 = f4exp(f4lrelu(f4add(al, adn)));
        }
        float4 t = w4;
#pragma unroll
        for (int d = S / 2; d >= 1; d >>= 1) {
            t.x += __shfl_xor(t.x, d);
            t.y += __shfl_xor(t.y, d);
            t.z += __shfl_xor(t.z, d);
            t.w += __shfl_xor(t.w, d);
        }
        den = f4add(den, t);
        wls[sub][i * 5 + 0] = w4.x;
        wls[sub][i * 5 + 1] = w4.y;
        wls[sub][i * 5 + 2] = w4.z;
        wls[sub][i * 5 + 3] = w4.w;

        const int padded = (cnt + 7) & ~7;
        for (int j = 0; j < padded; j += 8) {
            int   sk[8];
            float wk[8];
#pragma unroll
            for (int k = 0; k < 8; ++k) {
                sk[k] = __shfl(sl, base + ((j + k) < S ? (j + k) : 0));
                wk[k] = wls[sub][(j + k) * 5 + head];
            }
            uint4 v[8];
#pragma unroll
            for (int k = 0; k < 8; ++k)
                v[k] = *(const uint4*)(hb + (size_t)sk[k] * CH + i * 8);
#pragma unroll
            for (int k = 0; k < 8; ++k) {
                float2 q0 = bfpair(v[k].x), q1 = bfpair(v[k].y);
                float2 q2 = bfpair(v[k].z), q3 = bfpair(v[k].w);
                acc[0] += wk[k] * q0.x; acc[1] += wk[k] * q0.y;
                acc[2] += wk[k] * q1.x; acc[3] += wk[k] * q1.y;
                acc[4] += wk[k] * q2.x; acc[5] += wk[k] * q2.y;
                acc[6] += wk[k] * q3.x; acc[7] += wk[k] * q3.y;
            }
        }
    }

    const float invd = 1.0f / (pickh(den, head) + 1e-16f);
    const int c0 = i * CPL;
    float o[8];
#pragma unroll
    for (int k = 0; k < 8; ++k)
        o[k] = fmaxf(acc[k] * invd + bias[c0 + k], 0.f);
    if constexpr (OUTF32) {
        *(float4*)(out + (size_t)node * CH + c0)     = make_float4(o[0], o[1], o[2], o[3]);
        *(float4*)(out + (size_t)node * CH + c0 + 4) = make_float4(o[4], o[5], o[6], o[7]);
    } else {
        unsigned short oh[8];
#pragma unroll
        for (int k = 0; k < 8; ++k) oh[k] = bfr(o[k]);
        uint4 ph;
        ph.x = (unsigned)oh[0] | ((unsigned)oh[1] << 16);
        ph.y = (unsigned)oh[2] | ((unsigned)oh[3] << 16);
        ph.z = (unsigned)oh[4] | ((unsigned)oh[5] << 16);
        ph.w = (unsigned)oh[6] | ((unsigned)oh[7] << 16);
        *(uint4*)(out_hi + (size_t)node * CH + c0) = ph;
    }
}

// ---------------- fused mean-pool/FC (per-block binary search) ----------------
__global__ __launch_bounds__(256)
void pool_fc_kernel(const float* __restrict__ feat, const int* __restrict__ batch,
                    const float* __restrict__ Wfc, const float* __restrict__ bfc,
                    float* __restrict__ out, int n)
{
    __shared__ float4 part[16][16];
    __shared__ float pooled[64];
    __shared__ int sb[2];
    const int g = blockIdx.x;
    const int t = threadIdx.x;
    if (t < 2) {
        int target = g + t;
        int lo = 0, hi = n;
        while (lo < hi) {
            int mid = (lo + hi) >> 1;
            if (batch[mid] < target) lo = mid + 1; else hi = mid;
        }
        sb[t] = lo;
    }
    __syncthreads();
    const int s0 = sb[0], s1 = sb[1];
    const int q = t & 15, ns = t >> 4;
    float4 acc = make_float4(0.f, 0.f, 0.f, 0.f);
    for (int i = s0 + ns; i < s1; i += 16)
        acc = f4add(acc, *(const float4*)(feat + (size_t)i * 64 + q * 4));
    part[ns][q] = acc;
    __syncthreads();
    if (t < 16) {
        float4 s = part[0][t];
#pragma unroll
        for (int k = 1; k < 16; ++k) s = f4add(s, part[k][t]);
        float inv = 1.0f / fmaxf((float)(s1 - s0), 1.0f);
        pooled[t * 4 + 0] = s.x * inv;
        pooled[t * 4 + 1] = s.y * inv;
        pooled[t * 4 + 2] = s.z * inv;
        pooled[t * 4 + 3] = s.w * inv;
    }
    __syncthreads();
    if (t < 2) {
        float a = bfc[t];
        for (int c = 0; c < 64; ++c) a += pooled[c] * Wfc[c * 2 + t];
        out[g * 2 + t] = a;
    }
}

// ---------------- launch ----------------
extern "C" void kernel_launch(void* const* d_in, const int* in_sizes, int n_in,
                              void* d_out, int out_size, void* d_ws, size_t ws_size,
                              hipStream_t stream)
{
    const float* x    = (const float*)d_in[0];
    const int*   ei   = (const int*)d_in[1];
    const int*   batch= (const int*)d_in[2];
    const float* W1   = (const float*)d_in[3];
    const float* as1  = (const float*)d_in[4];
    const float* ad1  = (const float*)d_in[5];
    const float* b1   = (const float*)d_in[6];
    const float* W2   = (const float*)d_in[7];
    const float* as2  = (const float*)d_in[8];
    const float* ad2  = (const float*)d_in[9];
    const float* b2   = (const float*)d_in[10];
    const float* Wfc  = (const float*)d_in[11];
    const float* bfc  = (const float*)d_in[12];
    float* out = (float*)d_out;

    const int N = in_sizes[2];          // 50000 nodes
    const int E = in_sizes[1] / 27;     // 400000 edges
    const int F = in_sizes[0] / N;      // 128

    char* ws = (char*)d_ws;
    unsigned short* h1b   = (unsigned short*)(ws + OFF_H1B);
    unsigned short* h2b   = (unsigned short*)(ws + OFF_H2B);
    float*          out2  = (float*)(ws + OFF_OUT2);
    unsigned short* xhi   = (unsigned short*)(ws + OFF_XHI);
    unsigned short* xlo   = (unsigned short*)(ws + OFF_XLO);
    unsigned short* o1hi  = (unsigned short*)(ws + OFF_O1HI);
    unsigned short* w1th  = (unsigned short*)(ws + OFF_W1TH);
    unsigned short* w1tl  = (unsigned short*)(ws + OFF_W1TL);
    unsigned short* w2th  = (unsigned short*)(ws + OFF_W2TH);
    unsigned short* w2tl  = (unsigned short*)(ws + OFF_W2TL);
    float* al_s  = (float*)(ws + OFF_AS);
    float* al_d  = (float*)(ws + OFF_AD);
    int*   rp    = (int*)(ws + OFF_RP);     // (2N+1) entries; layer2 view = rp+N
    int*   cur   = (int*)(ws + OFF_CUR);    // 2N
    int*   cnt   = (int*)(ws + OFF_CNT);    // 2N
    int*   csr   = (int*)(ws + OFF_CSR);    // 2E (global positions)
    int*   bsum  = (int*)(ws + OFF_BSUM);

    const int e2grid4 = (2 * E + 1023) / 1024;     // 782 blocks (4 edges/thread)
    const int NB2     = (2 * N + 1023) / 1024;     // 98 blocks
    const int ZB      = ((2 * N / 4) + 255) / 256; // 98 zero-blocks in prep

    // ---- 1: fused prep (x split + W splits + cnt zero) ----
    prep_kernel<<<1216 + ZB, 256, 0, stream>>>(x, xhi, xlo, N * F / 4,
                                               W1, w1th, w1tl, W2, w2th, w2tl,
                                               cnt, 2 * N);

    // ---- 2-5: CSR build (count, scan, add+cursor, scatter) ----
    count2_kernel<<<e2grid4, 256, 0, stream>>>(ei + 26 * (size_t)E, ei + 16 * (size_t)E, cnt, N, E);
    scan_block_kernel<<<NB2, 1024, 0, stream>>>(cnt, rp, bsum, 2 * N);
    scan_add2_kernel<<<NB2, 1024, 0, stream>>>(bsum, rp, cur, 2 * N, NB2, 2 * E);
    scatter2_kernel<<<e2grid4, 256, 0, stream>>>(ei + 17 * (size_t)E, ei + 26 * (size_t)E,
                                                 ei + 15 * (size_t)E, ei + 16 * (size_t)E,
                                                 cur, csr, N, E);

    // ---- 6: layer-1 MFMA GEMM (split-bf16 A, 3-pass, BM=64) -> bf16 h1 ----
    {
        dim3 g((N + 63) / 64, 2);
        mfma_gemm_gat<64, 128, 128, 2, 2, 64, true><<<g, 256, 0, stream>>>(
            xhi, xlo, w1th, w1tl, h1b, as1, ad1, al_s, al_d, N, HEADS * 64);
    }
    // ---- 7: layer-1 aggregation (S=32, bf16 hi out) ----
    gat_agg<256, 32, false><<<(N + 7) / 8, 256, 0, stream>>>(h1b, al_s, al_d, rp, csr, b1,
                                                             nullptr, o1hi, N);

    // ---- 8: layer-2 MFMA GEMM (bf16 A, 2-pass) -> bf16 h2 ----
    {
        dim3 g((N + 63) / 64, 1);
        mfma_gemm_gat<64, 64, 256, 2, 2, 16, false><<<g, 256, 0, stream>>>(
            o1hi, nullptr, w2th, w2tl, h2b, as2, ad2, al_s, al_d, N, HEADS * 16);
    }
    // ---- 9: layer-2 aggregation (S=8, 16B gathers, f32 out) ----
    gat_agg<64, 8, true><<<(N + 31) / 32, 256, 0, stream>>>(h2b, al_s, al_d, rp + N, csr, b2,
                                                            out2, nullptr, N);

    // ---- 10: fused mean-pool + FC ----
    pool_fc_kernel<<<64, 256, 0, stream>>>(out2, batch, Wfc, bfc, out, N);
}

// Round 16
// 170.420 us; speedup vs baseline: 1.3255x; 1.2253x over previous
//
#include <hip/hip_runtime.h>
#include <math.h>

#define HEADS 4
#define NEG_SLOPE 0.2f
#define CAP 64   // bucket capacity per node (avg in-degree 8, Poisson tail << 1e-9)

// ---------------- workspace layout (bytes) ----------------
static constexpr size_t OFF_H1B  = 0;
static constexpr size_t OFF_H2B  = 0;
static constexpr size_t OFF_OUT2 = 6400000;
static constexpr size_t OFF_XHI  = 25600000;
static constexpr size_t OFF_XLO  = 38400000;
static constexpr size_t OFF_O1HI = 25600000;   // aliases xhi/xlo (dead by then)
static constexpr size_t OFF_W1TH = 76800000;   // 256x128 bf16 = 64KB
static constexpr size_t OFF_W1TL = 76865536;
static constexpr size_t OFF_W2TH = 76931072;   // 64x256 bf16 = 32KB
static constexpr size_t OFF_W2TL = 76963840;
static constexpr size_t OFF_AS   = 77000000;   // 800,000
static constexpr size_t OFF_AD   = 77800000;   // 800,000
static constexpr size_t OFF_CNT  = 78600064;   // 2N ints
static constexpr size_t OFF_CSR  = 79000128;   // 2N*CAP ints = 25.6 MB

typedef __attribute__((ext_vector_type(8))) short short8;
typedef __attribute__((ext_vector_type(4))) float f32x4;

// ---------------- helpers ----------------
__device__ __forceinline__ float4 f4add(float4 a, float4 b) {
    return make_float4(a.x + b.x, a.y + b.y, a.z + b.z, a.w + b.w);
}
__device__ __forceinline__ float lrelu(float x) { return x > 0.f ? x : NEG_SLOPE * x; }
__device__ __forceinline__ float4 f4lrelu(float4 a) {
    return make_float4(lrelu(a.x), lrelu(a.y), lrelu(a.z), lrelu(a.w));
}
__device__ __forceinline__ float4 f4exp(float4 a) {
    return make_float4(__expf(a.x), __expf(a.y), __expf(a.z), __expf(a.w));
}
__device__ __forceinline__ float pickh(float4 v, int head) {
    float r = v.x;
    r = head == 1 ? v.y : r;
    r = head == 2 ? v.z : r;
    r = head == 3 ? v.w : r;
    return r;
}
__device__ __forceinline__ unsigned short bfr(float x) {
    union { float f; unsigned u; } c; c.f = x;
    unsigned r = c.u + 0x7FFFu + ((c.u >> 16) & 1u);
    return (unsigned short)(r >> 16);
}
__device__ __forceinline__ float bf2f(unsigned short h) {
    union { unsigned u; float f; } c; c.u = ((unsigned)h) << 16;
    return c.f;
}
__device__ __forceinline__ float2 bfpair(unsigned u) {
    union { unsigned a; float f; } lo, hi;
    lo.a = u << 16;
    hi.a = u & 0xffff0000u;
    return make_float2(lo.f, hi.f);
}

// ---------------- fused prep: x-split + W1T/W2T-split + cnt zero ----------------
__global__ void prep_kernel(const float* __restrict__ x, unsigned short* __restrict__ xhi,
                            unsigned short* __restrict__ xlo, int n4,
                            const float* __restrict__ W1, unsigned short* __restrict__ w1th,
                            unsigned short* __restrict__ w1tl,
                            const float* __restrict__ W2, unsigned short* __restrict__ w2th,
                            unsigned short* __restrict__ w2tl,
                            int* __restrict__ cnt, int n2)
{
    const int b = blockIdx.x, t = threadIdx.x;
    if (b < 1024) {
        for (int i = b * 256 + t; i < n4; i += 1024 * 256) {
            float4 v = ((const float4*)x)[i];
            unsigned short h0 = bfr(v.x), h1 = bfr(v.y), h2 = bfr(v.z), h3 = bfr(v.w);
            unsigned short l0 = bfr(v.x - bf2f(h0)), l1 = bfr(v.y - bf2f(h1));
            unsigned short l2 = bfr(v.z - bf2f(h2)), l3 = bfr(v.w - bf2f(h3));
            ((uint2*)xhi)[i] = make_uint2((unsigned)h0 | ((unsigned)h1 << 16),
                                          (unsigned)h2 | ((unsigned)h3 << 16));
            ((uint2*)xlo)[i] = make_uint2((unsigned)l0 | ((unsigned)l1 << 16),
                                          (unsigned)l2 | ((unsigned)l3 << 16));
        }
    } else if (b < 1024 + 128) {
        int idx = (b - 1024) * 256 + t;          // W1: K=128, N=256
        const int K = 128, Nc = 256;
        int k = idx / Nc, n = idx - k * Nc;
        float v = W1[idx];
        unsigned short h = bfr(v);
        w1th[(size_t)n * K + k] = h;
        w1tl[(size_t)n * K + k] = bfr(v - bf2f(h));
    } else if (b < 1024 + 128 + 64) {
        int idx = (b - 1152) * 256 + t;          // W2: K=256, N=64
        const int K = 256, Nc = 64;
        int k = idx / Nc, n = idx - k * Nc;
        float v = W2[idx];
        unsigned short h = bfr(v);
        w2th[(size_t)n * K + k] = h;
        w2tl[(size_t)n * K + k] = bfr(v - bf2f(h));
    } else {
        int idx = (b - 1216) * 256 + t;          // zero cnt[2N] via int4
        if (idx < (n2 >> 2)) ((int4*)cnt)[idx] = make_int4(0, 0, 0, 0);
    }
}

// ---------------- single-pass bucket build (replaces count+scan+scatter) --------
// One atomic per edge: pos = atomicAdd(cnt[d]) ; csr[d*CAP+pos] = src.
// 4 edges/thread, phase-split for MLP. pos<CAP clamp guards memory (statistically
// unreachable for Poisson(8) degrees).
__global__ void bucket_kernel(const int* __restrict__ src1, const int* __restrict__ dst1,
                              const int* __restrict__ src2, const int* __restrict__ dst2,
                              int* __restrict__ cnt, int* __restrict__ csr, int N, int E)
{
    const int base = blockIdx.x * 1024 + threadIdx.x;
    int    srcv[4];
    size_t pos[4];
    bool   valid[4];
#pragma unroll
    for (int k = 0; k < 4; ++k) {
        int e = base + k * 256;
        valid[k] = false; srcv[k] = 0; pos[k] = 0;
        if (e < E) {
            int d = dst1[e];
            srcv[k] = src1[e];
            int p = atomicAdd(&cnt[d], 1);
            pos[k] = (size_t)d * CAP + p;
            valid[k] = (p < CAP);
        } else if (e < 2 * E) {
            int d = dst2[e - E];
            srcv[k] = src2[e - E];
            int p = atomicAdd(&cnt[N + d], 1);
            pos[k] = ((size_t)N + d) * CAP + p;
            valid[k] = (p < CAP);
        }
    }
#pragma unroll
    for (int k = 0; k < 4; ++k)
        if (valid[k]) csr[pos[k]] = srcv[k];
}

// ---------------- MFMA GEMM with GAT-alpha epilogue ----------------
// ALO=true: 3-pass split-bf16; ALO=false: plain bf16 A, 2-pass.
// C stored bf16, pairwise-packed via shfl_xor (even lanes store 4B).
template<int BM, int BN, int KDIM, int WR, int WC, int CPH, bool ALO>
__global__ __launch_bounds__(256, 2)
void mfma_gemm_gat(const unsigned short* __restrict__ Ahi, const unsigned short* __restrict__ Alo,
                   const unsigned short* __restrict__ BThi, const unsigned short* __restrict__ BTlo,
                   unsigned short* __restrict__ Cb,
                   const float* __restrict__ avec_s, const float* __restrict__ avec_d,
                   float* __restrict__ alpha_s, float* __restrict__ alpha_d,
                   int M, int N)
{
    constexpr int BK    = 32;
    constexpr int WROWS = BM / WR;
    constexpr int WCOLS = BN / WC;
    constexpr int FR    = WROWS / 16;
    constexpr int FC    = WCOLS / 16;
    constexpr int AP    = (BM * (BK / 8)) / 256;
    constexpr int BP    = (BN * (BK / 8)) / 256;
    static_assert(AP >= 1 && BP >= 1, "tile too small");

    __shared__ short As_hi[BM * BK], As_lo[ALO ? BM * BK : 64];
    __shared__ short Bs_hi[BN * BK], Bs_lo[BN * BK];

    const int tid  = threadIdx.x;
    const int w    = tid >> 6, lane = tid & 63;
    const int wr   = w / WC, wc = w % WC;
    const int lrow = lane & 15, lk = lane >> 4;
    const int m0   = blockIdx.x * BM, n0 = blockIdx.y * BN;

    f32x4 acc[FR][FC];
#pragma unroll
    for (int i = 0; i < FR; ++i)
#pragma unroll
        for (int j = 0; j < FC; ++j) acc[i][j] = (f32x4){0.f, 0.f, 0.f, 0.f};

    short8 rAh[AP], rAl[AP], rBh[BP], rBl[BP];

    auto LOAD = [&](int kb) {
#pragma unroll
        for (int p = 0; p < AP; ++p) {
            int id = p * 256 + tid;
            int r = id >> 2, c = id & 3;
            int row = m0 + r; row = row < M ? row : M - 1;
            size_t off = (size_t)row * KDIM + kb + c * 8;
            rAh[p] = *(const short8*)(Ahi + off);
            if constexpr (ALO) rAl[p] = *(const short8*)(Alo + off);
        }
#pragma unroll
        for (int p = 0; p < BP; ++p) {
            int id = p * 256 + tid;
            int r = id >> 2, c = id & 3;
            size_t off = (size_t)(n0 + r) * KDIM + kb + c * 8;
            rBh[p] = *(const short8*)(BThi + off);
            rBl[p] = *(const short8*)(BTlo + off);
        }
    };
    auto STORE = [&]() {
#pragma unroll
        for (int p = 0; p < AP; ++p) {
            int id = p * 256 + tid;
            int r = id >> 2, c = id & 3;
            *(short8*)(&As_hi[r * BK + c * 8]) = rAh[p];
            if constexpr (ALO) *(short8*)(&As_lo[r * BK + c * 8]) = rAl[p];
        }
#pragma unroll
        for (int p = 0; p < BP; ++p) {
            int id = p * 256 + tid;
            int r = id >> 2, c = id & 3;
            *(short8*)(&Bs_hi[r * BK + c * 8]) = rBh[p];
            *(short8*)(&Bs_lo[r * BK + c * 8]) = rBl[p];
        }
    };

    constexpr int NT = KDIM / BK;
    LOAD(0);
    for (int t = 0; t < NT; ++t) {
        STORE();
        __syncthreads();
        if (t + 1 < NT) LOAD((t + 1) * BK);

        short8 afh[FR], afl[FR], bfh[FC], bfl[FC];
#pragma unroll
        for (int fr = 0; fr < FR; ++fr) {
            int r = wr * WROWS + fr * 16 + lrow;
            afh[fr] = *(const short8*)(&As_hi[r * BK + lk * 8]);
            if constexpr (ALO) afl[fr] = *(const short8*)(&As_lo[r * BK + lk * 8]);
        }
#pragma unroll
        for (int fc = 0; fc < FC; ++fc) {
            int r = wc * WCOLS + fc * 16 + lrow;
            bfh[fc] = *(const short8*)(&Bs_hi[r * BK + lk * 8]);
            bfl[fc] = *(const short8*)(&Bs_lo[r * BK + lk * 8]);
        }
#pragma unroll
        for (int fr = 0; fr < FR; ++fr)
#pragma unroll
            for (int fc = 0; fc < FC; ++fc) {
                acc[fr][fc] = __builtin_amdgcn_mfma_f32_16x16x32_bf16(afh[fr], bfh[fc], acc[fr][fc], 0, 0, 0);
                acc[fr][fc] = __builtin_amdgcn_mfma_f32_16x16x32_bf16(afh[fr], bfl[fc], acc[fr][fc], 0, 0, 0);
                if constexpr (ALO)
                    acc[fr][fc] = __builtin_amdgcn_mfma_f32_16x16x32_bf16(afl[fr], bfh[fc], acc[fr][fc], 0, 0, 0);
            }
        __syncthreads();
    }

#pragma unroll
    for (int fr = 0; fr < FR; ++fr) {
        const int rbase = m0 + wr * WROWS + fr * 16 + lk * 4;
        float ps[4] = {0.f, 0.f, 0.f, 0.f}, pd[4] = {0.f, 0.f, 0.f, 0.f};
#pragma unroll
        for (int fc = 0; fc < FC; ++fc) {
            const int gc   = n0 + wc * WCOLS + fc * 16 + lrow;
            const int head = gc / CPH, ci = gc % CPH;
            const float asv = avec_s[head * CPH + ci];
            const float adv = avec_d[head * CPH + ci];
#pragma unroll
            for (int rg = 0; rg < 4; ++rg) {
                int row = rbase + rg;
                float v = acc[fr][fc][rg];
                unsigned short uh = bfr(v);
                unsigned up = (unsigned)__shfl_xor((int)(unsigned)uh, 1);
                if (!(lrow & 1) && row < M)
                    *(unsigned*)(Cb + (size_t)row * N + gc) = (unsigned)uh | (up << 16);
                ps[rg] += v * asv;
                pd[rg] += v * adv;
            }
            if constexpr (CPH == 16) {
#pragma unroll
                for (int rg = 0; rg < 4; ++rg) {
                    float s = ps[rg], d = pd[rg];
#pragma unroll
                    for (int m = 1; m <= 8; m <<= 1) {
                        s += __shfl_xor(s, m);
                        d += __shfl_xor(d, m);
                    }
                    if (lrow == 0 && rbase + rg < M) {
                        alpha_s[(size_t)(rbase + rg) * HEADS + head] = s;
                        alpha_d[(size_t)(rbase + rg) * HEADS + head] = d;
                    }
                    ps[rg] = 0.f; pd[rg] = 0.f;
                }
            }
        }
        if constexpr (CPH != 16) {
            const int head = (n0 + wc * WCOLS) / CPH;
#pragma unroll
            for (int rg = 0; rg < 4; ++rg) {
                float s = ps[rg], d = pd[rg];
#pragma unroll
                for (int m = 1; m <= 8; m <<= 1) {
                    s += __shfl_xor(s, m);
                    d += __shfl_xor(d, m);
                }
                if (lrow == 0 && rbase + rg < M) {
                    alpha_s[(size_t)(rbase + rg) * HEADS + head] = s;
                    alpha_d[(size_t)(rbase + rg) * HEADS + head] = d;
                }
            }
        }
    }
}

// ---------------- GAT softmax + aggregation (bucket CSR) ----------------
// S lanes per node (subgroup), CPL = CH/S = 8: every lane gathers one 16B uint4.
// deg = cnt[node]; edges at csr[node*CAP + j].
// OUTF32=false: write bf16 hi (layer 1); OUTF32=true: write f32 (layer 2).
template<int CH, int S, bool OUTF32>
__global__ __launch_bounds__(256)
void gat_agg(const unsigned short* __restrict__ hb, const float* __restrict__ alpha_s,
             const float* __restrict__ alpha_d, const int* __restrict__ cnt,
             const int* __restrict__ csr, const float* __restrict__ bias,
             float* __restrict__ out, unsigned short* __restrict__ out_hi, int n)
{
    constexpr int CPL = CH / S;
    constexpr int NSG = 256 / S;
    static_assert(CPL == 8, "lane owns one uint4");
    __shared__ float wls[NSG][S * 5];
    const int tid    = threadIdx.x;
    const int sub    = tid / S;
    const int i      = tid % S;
    const int lane64 = tid & 63;
    const int base   = lane64 & ~(S - 1);
    const int node   = blockIdx.x * NSG + sub;
    if (node >= n) return;
    const int head = (i * CPL) / (CH / 4);
    const int deg = min(cnt[node], CAP);
    const size_t ebase = (size_t)node * CAP;

    const float4 asn = *(const float4*)(alpha_s + (size_t)node * 4);
    const float4 adn = *(const float4*)(alpha_d + (size_t)node * 4);
    float4 den = f4exp(f4lrelu(f4add(asn, adn)));
    const float wse = pickh(den, head);

    float acc[8];
    {
        uint4 hv = *(const uint4*)(hb + (size_t)node * CH + i * 8);
        float2 q0 = bfpair(hv.x), q1 = bfpair(hv.y), q2 = bfpair(hv.z), q3 = bfpair(hv.w);
        acc[0] = wse * q0.x; acc[1] = wse * q0.y; acc[2] = wse * q1.x; acc[3] = wse * q1.y;
        acc[4] = wse * q2.x; acc[5] = wse * q2.y; acc[6] = wse * q3.x; acc[7] = wse * q3.y;
    }

    for (int ch = 0; ch < deg; ch += S) {
        const int cntc = min(S, deg - ch);
        float4 w4 = make_float4(0.f, 0.f, 0.f, 0.f);
        int sl = 0;
        if (i < cntc) {
            sl = csr[ebase + ch + i];
            float4 al = *(const float4*)(alpha_s + (size_t)sl * 4);
            w4 = f4exp(f4lrelu(f4add(al, adn)));
        }
        float4 t = w4;
#pragma unroll
        for (int d = S / 2; d >= 1; d >>= 1) {
            t.x += __shfl_xor(t.x, d);
            t.y += __shfl_xor(t.y, d);
            t.z += __shfl_xor(t.z, d);
            t.w += __shfl_xor(t.w, d);
        }
        den = f4add(den, t);
        wls[sub][i * 5 + 0] = w4.x;
        wls[sub][i * 5 + 1] = w4.y;
        wls[sub][i * 5 + 2] = w4.z;
        wls[sub][i * 5 + 3] = w4.w;

        const int padded = (cntc + 7) & ~7;
        for (int j = 0; j < padded; j += 8) {
            int   sk[8];
            float wk[8];
#pragma unroll
            for (int k = 0; k < 8; ++k) {
                sk[k] = __shfl(sl, base + ((j + k) < S ? (j + k) : 0));
                wk[k] = wls[sub][(j + k) * 5 + head];
            }
            uint4 v[8];
#pragma unroll
            for (int k = 0; k < 8; ++k)
                v[k] = *(const uint4*)(hb + (size_t)sk[k] * CH + i * 8);
#pragma unroll
            for (int k = 0; k < 8; ++k) {
                float2 q0 = bfpair(v[k].x), q1 = bfpair(v[k].y);
                float2 q2 = bfpair(v[k].z), q3 = bfpair(v[k].w);
                acc[0] += wk[k] * q0.x; acc[1] += wk[k] * q0.y;
                acc[2] += wk[k] * q1.x; acc[3] += wk[k] * q1.y;
                acc[4] += wk[k] * q2.x; acc[5] += wk[k] * q2.y;
                acc[6] += wk[k] * q3.x; acc[7] += wk[k] * q3.y;
            }
        }
    }

    const float invd = 1.0f / (pickh(den, head) + 1e-16f);
    const int c0 = i * CPL;
    float o[8];
#pragma unroll
    for (int k = 0; k < 8; ++k)
        o[k] = fmaxf(acc[k] * invd + bias[c0 + k], 0.f);
    if constexpr (OUTF32) {
        *(float4*)(out + (size_t)node * CH + c0)     = make_float4(o[0], o[1], o[2], o[3]);
        *(float4*)(out + (size_t)node * CH + c0 + 4) = make_float4(o[4], o[5], o[6], o[7]);
    } else {
        unsigned short oh[8];
#pragma unroll
        for (int k = 0; k < 8; ++k) oh[k] = bfr(o[k]);
        uint4 ph;
        ph.x = (unsigned)oh[0] | ((unsigned)oh[1] << 16);
        ph.y = (unsigned)oh[2] | ((unsigned)oh[3] << 16);
        ph.z = (unsigned)oh[4] | ((unsigned)oh[5] << 16);
        ph.w = (unsigned)oh[6] | ((unsigned)oh[7] << 16);
        *(uint4*)(out_hi + (size_t)node * CH + c0) = ph;
    }
}

// ---------------- fused mean-pool/FC (per-block binary search) ----------------
__global__ __launch_bounds__(256)
void pool_fc_kernel(const float* __restrict__ feat, const int* __restrict__ batch,
                    const float* __restrict__ Wfc, const float* __restrict__ bfc,
                    float* __restrict__ out, int n)
{
    __shared__ float4 part[16][16];
    __shared__ float pooled[64];
    __shared__ int sb[2];
    const int g = blockIdx.x;
    const int t = threadIdx.x;
    if (t < 2) {
        int target = g + t;
        int lo = 0, hi = n;
        while (lo < hi) {
            int mid = (lo + hi) >> 1;
            if (batch[mid] < target) lo = mid + 1; else hi = mid;
        }
        sb[t] = lo;
    }
    __syncthreads();
    const int s0 = sb[0], s1 = sb[1];
    const int q = t & 15, ns = t >> 4;
    float4 acc = make_float4(0.f, 0.f, 0.f, 0.f);
    for (int i = s0 + ns; i < s1; i += 16)
        acc = f4add(acc, *(const float4*)(feat + (size_t)i * 64 + q * 4));
    part[ns][q] = acc;
    __syncthreads();
    if (t < 16) {
        float4 s = part[0][t];
#pragma unroll
        for (int k = 1; k < 16; ++k) s = f4add(s, part[k][t]);
        float inv = 1.0f / fmaxf((float)(s1 - s0), 1.0f);
        pooled[t * 4 + 0] = s.x * inv;
        pooled[t * 4 + 1] = s.y * inv;
        pooled[t * 4 + 2] = s.z * inv;
        pooled[t * 4 + 3] = s.w * inv;
    }
    __syncthreads();
    if (t < 2) {
        float a = bfc[t];
        for (int c = 0; c < 64; ++c) a += pooled[c] * Wfc[c * 2 + t];
        out[g * 2 + t] = a;
    }
}

// ---------------- launch ----------------
extern "C" void kernel_launch(void* const* d_in, const int* in_sizes, int n_in,
                              void* d_out, int out_size, void* d_ws, size_t ws_size,
                              hipStream_t stream)
{
    const float* x    = (const float*)d_in[0];
    const int*   ei   = (const int*)d_in[1];
    const int*   batch= (const int*)d_in[2];
    const float* W1   = (const float*)d_in[3];
    const float* as1  = (const float*)d_in[4];
    const float* ad1  = (const float*)d_in[5];
    const float* b1   = (const float*)d_in[6];
    const float* W2   = (const float*)d_in[7];
    const float* as2  = (const float*)d_in[8];
    const float* ad2  = (const float*)d_in[9];
    const float* b2   = (const float*)d_in[10];
    const float* Wfc  = (const float*)d_in[11];
    const float* bfc  = (const float*)d_in[12];
    float* out = (float*)d_out;

    const int N = in_sizes[2];          // 50000 nodes
    const int E = in_sizes[1] / 27;     // 400000 edges
    const int F = in_sizes[0] / N;      // 128

    char* ws = (char*)d_ws;
    unsigned short* h1b   = (unsigned short*)(ws + OFF_H1B);
    unsigned short* h2b   = (unsigned short*)(ws + OFF_H2B);
    float*          out2  = (float*)(ws + OFF_OUT2);
    unsigned short* xhi   = (unsigned short*)(ws + OFF_XHI);
    unsigned short* xlo   = (unsigned short*)(ws + OFF_XLO);
    unsigned short* o1hi  = (unsigned short*)(ws + OFF_O1HI);
    unsigned short* w1th  = (unsigned short*)(ws + OFF_W1TH);
    unsigned short* w1tl  = (unsigned short*)(ws + OFF_W1TL);
    unsigned short* w2th  = (unsigned short*)(ws + OFF_W2TH);
    unsigned short* w2tl  = (unsigned short*)(ws + OFF_W2TL);
    float* al_s  = (float*)(ws + OFF_AS);
    float* al_d  = (float*)(ws + OFF_AD);
    int*   cnt   = (int*)(ws + OFF_CNT);    // 2N counts (layer2 view = cnt+N)
    int*   csr   = (int*)(ws + OFF_CSR);    // 2N*CAP bucket table

    const int e2grid4 = (2 * E + 1023) / 1024;     // 782 blocks (4 edges/thread)
    const int ZB      = ((2 * N / 4) + 255) / 256; // 98 zero-blocks in prep

    // ---- 1: fused prep (x split + W splits + cnt zero) ----
    prep_kernel<<<1216 + ZB, 256, 0, stream>>>(x, xhi, xlo, N * F / 4,
                                               W1, w1th, w1tl, W2, w2th, w2tl,
                                               cnt, 2 * N);

    // ---- 2: single-pass bucket build (both layers) ----
    bucket_kernel<<<e2grid4, 256, 0, stream>>>(ei + 17 * (size_t)E, ei + 26 * (size_t)E,
                                               ei + 15 * (size_t)E, ei + 16 * (size_t)E,
                                               cnt, csr, N, E);

    // ---- 3: layer-1 MFMA GEMM (split-bf16 A, 3-pass, BM=64) -> bf16 h1 ----
    {
        dim3 g((N + 63) / 64, 2);
        mfma_gemm_gat<64, 128, 128, 2, 2, 64, true><<<g, 256, 0, stream>>>(
            xhi, xlo, w1th, w1tl, h1b, as1, ad1, al_s, al_d, N, HEADS * 64);
    }
    // ---- 4: layer-1 aggregation (S=32, bf16 hi out) ----
    gat_agg<256, 32, false><<<(N + 7) / 8, 256, 0, stream>>>(h1b, al_s, al_d, cnt, csr, b1,
                                                             nullptr, o1hi, N);

    // ---- 5: layer-2 MFMA GEMM (bf16 A, 2-pass) -> bf16 h2 ----
    {
        dim3 g((N + 63) / 64, 1);
        mfma_gemm_gat<64, 64, 256, 2, 2, 16, false><<<g, 256, 0, stream>>>(
            o1hi, nullptr, w2th, w2tl, h2b, as2, ad2, al_s, al_d, N, HEADS * 16);
    }
    // ---- 6: layer-2 aggregation (S=8, 16B gathers, f32 out) ----
    gat_agg<64, 8, true><<<(N + 31) / 32, 256, 0, stream>>>(h2b, al_s, al_d, cnt + N,
                                                            csr + (size_t)N * CAP, b2,
                                                            out2, nullptr, N);

    // ---- 7: fused mean-pool + FC ----
    pool_fc_kernel<<<64, 256, 0, stream>>>(out2, batch, Wfc, bfc, out, N);
}

// Round 17
// 168.300 us; speedup vs baseline: 1.3422x; 1.0126x over previous
//
#include <hip/hip_runtime.h>
#include <math.h>

#define HEADS 4
#define NEG_SLOPE 0.2f
#define CAP 32   // bucket capacity per node (avg in-degree 8; P(deg>32) ~ 2e-11; clamp guards)

// ---------------- workspace layout (bytes) ----------------
static constexpr size_t OFF_H1B  = 0;
static constexpr size_t OFF_H2B  = 0;
static constexpr size_t OFF_OUT2 = 6400000;
static constexpr size_t OFF_XHI  = 25600000;
static constexpr size_t OFF_XLO  = 38400000;
static constexpr size_t OFF_O1HI = 25600000;   // aliases xhi/xlo (dead by then)
static constexpr size_t OFF_W1TH = 76800000;   // 256x128 bf16 = 64KB
static constexpr size_t OFF_W1TL = 76865536;
static constexpr size_t OFF_W2TH = 76931072;   // 64x256 bf16 = 32KB
static constexpr size_t OFF_W2TL = 76963840;
static constexpr size_t OFF_AS   = 77000000;   // 800,000
static constexpr size_t OFF_AD   = 77800000;   // 800,000
static constexpr size_t OFF_CNT  = 78600064;   // 2N ints
static constexpr size_t OFF_CSR  = 79000128;   // 2N*CAP ints = 12.8 MB

typedef __attribute__((ext_vector_type(8))) short short8;
typedef __attribute__((ext_vector_type(4))) float f32x4;

// ---------------- helpers ----------------
__device__ __forceinline__ float4 f4add(float4 a, float4 b) {
    return make_float4(a.x + b.x, a.y + b.y, a.z + b.z, a.w + b.w);
}
__device__ __forceinline__ float lrelu(float x) { return x > 0.f ? x : NEG_SLOPE * x; }
__device__ __forceinline__ float4 f4lrelu(float4 a) {
    return make_float4(lrelu(a.x), lrelu(a.y), lrelu(a.z), lrelu(a.w));
}
__device__ __forceinline__ float4 f4exp(float4 a) {
    return make_float4(__expf(a.x), __expf(a.y), __expf(a.z), __expf(a.w));
}
__device__ __forceinline__ float pickh(float4 v, int head) {
    float r = v.x;
    r = head == 1 ? v.y : r;
    r = head == 2 ? v.z : r;
    r = head == 3 ? v.w : r;
    return r;
}
__device__ __forceinline__ unsigned short bfr(float x) {
    union { float f; unsigned u; } c; c.f = x;
    unsigned r = c.u + 0x7FFFu + ((c.u >> 16) & 1u);
    return (unsigned short)(r >> 16);
}
__device__ __forceinline__ float bf2f(unsigned short h) {
    union { unsigned u; float f; } c; c.u = ((unsigned)h) << 16;
    return c.f;
}
__device__ __forceinline__ float2 bfpair(unsigned u) {
    union { unsigned a; float f; } lo, hi;
    lo.a = u << 16;
    hi.a = u & 0xffff0000u;
    return make_float2(lo.f, hi.f);
}

// ---------------- fused prep: x-split + W1T/W2T-split + cnt zero ----------------
__global__ void prep_kernel(const float* __restrict__ x, unsigned short* __restrict__ xhi,
                            unsigned short* __restrict__ xlo, int n4,
                            const float* __restrict__ W1, unsigned short* __restrict__ w1th,
                            unsigned short* __restrict__ w1tl,
                            const float* __restrict__ W2, unsigned short* __restrict__ w2th,
                            unsigned short* __restrict__ w2tl,
                            int* __restrict__ cnt, int n2)
{
    const int b = blockIdx.x, t = threadIdx.x;
    if (b < 1024) {
        for (int i = b * 256 + t; i < n4; i += 1024 * 256) {
            float4 v = ((const float4*)x)[i];
            unsigned short h0 = bfr(v.x), h1 = bfr(v.y), h2 = bfr(v.z), h3 = bfr(v.w);
            unsigned short l0 = bfr(v.x - bf2f(h0)), l1 = bfr(v.y - bf2f(h1));
            unsigned short l2 = bfr(v.z - bf2f(h2)), l3 = bfr(v.w - bf2f(h3));
            ((uint2*)xhi)[i] = make_uint2((unsigned)h0 | ((unsigned)h1 << 16),
                                          (unsigned)h2 | ((unsigned)h3 << 16));
            ((uint2*)xlo)[i] = make_uint2((unsigned)l0 | ((unsigned)l1 << 16),
                                          (unsigned)l2 | ((unsigned)l3 << 16));
        }
    } else if (b < 1024 + 128) {
        int idx = (b - 1024) * 256 + t;          // W1: K=128, N=256
        const int K = 128, Nc = 256;
        int k = idx / Nc, n = idx - k * Nc;
        float v = W1[idx];
        unsigned short h = bfr(v);
        w1th[(size_t)n * K + k] = h;
        w1tl[(size_t)n * K + k] = bfr(v - bf2f(h));
    } else if (b < 1024 + 128 + 64) {
        int idx = (b - 1152) * 256 + t;          // W2: K=256, N=64
        const int K = 256, Nc = 64;
        int k = idx / Nc, n = idx - k * Nc;
        float v = W2[idx];
        unsigned short h = bfr(v);
        w2th[(size_t)n * K + k] = h;
        w2tl[(size_t)n * K + k] = bfr(v - bf2f(h));
    } else {
        int idx = (b - 1216) * 256 + t;          // zero cnt[2N] via int4
        if (idx < (n2 >> 2)) ((int4*)cnt)[idx] = make_int4(0, 0, 0, 0);
    }
}

// ---------------- dst-partitioned, XCD-affine bucket build ----------------
// Partition p = dst & 7 handled only by blocks with blockIdx&7 == p. With the
// round-robin block->XCD heuristic, each bucket's cache lines are written by a
// single XCD -> lines coalesce in that L2 and write back once.
// N % 8 == 0, so layer-2 buckets (N+d) keep the same owner.
// Each chunk of 2048 edges is scanned by all 8 partitions (8x cheap dst reads).
__global__ void bucket_kernel(const int* __restrict__ src1, const int* __restrict__ dst1,
                              const int* __restrict__ src2, const int* __restrict__ dst2,
                              int* __restrict__ cnt, int* __restrict__ csr, int N, int E)
{
    const int part  = blockIdx.x & 7;
    const int chunk = blockIdx.x >> 3;
    const int base  = chunk * 2048 + threadIdx.x;
#pragma unroll
    for (int k = 0; k < 8; ++k) {
        int e = base + k * 256;
        if (e < E) {
            int d = dst1[e];
            if ((d & 7) == part) {
                int p = atomicAdd(&cnt[d], 1);
                if (p < CAP) csr[(size_t)d * CAP + p] = src1[e];
            }
        } else if (e < 2 * E) {
            int d = dst2[e - E];
            if ((d & 7) == part) {
                int p = atomicAdd(&cnt[N + d], 1);
                if (p < CAP) csr[((size_t)N + d) * CAP + p] = src2[e - E];
            }
        }
    }
}

// ---------------- MFMA GEMM with GAT-alpha epilogue ----------------
// ALO=true: 3-pass split-bf16; ALO=false: plain bf16 A, 2-pass.
// C stored bf16, pairwise-packed via shfl_xor (even lanes store 4B).
template<int BM, int BN, int KDIM, int WR, int WC, int CPH, bool ALO>
__global__ __launch_bounds__(256, 2)
void mfma_gemm_gat(const unsigned short* __restrict__ Ahi, const unsigned short* __restrict__ Alo,
                   const unsigned short* __restrict__ BThi, const unsigned short* __restrict__ BTlo,
                   unsigned short* __restrict__ Cb,
                   const float* __restrict__ avec_s, const float* __restrict__ avec_d,
                   float* __restrict__ alpha_s, float* __restrict__ alpha_d,
                   int M, int N)
{
    constexpr int BK    = 32;
    constexpr int WROWS = BM / WR;
    constexpr int WCOLS = BN / WC;
    constexpr int FR    = WROWS / 16;
    constexpr int FC    = WCOLS / 16;
    constexpr int AP    = (BM * (BK / 8)) / 256;
    constexpr int BP    = (BN * (BK / 8)) / 256;
    static_assert(AP >= 1 && BP >= 1, "tile too small");

    __shared__ short As_hi[BM * BK], As_lo[ALO ? BM * BK : 64];
    __shared__ short Bs_hi[BN * BK], Bs_lo[BN * BK];

    const int tid  = threadIdx.x;
    const int w    = tid >> 6, lane = tid & 63;
    const int wr   = w / WC, wc = w % WC;
    const int lrow = lane & 15, lk = lane >> 4;
    const int m0   = blockIdx.x * BM, n0 = blockIdx.y * BN;

    f32x4 acc[FR][FC];
#pragma unroll
    for (int i = 0; i < FR; ++i)
#pragma unroll
        for (int j = 0; j < FC; ++j) acc[i][j] = (f32x4){0.f, 0.f, 0.f, 0.f};

    short8 rAh[AP], rAl[AP], rBh[BP], rBl[BP];

    auto LOAD = [&](int kb) {
#pragma unroll
        for (int p = 0; p < AP; ++p) {
            int id = p * 256 + tid;
            int r = id >> 2, c = id & 3;
            int row = m0 + r; row = row < M ? row : M - 1;
            size_t off = (size_t)row * KDIM + kb + c * 8;
            rAh[p] = *(const short8*)(Ahi + off);
            if constexpr (ALO) rAl[p] = *(const short8*)(Alo + off);
        }
#pragma unroll
        for (int p = 0; p < BP; ++p) {
            int id = p * 256 + tid;
            int r = id >> 2, c = id & 3;
            size_t off = (size_t)(n0 + r) * KDIM + kb + c * 8;
            rBh[p] = *(const short8*)(BThi + off);
            rBl[p] = *(const short8*)(BTlo + off);
        }
    };
    auto STORE = [&]() {
#pragma unroll
        for (int p = 0; p < AP; ++p) {
            int id = p * 256 + tid;
            int r = id >> 2, c = id & 3;
            *(short8*)(&As_hi[r * BK + c * 8]) = rAh[p];
            if constexpr (ALO) *(short8*)(&As_lo[r * BK + c * 8]) = rAl[p];
        }
#pragma unroll
        for (int p = 0; p < BP; ++p) {
            int id = p * 256 + tid;
            int r = id >> 2, c = id & 3;
            *(short8*)(&Bs_hi[r * BK + c * 8]) = rBh[p];
            *(short8*)(&Bs_lo[r * BK + c * 8]) = rBl[p];
        }
    };

    constexpr int NT = KDIM / BK;
    LOAD(0);
    for (int t = 0; t < NT; ++t) {
        STORE();
        __syncthreads();
        if (t + 1 < NT) LOAD((t + 1) * BK);

        short8 afh[FR], afl[FR], bfh[FC], bfl[FC];
#pragma unroll
        for (int fr = 0; fr < FR; ++fr) {
            int r = wr * WROWS + fr * 16 + lrow;
            afh[fr] = *(const short8*)(&As_hi[r * BK + lk * 8]);
            if constexpr (ALO) afl[fr] = *(const short8*)(&As_lo[r * BK + lk * 8]);
        }
#pragma unroll
        for (int fc = 0; fc < FC; ++fc) {
            int r = wc * WCOLS + fc * 16 + lrow;
            bfh[fc] = *(const short8*)(&Bs_hi[r * BK + lk * 8]);
            bfl[fc] = *(const short8*)(&Bs_lo[r * BK + lk * 8]);
        }
#pragma unroll
        for (int fr = 0; fr < FR; ++fr)
#pragma unroll
            for (int fc = 0; fc < FC; ++fc) {
                acc[fr][fc] = __builtin_amdgcn_mfma_f32_16x16x32_bf16(afh[fr], bfh[fc], acc[fr][fc], 0, 0, 0);
                acc[fr][fc] = __builtin_amdgcn_mfma_f32_16x16x32_bf16(afh[fr], bfl[fc], acc[fr][fc], 0, 0, 0);
                if constexpr (ALO)
                    acc[fr][fc] = __builtin_amdgcn_mfma_f32_16x16x32_bf16(afl[fr], bfh[fc], acc[fr][fc], 0, 0, 0);
            }
        __syncthreads();
    }

#pragma unroll
    for (int fr = 0; fr < FR; ++fr) {
        const int rbase = m0 + wr * WROWS + fr * 16 + lk * 4;
        float ps[4] = {0.f, 0.f, 0.f, 0.f}, pd[4] = {0.f, 0.f, 0.f, 0.f};
#pragma unroll
        for (int fc = 0; fc < FC; ++fc) {
            const int gc   = n0 + wc * WCOLS + fc * 16 + lrow;
            const int head = gc / CPH, ci = gc % CPH;
            const float asv = avec_s[head * CPH + ci];
            const float adv = avec_d[head * CPH + ci];
#pragma unroll
            for (int rg = 0; rg < 4; ++rg) {
                int row = rbase + rg;
                float v = acc[fr][fc][rg];
                unsigned short uh = bfr(v);
                unsigned up = (unsigned)__shfl_xor((int)(unsigned)uh, 1);
                if (!(lrow & 1) && row < M)
                    *(unsigned*)(Cb + (size_t)row * N + gc) = (unsigned)uh | (up << 16);
                ps[rg] += v * asv;
                pd[rg] += v * adv;
            }
            if constexpr (CPH == 16) {
#pragma unroll
                for (int rg = 0; rg < 4; ++rg) {
                    float s = ps[rg], d = pd[rg];
#pragma unroll
                    for (int m = 1; m <= 8; m <<= 1) {
                        s += __shfl_xor(s, m);
                        d += __shfl_xor(d, m);
                    }
                    if (lrow == 0 && rbase + rg < M) {
                        alpha_s[(size_t)(rbase + rg) * HEADS + head] = s;
                        alpha_d[(size_t)(rbase + rg) * HEADS + head] = d;
                    }
                    ps[rg] = 0.f; pd[rg] = 0.f;
                }
            }
        }
        if constexpr (CPH != 16) {
            const int head = (n0 + wc * WCOLS) / CPH;
#pragma unroll
            for (int rg = 0; rg < 4; ++rg) {
                float s = ps[rg], d = pd[rg];
#pragma unroll
                for (int m = 1; m <= 8; m <<= 1) {
                    s += __shfl_xor(s, m);
                    d += __shfl_xor(d, m);
                }
                if (lrow == 0 && rbase + rg < M) {
                    alpha_s[(size_t)(rbase + rg) * HEADS + head] = s;
                    alpha_d[(size_t)(rbase + rg) * HEADS + head] = d;
                }
            }
        }
    }
}

// ---------------- GAT softmax + aggregation (bucket CSR) ----------------
// S lanes per node (subgroup), CPL = CH/S = 8: every lane gathers one 16B uint4.
// deg = cnt[node]; edges at csr[node*CAP + j].
// OUTF32=false: write bf16 hi (layer 1); OUTF32=true: write f32 (layer 2).
template<int CH, int S, bool OUTF32>
__global__ __launch_bounds__(256)
void gat_agg(const unsigned short* __restrict__ hb, const float* __restrict__ alpha_s,
             const float* __restrict__ alpha_d, const int* __restrict__ cnt,
             const int* __restrict__ csr, const float* __restrict__ bias,
             float* __restrict__ out, unsigned short* __restrict__ out_hi, int n)
{
    constexpr int CPL = CH / S;
    constexpr int NSG = 256 / S;
    static_assert(CPL == 8, "lane owns one uint4");
    __shared__ float wls[NSG][S * 5];
    const int tid    = threadIdx.x;
    const int sub    = tid / S;
    const int i      = tid % S;
    const int lane64 = tid & 63;
    const int base   = lane64 & ~(S - 1);
    const int node   = blockIdx.x * NSG + sub;
    if (node >= n) return;
    const int head = (i * CPL) / (CH / 4);
    const int deg = min(cnt[node], CAP);
    const size_t ebase = (size_t)node * CAP;

    const float4 asn = *(const float4*)(alpha_s + (size_t)node * 4);
    const float4 adn = *(const float4*)(alpha_d + (size_t)node * 4);
    float4 den = f4exp(f4lrelu(f4add(asn, adn)));
    const float wse = pickh(den, head);

    float acc[8];
    {
        uint4 hv = *(const uint4*)(hb + (size_t)node * CH + i * 8);
        float2 q0 = bfpair(hv.x), q1 = bfpair(hv.y), q2 = bfpair(hv.z), q3 = bfpair(hv.w);
        acc[0] = wse * q0.x; acc[1] = wse * q0.y; acc[2] = wse * q1.x; acc[3] = wse * q1.y;
        acc[4] = wse * q2.x; acc[5] = wse * q2.y; acc[6] = wse * q3.x; acc[7] = wse * q3.y;
    }

    for (int ch = 0; ch < deg; ch += S) {
        const int cntc = min(S, deg - ch);
        float4 w4 = make_float4(0.f, 0.f, 0.f, 0.f);
        int sl = 0;
        if (i < cntc) {
            sl = csr[ebase + ch + i];
            float4 al = *(const float4*)(alpha_s + (size_t)sl * 4);
            w4 = f4exp(f4lrelu(f4add(al, adn)));
        }
        float4 t = w4;
#pragma unroll
        for (int d = S / 2; d >= 1; d >>= 1) {
            t.x += __shfl_xor(t.x, d);
            t.y += __shfl_xor(t.y, d);
            t.z += __shfl_xor(t.z, d);
            t.w += __shfl_xor(t.w, d);
        }
        den = f4add(den, t);
        wls[sub][i * 5 + 0] = w4.x;
        wls[sub][i * 5 + 1] = w4.y;
        wls[sub][i * 5 + 2] = w4.z;
        wls[sub][i * 5 + 3] = w4.w;

        const int padded = (cntc + 7) & ~7;
        for (int j = 0; j < padded; j += 8) {
            int   sk[8];
            float wk[8];
#pragma unroll
            for (int k = 0; k < 8; ++k) {
                sk[k] = __shfl(sl, base + ((j + k) < S ? (j + k) : 0));
                wk[k] = wls[sub][(j + k) * 5 + head];
            }
            uint4 v[8];
#pragma unroll
            for (int k = 0; k < 8; ++k)
                v[k] = *(const uint4*)(hb + (size_t)sk[k] * CH + i * 8);
#pragma unroll
            for (int k = 0; k < 8; ++k) {
                float2 q0 = bfpair(v[k].x), q1 = bfpair(v[k].y);
                float2 q2 = bfpair(v[k].z), q3 = bfpair(v[k].w);
                acc[0] += wk[k] * q0.x; acc[1] += wk[k] * q0.y;
                acc[2] += wk[k] * q1.x; acc[3] += wk[k] * q1.y;
                acc[4] += wk[k] * q2.x; acc[5] += wk[k] * q2.y;
                acc[6] += wk[k] * q3.x; acc[7] += wk[k] * q3.y;
            }
        }
    }

    const float invd = 1.0f / (pickh(den, head) + 1e-16f);
    const int c0 = i * CPL;
    float o[8];
#pragma unroll
    for (int k = 0; k < 8; ++k)
        o[k] = fmaxf(acc[k] * invd + bias[c0 + k], 0.f);
    if constexpr (OUTF32) {
        *(float4*)(out + (size_t)node * CH + c0)     = make_float4(o[0], o[1], o[2], o[3]);
        *(float4*)(out + (size_t)node * CH + c0 + 4) = make_float4(o[4], o[5], o[6], o[7]);
    } else {
        unsigned short oh[8];
#pragma unroll
        for (int k = 0; k < 8; ++k) oh[k] = bfr(o[k]);
        uint4 ph;
        ph.x = (unsigned)oh[0] | ((unsigned)oh[1] << 16);
        ph.y = (unsigned)oh[2] | ((unsigned)oh[3] << 16);
        ph.z = (unsigned)oh[4] | ((unsigned)oh[5] << 16);
        ph.w = (unsigned)oh[6] | ((unsigned)oh[7] << 16);
        *(uint4*)(out_hi + (size_t)node * CH + c0) = ph;
    }
}

// ---------------- fused mean-pool/FC (per-block binary search) ----------------
__global__ __launch_bounds__(256)
void pool_fc_kernel(const float* __restrict__ feat, const int* __restrict__ batch,
                    const float* __restrict__ Wfc, const float* __restrict__ bfc,
                    float* __restrict__ out, int n)
{
    __shared__ float4 part[16][16];
    __shared__ float pooled[64];
    __shared__ int sb[2];
    const int g = blockIdx.x;
    const int t = threadIdx.x;
    if (t < 2) {
        int target = g + t;
        int lo = 0, hi = n;
        while (lo < hi) {
            int mid = (lo + hi) >> 1;
            if (batch[mid] < target) lo = mid + 1; else hi = mid;
        }
        sb[t] = lo;
    }
    __syncthreads();
    const int s0 = sb[0], s1 = sb[1];
    const int q = t & 15, ns = t >> 4;
    float4 acc = make_float4(0.f, 0.f, 0.f, 0.f);
    for (int i = s0 + ns; i < s1; i += 16)
        acc = f4add(acc, *(const float4*)(feat + (size_t)i * 64 + q * 4));
    part[ns][q] = acc;
    __syncthreads();
    if (t < 16) {
        float4 s = part[0][t];
#pragma unroll
        for (int k = 1; k < 16; ++k) s = f4add(s, part[k][t]);
        float inv = 1.0f / fmaxf((float)(s1 - s0), 1.0f);
        pooled[t * 4 + 0] = s.x * inv;
        pooled[t * 4 + 1] = s.y * inv;
        pooled[t * 4 + 2] = s.z * inv;
        pooled[t * 4 + 3] = s.w * inv;
    }
    __syncthreads();
    if (t < 2) {
        float a = bfc[t];
        for (int c = 0; c < 64; ++c) a += pooled[c] * Wfc[c * 2 + t];
        out[g * 2 + t] = a;
    }
}

// ---------------- launch ----------------
extern "C" void kernel_launch(void* const* d_in, const int* in_sizes, int n_in,
                              void* d_out, int out_size, void* d_ws, size_t ws_size,
                              hipStream_t stream)
{
    const float* x    = (const float*)d_in[0];
    const int*   ei   = (const int*)d_in[1];
    const int*   batch= (const int*)d_in[2];
    const float* W1   = (const float*)d_in[3];
    const float* as1  = (const float*)d_in[4];
    const float* ad1  = (const float*)d_in[5];
    const float* b1   = (const float*)d_in[6];
    const float* W2   = (const float*)d_in[7];
    const float* as2  = (const float*)d_in[8];
    const float* ad2  = (const float*)d_in[9];
    const float* b2   = (const float*)d_in[10];
    const float* Wfc  = (const float*)d_in[11];
    const float* bfc  = (const float*)d_in[12];
    float* out = (float*)d_out;

    const int N = in_sizes[2];          // 50000 nodes
    const int E = in_sizes[1] / 27;     // 400000 edges
    const int F = in_sizes[0] / N;      // 128

    char* ws = (char*)d_ws;
    unsigned short* h1b   = (unsigned short*)(ws + OFF_H1B);
    unsigned short* h2b   = (unsigned short*)(ws + OFF_H2B);
    float*          out2  = (float*)(ws + OFF_OUT2);
    unsigned short* xhi   = (unsigned short*)(ws + OFF_XHI);
    unsigned short* xlo   = (unsigned short*)(ws + OFF_XLO);
    unsigned short* o1hi  = (unsigned short*)(ws + OFF_O1HI);
    unsigned short* w1th  = (unsigned short*)(ws + OFF_W1TH);
    unsigned short* w1tl  = (unsigned short*)(ws + OFF_W1TL);
    unsigned short* w2th  = (unsigned short*)(ws + OFF_W2TH);
    unsigned short* w2tl  = (unsigned short*)(ws + OFF_W2TL);
    float* al_s  = (float*)(ws + OFF_AS);
    float* al_d  = (float*)(ws + OFF_AD);
    int*   cnt   = (int*)(ws + OFF_CNT);    // 2N counts (layer2 view = cnt+N)
    int*   csr   = (int*)(ws + OFF_CSR);    // 2N*CAP bucket table

    const int NCH = (2 * E + 2047) / 2048;         // 391 edge chunks
    const int ZB  = ((2 * N / 4) + 255) / 256;     // 98 zero-blocks in prep

    // ---- 1: fused prep (x split + W splits + cnt zero) ----
    prep_kernel<<<1216 + ZB, 256, 0, stream>>>(x, xhi, xlo, N * F / 4,
                                               W1, w1th, w1tl, W2, w2th, w2tl,
                                               cnt, 2 * N);

    // ---- 2: partitioned bucket build (both layers) ----
    bucket_kernel<<<NCH * 8, 256, 0, stream>>>(ei + 17 * (size_t)E, ei + 26 * (size_t)E,
                                               ei + 15 * (size_t)E, ei + 16 * (size_t)E,
                                               cnt, csr, N, E);

    // ---- 3: layer-1 MFMA GEMM (split-bf16 A, 3-pass, BM=64) -> bf16 h1 ----
    {
        dim3 g((N + 63) / 64, 2);
        mfma_gemm_gat<64, 128, 128, 2, 2, 64, true><<<g, 256, 0, stream>>>(
            xhi, xlo, w1th, w1tl, h1b, as1, ad1, al_s, al_d, N, HEADS * 64);
    }
    // ---- 4: layer-1 aggregation (S=32, bf16 hi out) ----
    gat_agg<256, 32, false><<<(N + 7) / 8, 256, 0, stream>>>(h1b, al_s, al_d, cnt, csr, b1,
                                                             nullptr, o1hi, N);

    // ---- 5: layer-2 MFMA GEMM (bf16 A, 2-pass) -> bf16 h2 ----
    {
        dim3 g((N + 63) / 64, 1);
        mfma_gemm_gat<64, 64, 256, 2, 2, 16, false><<<g, 256, 0, stream>>>(
            o1hi, nullptr, w2th, w2tl, h2b, as2, ad2, al_s, al_d, N, HEADS * 16);
    }
    // ---- 6: layer-2 aggregation (S=8, 16B gathers, f32 out) ----
    gat_agg<64, 8, true><<<(N + 31) / 32, 256, 0, stream>>>(h2b, al_s, al_d, cnt + N,
                                                            csr + (size_t)N * CAP, b2,
                                                            out2, nullptr, N);

    // ---- 7: fused mean-pool + FC ----
    pool_fc_kernel<<<64, 256, 0, stream>>>(out2, batch, Wfc, bfc, out, N);
}

// Round 18
// 159.772 us; speedup vs baseline: 1.4138x; 1.0534x over previous
//
#include <hip/hip_runtime.h>
#include <math.h>

#define HEADS 4
#define NEG_SLOPE 0.2f
#define CAP 32   // bucket capacity per node (avg in-degree 8; P(deg>32) ~ 2e-11; clamp guards)

// ---------------- workspace layout (bytes) ----------------
static constexpr size_t OFF_H1B  = 0;
static constexpr size_t OFF_H2B  = 0;
static constexpr size_t OFF_OUT2 = 6400000;
static constexpr size_t OFF_XHI  = 25600000;
static constexpr size_t OFF_XLO  = 38400000;
static constexpr size_t OFF_O1HI = 25600000;   // aliases xhi/xlo (dead by then)
static constexpr size_t OFF_W1TH = 76800000;   // 256x128 bf16 = 64KB
static constexpr size_t OFF_W1TL = 76865536;
static constexpr size_t OFF_W2TH = 76931072;   // 64x256 bf16 = 32KB
static constexpr size_t OFF_W2TL = 76963840;
static constexpr size_t OFF_AS   = 77000000;   // 800,000
static constexpr size_t OFF_AD   = 77800000;   // 800,000
static constexpr size_t OFF_CNT  = 78600064;   // 2N ints
static constexpr size_t OFF_CSR  = 79000128;   // 2N*CAP ints = 12.8 MB

typedef __attribute__((ext_vector_type(8))) short short8;
typedef __attribute__((ext_vector_type(4))) float f32x4;

// ---------------- helpers ----------------
__device__ __forceinline__ float4 f4add(float4 a, float4 b) {
    return make_float4(a.x + b.x, a.y + b.y, a.z + b.z, a.w + b.w);
}
__device__ __forceinline__ float lrelu(float x) { return x > 0.f ? x : NEG_SLOPE * x; }
__device__ __forceinline__ float4 f4lrelu(float4 a) {
    return make_float4(lrelu(a.x), lrelu(a.y), lrelu(a.z), lrelu(a.w));
}
__device__ __forceinline__ float4 f4exp(float4 a) {
    return make_float4(__expf(a.x), __expf(a.y), __expf(a.z), __expf(a.w));
}
__device__ __forceinline__ float pickh(float4 v, int head) {
    float r = v.x;
    r = head == 1 ? v.y : r;
    r = head == 2 ? v.z : r;
    r = head == 3 ? v.w : r;
    return r;
}
__device__ __forceinline__ unsigned short bfr(float x) {
    union { float f; unsigned u; } c; c.f = x;
    unsigned r = c.u + 0x7FFFu + ((c.u >> 16) & 1u);
    return (unsigned short)(r >> 16);
}
__device__ __forceinline__ float bf2f(unsigned short h) {
    union { unsigned u; float f; } c; c.u = ((unsigned)h) << 16;
    return c.f;
}
__device__ __forceinline__ float2 bfpair(unsigned u) {
    union { unsigned a; float f; } lo, hi;
    lo.a = u << 16;
    hi.a = u & 0xffff0000u;
    return make_float2(lo.f, hi.f);
}

// ---------------- fused prep: x-split + W1T/W2T-split + cnt zero ----------------
__global__ void prep_kernel(const float* __restrict__ x, unsigned short* __restrict__ xhi,
                            unsigned short* __restrict__ xlo, int n4,
                            const float* __restrict__ W1, unsigned short* __restrict__ w1th,
                            unsigned short* __restrict__ w1tl,
                            const float* __restrict__ W2, unsigned short* __restrict__ w2th,
                            unsigned short* __restrict__ w2tl,
                            int* __restrict__ cnt, int n2)
{
    const int b = blockIdx.x, t = threadIdx.x;
    if (b < 1024) {
        for (int i = b * 256 + t; i < n4; i += 1024 * 256) {
            float4 v = ((const float4*)x)[i];
            unsigned short h0 = bfr(v.x), h1 = bfr(v.y), h2 = bfr(v.z), h3 = bfr(v.w);
            unsigned short l0 = bfr(v.x - bf2f(h0)), l1 = bfr(v.y - bf2f(h1));
            unsigned short l2 = bfr(v.z - bf2f(h2)), l3 = bfr(v.w - bf2f(h3));
            ((uint2*)xhi)[i] = make_uint2((unsigned)h0 | ((unsigned)h1 << 16),
                                          (unsigned)h2 | ((unsigned)h3 << 16));
            ((uint2*)xlo)[i] = make_uint2((unsigned)l0 | ((unsigned)l1 << 16),
                                          (unsigned)l2 | ((unsigned)l3 << 16));
        }
    } else if (b < 1024 + 128) {
        int idx = (b - 1024) * 256 + t;          // W1: K=128, N=256
        const int K = 128, Nc = 256;
        int k = idx / Nc, n = idx - k * Nc;
        float v = W1[idx];
        unsigned short h = bfr(v);
        w1th[(size_t)n * K + k] = h;
        w1tl[(size_t)n * K + k] = bfr(v - bf2f(h));
    } else if (b < 1024 + 128 + 64) {
        int idx = (b - 1152) * 256 + t;          // W2: K=256, N=64
        const int K = 256, Nc = 64;
        int k = idx / Nc, n = idx - k * Nc;
        float v = W2[idx];
        unsigned short h = bfr(v);
        w2th[(size_t)n * K + k] = h;
        w2tl[(size_t)n * K + k] = bfr(v - bf2f(h));
    } else {
        int idx = (b - 1216) * 256 + t;          // zero cnt[2N] via int4
        if (idx < (n2 >> 2)) ((int4*)cnt)[idx] = make_int4(0, 0, 0, 0);
    }
}

// ---------------- FUSED: layer-1 MFMA GEMM  ||  XCD-affine bucket build -----------
// Blocks [0, GEMM_CNT): GEMM1 (BM=64, BN=128, K=128, 2x2 waves, CPH=64, split-A).
// Blocks [GEMM_CNT, ...): dst-partitioned bucket build (partition = b&7; with
// GEMM_CNT%8==4 the partition->XCD mapping stays consistent).
// The two halves are data-independent; bucket scatter latency hides under MFMA.
__global__ __launch_bounds__(256, 2)
void gemm1_bucket_kernel(const unsigned short* __restrict__ Ahi, const unsigned short* __restrict__ Alo,
                         const unsigned short* __restrict__ BThi, const unsigned short* __restrict__ BTlo,
                         unsigned short* __restrict__ Cb,
                         const float* __restrict__ avec_s, const float* __restrict__ avec_d,
                         float* __restrict__ alpha_s, float* __restrict__ alpha_d,
                         int M, int N, int GX,
                         const int* __restrict__ src1, const int* __restrict__ dst1,
                         const int* __restrict__ src2, const int* __restrict__ dst2,
                         int* __restrict__ cnt, int* __restrict__ csr, int NN, int E)
{
    constexpr int BM = 64, BN = 128, KDIM = 128, WC = 2, CPH = 64;
    constexpr int BK    = 32;
    constexpr int WROWS = 32;           // BM/WR
    constexpr int WCOLS = 64;           // BN/WC
    constexpr int FR    = 2;            // WROWS/16
    constexpr int FC    = 4;            // WCOLS/16
    constexpr int AP    = 1;            // BM*(BK/8)/256
    constexpr int BP    = 2;            // BN*(BK/8)/256

    __shared__ short As_hi[BM * BK], As_lo[BM * BK];
    __shared__ short Bs_hi[BN * BK], Bs_lo[BN * BK];

    const int GEMM_CNT = GX * 2;

    if ((int)blockIdx.x >= GEMM_CNT) {
        // ---------------- bucket half ----------------
        const int b     = blockIdx.x - GEMM_CNT;
        const int part  = b & 7;
        const int chunk = b >> 3;
        const int base  = chunk * 2048 + threadIdx.x;
#pragma unroll
        for (int k = 0; k < 8; ++k) {
            int e = base + k * 256;
            if (e < E) {
                int d = dst1[e];
                if ((d & 7) == part) {
                    int p = atomicAdd(&cnt[d], 1);
                    if (p < CAP) csr[(size_t)d * CAP + p] = src1[e];
                }
            } else if (e < 2 * E) {
                int d = dst2[e - E];
                if ((d & 7) == part) {
                    int p = atomicAdd(&cnt[NN + d], 1);
                    if (p < CAP) csr[((size_t)NN + d) * CAP + p] = src2[e - E];
                }
            }
        }
        return;
    }

    // ---------------- GEMM1 half ----------------
    const int bx = blockIdx.x % GX, by = blockIdx.x / GX;
    const int tid  = threadIdx.x;
    const int w    = tid >> 6, lane = tid & 63;
    const int wr   = w / WC, wc = w % WC;
    const int lrow = lane & 15, lk = lane >> 4;
    const int m0   = bx * BM, n0 = by * BN;

    f32x4 acc[FR][FC];
#pragma unroll
    for (int i = 0; i < FR; ++i)
#pragma unroll
        for (int j = 0; j < FC; ++j) acc[i][j] = (f32x4){0.f, 0.f, 0.f, 0.f};

    short8 rAh[AP], rAl[AP], rBh[BP], rBl[BP];

    auto LOAD = [&](int kb) {
#pragma unroll
        for (int p = 0; p < AP; ++p) {
            int id = p * 256 + tid;
            int r = id >> 2, c = id & 3;
            int row = m0 + r; row = row < M ? row : M - 1;
            size_t off = (size_t)row * KDIM + kb + c * 8;
            rAh[p] = *(const short8*)(Ahi + off);
            rAl[p] = *(const short8*)(Alo + off);
        }
#pragma unroll
        for (int p = 0; p < BP; ++p) {
            int id = p * 256 + tid;
            int r = id >> 2, c = id & 3;
            size_t off = (size_t)(n0 + r) * KDIM + kb + c * 8;
            rBh[p] = *(const short8*)(BThi + off);
            rBl[p] = *(const short8*)(BTlo + off);
        }
    };
    auto STORE = [&]() {
#pragma unroll
        for (int p = 0; p < AP; ++p) {
            int id = p * 256 + tid;
            int r = id >> 2, c = id & 3;
            *(short8*)(&As_hi[r * BK + c * 8]) = rAh[p];
            *(short8*)(&As_lo[r * BK + c * 8]) = rAl[p];
        }
#pragma unroll
        for (int p = 0; p < BP; ++p) {
            int id = p * 256 + tid;
            int r = id >> 2, c = id & 3;
            *(short8*)(&Bs_hi[r * BK + c * 8]) = rBh[p];
            *(short8*)(&Bs_lo[r * BK + c * 8]) = rBl[p];
        }
    };

    constexpr int NT = KDIM / BK;
    LOAD(0);
    for (int t = 0; t < NT; ++t) {
        STORE();
        __syncthreads();
        if (t + 1 < NT) LOAD((t + 1) * BK);

        short8 afh[FR], afl[FR], bfh[FC], bfl[FC];
#pragma unroll
        for (int fr = 0; fr < FR; ++fr) {
            int r = wr * WROWS + fr * 16 + lrow;
            afh[fr] = *(const short8*)(&As_hi[r * BK + lk * 8]);
            afl[fr] = *(const short8*)(&As_lo[r * BK + lk * 8]);
        }
#pragma unroll
        for (int fc = 0; fc < FC; ++fc) {
            int r = wc * WCOLS + fc * 16 + lrow;
            bfh[fc] = *(const short8*)(&Bs_hi[r * BK + lk * 8]);
            bfl[fc] = *(const short8*)(&Bs_lo[r * BK + lk * 8]);
        }
#pragma unroll
        for (int fr = 0; fr < FR; ++fr)
#pragma unroll
            for (int fc = 0; fc < FC; ++fc) {
                acc[fr][fc] = __builtin_amdgcn_mfma_f32_16x16x32_bf16(afh[fr], bfh[fc], acc[fr][fc], 0, 0, 0);
                acc[fr][fc] = __builtin_amdgcn_mfma_f32_16x16x32_bf16(afh[fr], bfl[fc], acc[fr][fc], 0, 0, 0);
                acc[fr][fc] = __builtin_amdgcn_mfma_f32_16x16x32_bf16(afl[fr], bfh[fc], acc[fr][fc], 0, 0, 0);
            }
        __syncthreads();
    }

#pragma unroll
    for (int fr = 0; fr < FR; ++fr) {
        const int rbase = m0 + wr * WROWS + fr * 16 + lk * 4;
        float ps[4] = {0.f, 0.f, 0.f, 0.f}, pd[4] = {0.f, 0.f, 0.f, 0.f};
#pragma unroll
        for (int fc = 0; fc < FC; ++fc) {
            const int gc   = n0 + wc * WCOLS + fc * 16 + lrow;
            const int head = gc / CPH, ci = gc % CPH;
            const float asv = avec_s[head * CPH + ci];
            const float adv = avec_d[head * CPH + ci];
#pragma unroll
            for (int rg = 0; rg < 4; ++rg) {
                int row = rbase + rg;
                float v = acc[fr][fc][rg];
                unsigned short uh = bfr(v);
                unsigned up = (unsigned)__shfl_xor((int)(unsigned)uh, 1);
                if (!(lrow & 1) && row < M)
                    *(unsigned*)(Cb + (size_t)row * N + gc) = (unsigned)uh | (up << 16);
                ps[rg] += v * asv;
                pd[rg] += v * adv;
            }
        }
        const int head = (n0 + wc * WCOLS) / CPH;
#pragma unroll
        for (int rg = 0; rg < 4; ++rg) {
            float s = ps[rg], d = pd[rg];
#pragma unroll
            for (int m = 1; m <= 8; m <<= 1) {
                s += __shfl_xor(s, m);
                d += __shfl_xor(d, m);
            }
            if (lrow == 0 && rbase + rg < M) {
                alpha_s[(size_t)(rbase + rg) * HEADS + head] = s;
                alpha_d[(size_t)(rbase + rg) * HEADS + head] = d;
            }
        }
    }
}

// ---------------- MFMA GEMM template (layer 2) ----------------
template<int BM, int BN, int KDIM, int WR, int WC, int CPH, bool ALO>
__global__ __launch_bounds__(256, 2)
void mfma_gemm_gat(const unsigned short* __restrict__ Ahi, const unsigned short* __restrict__ Alo,
                   const unsigned short* __restrict__ BThi, const unsigned short* __restrict__ BTlo,
                   unsigned short* __restrict__ Cb,
                   const float* __restrict__ avec_s, const float* __restrict__ avec_d,
                   float* __restrict__ alpha_s, float* __restrict__ alpha_d,
                   int M, int N)
{
    constexpr int BK    = 32;
    constexpr int WROWS = BM / WR;
    constexpr int WCOLS = BN / WC;
    constexpr int FR    = WROWS / 16;
    constexpr int FC    = WCOLS / 16;
    constexpr int AP    = (BM * (BK / 8)) / 256;
    constexpr int BP    = (BN * (BK / 8)) / 256;
    static_assert(AP >= 1 && BP >= 1, "tile too small");

    __shared__ short As_hi[BM * BK], As_lo[ALO ? BM * BK : 64];
    __shared__ short Bs_hi[BN * BK], Bs_lo[BN * BK];

    const int tid  = threadIdx.x;
    const int w    = tid >> 6, lane = tid & 63;
    const int wr   = w / WC, wc = w % WC;
    const int lrow = lane & 15, lk = lane >> 4;
    const int m0   = blockIdx.x * BM, n0 = blockIdx.y * BN;

    f32x4 acc[FR][FC];
#pragma unroll
    for (int i = 0; i < FR; ++i)
#pragma unroll
        for (int j = 0; j < FC; ++j) acc[i][j] = (f32x4){0.f, 0.f, 0.f, 0.f};

    short8 rAh[AP], rAl[AP], rBh[BP], rBl[BP];

    auto LOAD = [&](int kb) {
#pragma unroll
        for (int p = 0; p < AP; ++p) {
            int id = p * 256 + tid;
            int r = id >> 2, c = id & 3;
            int row = m0 + r; row = row < M ? row : M - 1;
            size_t off = (size_t)row * KDIM + kb + c * 8;
            rAh[p] = *(const short8*)(Ahi + off);
            if constexpr (ALO) rAl[p] = *(const short8*)(Alo + off);
        }
#pragma unroll
        for (int p = 0; p < BP; ++p) {
            int id = p * 256 + tid;
            int r = id >> 2, c = id & 3;
            size_t off = (size_t)(n0 + r) * KDIM + kb + c * 8;
            rBh[p] = *(const short8*)(BThi + off);
            rBl[p] = *(const short8*)(BTlo + off);
        }
    };
    auto STORE = [&]() {
#pragma unroll
        for (int p = 0; p < AP; ++p) {
            int id = p * 256 + tid;
            int r = id >> 2, c = id & 3;
            *(short8*)(&As_hi[r * BK + c * 8]) = rAh[p];
            if constexpr (ALO) *(short8*)(&As_lo[r * BK + c * 8]) = rAl[p];
        }
#pragma unroll
        for (int p = 0; p < BP; ++p) {
            int id = p * 256 + tid;
            int r = id >> 2, c = id & 3;
            *(short8*)(&Bs_hi[r * BK + c * 8]) = rBh[p];
            *(short8*)(&Bs_lo[r * BK + c * 8]) = rBl[p];
        }
    };

    constexpr int NT = KDIM / BK;
    LOAD(0);
    for (int t = 0; t < NT; ++t) {
        STORE();
        __syncthreads();
        if (t + 1 < NT) LOAD((t + 1) * BK);

        short8 afh[FR], afl[FR], bfh[FC], bfl[FC];
#pragma unroll
        for (int fr = 0; fr < FR; ++fr) {
            int r = wr * WROWS + fr * 16 + lrow;
            afh[fr] = *(const short8*)(&As_hi[r * BK + lk * 8]);
            if constexpr (ALO) afl[fr] = *(const short8*)(&As_lo[r * BK + lk * 8]);
        }
#pragma unroll
        for (int fc = 0; fc < FC; ++fc) {
            int r = wc * WCOLS + fc * 16 + lrow;
            bfh[fc] = *(const short8*)(&Bs_hi[r * BK + lk * 8]);
            bfl[fc] = *(const short8*)(&Bs_lo[r * BK + lk * 8]);
        }
#pragma unroll
        for (int fr = 0; fr < FR; ++fr)
#pragma unroll
            for (int fc = 0; fc < FC; ++fc) {
                acc[fr][fc] = __builtin_amdgcn_mfma_f32_16x16x32_bf16(afh[fr], bfh[fc], acc[fr][fc], 0, 0, 0);
                acc[fr][fc] = __builtin_amdgcn_mfma_f32_16x16x32_bf16(afh[fr], bfl[fc], acc[fr][fc], 0, 0, 0);
                if constexpr (ALO)
                    acc[fr][fc] = __builtin_amdgcn_mfma_f32_16x16x32_bf16(afl[fr], bfh[fc], acc[fr][fc], 0, 0, 0);
            }
        __syncthreads();
    }

#pragma unroll
    for (int fr = 0; fr < FR; ++fr) {
        const int rbase = m0 + wr * WROWS + fr * 16 + lk * 4;
        float ps[4] = {0.f, 0.f, 0.f, 0.f}, pd[4] = {0.f, 0.f, 0.f, 0.f};
#pragma unroll
        for (int fc = 0; fc < FC; ++fc) {
            const int gc   = n0 + wc * WCOLS + fc * 16 + lrow;
            const int head = gc / CPH, ci = gc % CPH;
            const float asv = avec_s[head * CPH + ci];
            const float adv = avec_d[head * CPH + ci];
#pragma unroll
            for (int rg = 0; rg < 4; ++rg) {
                int row = rbase + rg;
                float v = acc[fr][fc][rg];
                unsigned short uh = bfr(v);
                unsigned up = (unsigned)__shfl_xor((int)(unsigned)uh, 1);
                if (!(lrow & 1) && row < M)
                    *(unsigned*)(Cb + (size_t)row * N + gc) = (unsigned)uh | (up << 16);
                ps[rg] += v * asv;
                pd[rg] += v * adv;
            }
            if constexpr (CPH == 16) {
#pragma unroll
                for (int rg = 0; rg < 4; ++rg) {
                    float s = ps[rg], d = pd[rg];
#pragma unroll
                    for (int m = 1; m <= 8; m <<= 1) {
                        s += __shfl_xor(s, m);
                        d += __shfl_xor(d, m);
                    }
                    if (lrow == 0 && rbase + rg < M) {
                        alpha_s[(size_t)(rbase + rg) * HEADS + head] = s;
                        alpha_d[(size_t)(rbase + rg) * HEADS + head] = d;
                    }
                    ps[rg] = 0.f; pd[rg] = 0.f;
                }
            }
        }
        if constexpr (CPH != 16) {
            const int head = (n0 + wc * WCOLS) / CPH;
#pragma unroll
            for (int rg = 0; rg < 4; ++rg) {
                float s = ps[rg], d = pd[rg];
#pragma unroll
                for (int m = 1; m <= 8; m <<= 1) {
                    s += __shfl_xor(s, m);
                    d += __shfl_xor(d, m);
                }
                if (lrow == 0 && rbase + rg < M) {
                    alpha_s[(size_t)(rbase + rg) * HEADS + head] = s;
                    alpha_d[(size_t)(rbase + rg) * HEADS + head] = d;
                }
            }
        }
    }
}

// ---------------- GAT softmax + aggregation (bucket CSR) ----------------
template<int CH, int S, bool OUTF32>
__global__ __launch_bounds__(256)
void gat_agg(const unsigned short* __restrict__ hb, const float* __restrict__ alpha_s,
             const float* __restrict__ alpha_d, const int* __restrict__ cnt,
             const int* __restrict__ csr, const float* __restrict__ bias,
             float* __restrict__ out, unsigned short* __restrict__ out_hi, int n)
{
    constexpr int CPL = CH / S;
    constexpr int NSG = 256 / S;
    static_assert(CPL == 8, "lane owns one uint4");
    __shared__ float wls[NSG][S * 5];
    const int tid    = threadIdx.x;
    const int sub    = tid / S;
    const int i      = tid % S;
    const int lane64 = tid & 63;
    const int base   = lane64 & ~(S - 1);
    const int node   = blockIdx.x * NSG + sub;
    if (node >= n) return;
    const int head = (i * CPL) / (CH / 4);
    const int deg = min(cnt[node], CAP);
    const size_t ebase = (size_t)node * CAP;

    const float4 asn = *(const float4*)(alpha_s + (size_t)node * 4);
    const float4 adn = *(const float4*)(alpha_d + (size_t)node * 4);
    float4 den = f4exp(f4lrelu(f4add(asn, adn)));
    const float wse = pickh(den, head);

    float acc[8];
    {
        uint4 hv = *(const uint4*)(hb + (size_t)node * CH + i * 8);
        float2 q0 = bfpair(hv.x), q1 = bfpair(hv.y), q2 = bfpair(hv.z), q3 = bfpair(hv.w);
        acc[0] = wse * q0.x; acc[1] = wse * q0.y; acc[2] = wse * q1.x; acc[3] = wse * q1.y;
        acc[4] = wse * q2.x; acc[5] = wse * q2.y; acc[6] = wse * q3.x; acc[7] = wse * q3.y;
    }

    for (int ch = 0; ch < deg; ch += S) {
        const int cntc = min(S, deg - ch);
        float4 w4 = make_float4(0.f, 0.f, 0.f, 0.f);
        int sl = 0;
        if (i < cntc) {
            sl = csr[ebase + ch + i];
            float4 al = *(const float4*)(alpha_s + (size_t)sl * 4);
            w4 = f4exp(f4lrelu(f4add(al, adn)));
        }
        float4 t = w4;
#pragma unroll
        for (int d = S / 2; d >= 1; d >>= 1) {
            t.x += __shfl_xor(t.x, d);
            t.y += __shfl_xor(t.y, d);
            t.z += __shfl_xor(t.z, d);
            t.w += __shfl_xor(t.w, d);
        }
        den = f4add(den, t);
        wls[sub][i * 5 + 0] = w4.x;
        wls[sub][i * 5 + 1] = w4.y;
        wls[sub][i * 5 + 2] = w4.z;
        wls[sub][i * 5 + 3] = w4.w;

        const int padded = (cntc + 7) & ~7;
        for (int j = 0; j < padded; j += 8) {
            int   sk[8];
            float wk[8];
#pragma unroll
            for (int k = 0; k < 8; ++k) {
                sk[k] = __shfl(sl, base + ((j + k) < S ? (j + k) : 0));
                wk[k] = wls[sub][(j + k) * 5 + head];
            }
            uint4 v[8];
#pragma unroll
            for (int k = 0; k < 8; ++k)
                v[k] = *(const uint4*)(hb + (size_t)sk[k] * CH + i * 8);
#pragma unroll
            for (int k = 0; k < 8; ++k) {
                float2 q0 = bfpair(v[k].x), q1 = bfpair(v[k].y);
                float2 q2 = bfpair(v[k].z), q3 = bfpair(v[k].w);
                acc[0] += wk[k] * q0.x; acc[1] += wk[k] * q0.y;
                acc[2] += wk[k] * q1.x; acc[3] += wk[k] * q1.y;
                acc[4] += wk[k] * q2.x; acc[5] += wk[k] * q2.y;
                acc[6] += wk[k] * q3.x; acc[7] += wk[k] * q3.y;
            }
        }
    }

    const float invd = 1.0f / (pickh(den, head) + 1e-16f);
    const int c0 = i * CPL;
    float o[8];
#pragma unroll
    for (int k = 0; k < 8; ++k)
        o[k] = fmaxf(acc[k] * invd + bias[c0 + k], 0.f);
    if constexpr (OUTF32) {
        *(float4*)(out + (size_t)node * CH + c0)     = make_float4(o[0], o[1], o[2], o[3]);
        *(float4*)(out + (size_t)node * CH + c0 + 4) = make_float4(o[4], o[5], o[6], o[7]);
    } else {
        unsigned short oh[8];
#pragma unroll
        for (int k = 0; k < 8; ++k) oh[k] = bfr(o[k]);
        uint4 ph;
        ph.x = (unsigned)oh[0] | ((unsigned)oh[1] << 16);
        ph.y = (unsigned)oh[2] | ((unsigned)oh[3] << 16);
        ph.z = (unsigned)oh[4] | ((unsigned)oh[5] << 16);
        ph.w = (unsigned)oh[6] | ((unsigned)oh[7] << 16);
        *(uint4*)(out_hi + (size_t)node * CH + c0) = ph;
    }
}

// ---------------- fused mean-pool/FC (per-block binary search) ----------------
__global__ __launch_bounds__(256)
void pool_fc_kernel(const float* __restrict__ feat, const int* __restrict__ batch,
                    const float* __restrict__ Wfc, const float* __restrict__ bfc,
                    float* __restrict__ out, int n)
{
    __shared__ float4 part[16][16];
    __shared__ float pooled[64];
    __shared__ int sb[2];
    const int g = blockIdx.x;
    const int t = threadIdx.x;
    if (t < 2) {
        int target = g + t;
        int lo = 0, hi = n;
        while (lo < hi) {
            int mid = (lo + hi) >> 1;
            if (batch[mid] < target) lo = mid + 1; else hi = mid;
        }
        sb[t] = lo;
    }
    __syncthreads();
    const int s0 = sb[0], s1 = sb[1];
    const int q = t & 15, ns = t >> 4;
    float4 acc = make_float4(0.f, 0.f, 0.f, 0.f);
    for (int i = s0 + ns; i < s1; i += 16)
        acc = f4add(acc, *(const float4*)(feat + (size_t)i * 64 + q * 4));
    part[ns][q] = acc;
    __syncthreads();
    if (t < 16) {
        float4 s = part[0][t];
#pragma unroll
        for (int k = 1; k < 16; ++k) s = f4add(s, part[k][t]);
        float inv = 1.0f / fmaxf((float)(s1 - s0), 1.0f);
        pooled[t * 4 + 0] = s.x * inv;
        pooled[t * 4 + 1] = s.y * inv;
        pooled[t * 4 + 2] = s.z * inv;
        pooled[t * 4 + 3] = s.w * inv;
    }
    __syncthreads();
    if (t < 2) {
        float a = bfc[t];
        for (int c = 0; c < 64; ++c) a += pooled[c] * Wfc[c * 2 + t];
        out[g * 2 + t] = a;
    }
}

// ---------------- launch ----------------
extern "C" void kernel_launch(void* const* d_in, const int* in_sizes, int n_in,
                              void* d_out, int out_size, void* d_ws, size_t ws_size,
                              hipStream_t stream)
{
    const float* x    = (const float*)d_in[0];
    const int*   ei   = (const int*)d_in[1];
    const int*   batch= (const int*)d_in[2];
    const float* W1   = (const float*)d_in[3];
    const float* as1  = (const float*)d_in[4];
    const float* ad1  = (const float*)d_in[5];
    const float* b1   = (const float*)d_in[6];
    const float* W2   = (const float*)d_in[7];
    const float* as2  = (const float*)d_in[8];
    const float* ad2  = (const float*)d_in[9];
    const float* b2   = (const float*)d_in[10];
    const float* Wfc  = (const float*)d_in[11];
    const float* bfc  = (const float*)d_in[12];
    float* out = (float*)d_out;

    const int N = in_sizes[2];          // 50000 nodes
    const int E = in_sizes[1] / 27;     // 400000 edges
    const int F = in_sizes[0] / N;      // 128

    char* ws = (char*)d_ws;
    unsigned short* h1b   = (unsigned short*)(ws + OFF_H1B);
    unsigned short* h2b   = (unsigned short*)(ws + OFF_H2B);
    float*          out2  = (float*)(ws + OFF_OUT2);
    unsigned short* xhi   = (unsigned short*)(ws + OFF_XHI);
    unsigned short* xlo   = (unsigned short*)(ws + OFF_XLO);
    unsigned short* o1hi  = (unsigned short*)(ws + OFF_O1HI);
    unsigned short* w1th  = (unsigned short*)(ws + OFF_W1TH);
    unsigned short* w1tl  = (unsigned short*)(ws + OFF_W1TL);
    unsigned short* w2th  = (unsigned short*)(ws + OFF_W2TH);
    unsigned short* w2tl  = (unsigned short*)(ws + OFF_W2TL);
    float* al_s  = (float*)(ws + OFF_AS);
    float* al_d  = (float*)(ws + OFF_AD);
    int*   cnt   = (int*)(ws + OFF_CNT);    // 2N counts (layer2 view = cnt+N)
    int*   csr   = (int*)(ws + OFF_CSR);    // 2N*CAP bucket table

    const int NCH = (2 * E + 2047) / 2048;         // 391 edge chunks
    const int ZB  = ((2 * N / 4) + 255) / 256;     // 98 zero-blocks in prep
    const int GX  = (N + 63) / 64;                 // 782 gemm1 blocks per col-half

    // ---- 1: fused prep (x split + W splits + cnt zero) ----
    prep_kernel<<<1216 + ZB, 256, 0, stream>>>(x, xhi, xlo, N * F / 4,
                                               W1, w1th, w1tl, W2, w2th, w2tl,
                                               cnt, 2 * N);

    // ---- 2: FUSED layer-1 GEMM || bucket build ----
    gemm1_bucket_kernel<<<GX * 2 + NCH * 8, 256, 0, stream>>>(
        xhi, xlo, w1th, w1tl, h1b, as1, ad1, al_s, al_d, N, HEADS * 64, GX,
        ei + 17 * (size_t)E, ei + 26 * (size_t)E,
        ei + 15 * (size_t)E, ei + 16 * (size_t)E,
        cnt, csr, N, E);

    // ---- 3: layer-1 aggregation (S=32, bf16 hi out) ----
    gat_agg<256, 32, false><<<(N + 7) / 8, 256, 0, stream>>>(h1b, al_s, al_d, cnt, csr, b1,
                                                             nullptr, o1hi, N);

    // ---- 4: layer-2 MFMA GEMM (bf16 A, 2-pass) -> bf16 h2 ----
    {
        dim3 g((N + 63) / 64, 1);
        mfma_gemm_gat<64, 64, 256, 2, 2, 16, false><<<g, 256, 0, stream>>>(
            o1hi, nullptr, w2th, w2tl, h2b, as2, ad2, al_s, al_d, N, HEADS * 16);
    }
    // ---- 5: layer-2 aggregation (S=8, 16B gathers, f32 out) ----
    gat_agg<64, 8, true><<<(N + 31) / 32, 256, 0, stream>>>(h2b, al_s, al_d, cnt + N,
                                                            csr + (size_t)N * CAP, b2,
                                                            out2, nullptr, N);

    // ---- 6: fused mean-pool + FC ----
    pool_fc_kernel<<<64, 256, 0, stream>>>(out2, batch, Wfc, bfc, out, N);
}

// Round 19
// 151.954 us; speedup vs baseline: 1.4865x; 1.0514x over previous
//
#include <hip/hip_runtime.h>
#include <math.h>

#define HEADS 4
#define NEG_SLOPE 0.2f
#define CAP 32   // bucket capacity per node (avg in-degree 8; P(deg>32) ~ 2e-11; clamp guards)

// ---------------- workspace layout (bytes) ----------------
static constexpr size_t OFF_H1B  = 0;
static constexpr size_t OFF_H2B  = 0;
static constexpr size_t OFF_OUT2 = 6400000;
static constexpr size_t OFF_XHI  = 25600000;
static constexpr size_t OFF_XLO  = 38400000;
static constexpr size_t OFF_O1HI = 25600000;   // aliases xhi/xlo (dead by then)
static constexpr size_t OFF_W1TH = 76800000;   // 256x128 bf16 = 64KB
static constexpr size_t OFF_W1TL = 76865536;
static constexpr size_t OFF_W2TH = 76931072;   // 64x256 bf16 = 32KB
static constexpr size_t OFF_W2TL = 76963840;
static constexpr size_t OFF_AS   = 77000000;   // 800,000
static constexpr size_t OFF_AD   = 77800000;   // 800,000
static constexpr size_t OFF_CNT  = 78600064;   // 2N ints
static constexpr size_t OFF_CSR  = 79000128;   // 2N*CAP ints = 12.8 MB

typedef __attribute__((ext_vector_type(8))) short short8;
typedef __attribute__((ext_vector_type(4))) float f32x4;

// ---------------- helpers ----------------
__device__ __forceinline__ float4 f4add(float4 a, float4 b) {
    return make_float4(a.x + b.x, a.y + b.y, a.z + b.z, a.w + b.w);
}
__device__ __forceinline__ float lrelu(float x) { return x > 0.f ? x : NEG_SLOPE * x; }
__device__ __forceinline__ float4 f4lrelu(float4 a) {
    return make_float4(lrelu(a.x), lrelu(a.y), lrelu(a.z), lrelu(a.w));
}
__device__ __forceinline__ float4 f4exp(float4 a) {
    return make_float4(__expf(a.x), __expf(a.y), __expf(a.z), __expf(a.w));
}
__device__ __forceinline__ float pickh(float4 v, int head) {
    float r = v.x;
    r = head == 1 ? v.y : r;
    r = head == 2 ? v.z : r;
    r = head == 3 ? v.w : r;
    return r;
}
__device__ __forceinline__ unsigned short bfr(float x) {
    union { float f; unsigned u; } c; c.f = x;
    unsigned r = c.u + 0x7FFFu + ((c.u >> 16) & 1u);
    return (unsigned short)(r >> 16);
}
__device__ __forceinline__ float bf2f(unsigned short h) {
    union { unsigned u; float f; } c; c.u = ((unsigned)h) << 16;
    return c.f;
}
__device__ __forceinline__ float2 bfpair(unsigned u) {
    union { unsigned a; float f; } lo, hi;
    lo.a = u << 16;
    hi.a = u & 0xffff0000u;
    return make_float2(lo.f, hi.f);
}

// ---------------- fused prep: x-split + W1T/W2T-split + cnt zero ----------------
__global__ void prep_kernel(const float* __restrict__ x, unsigned short* __restrict__ xhi,
                            unsigned short* __restrict__ xlo, int n4,
                            const float* __restrict__ W1, unsigned short* __restrict__ w1th,
                            unsigned short* __restrict__ w1tl,
                            const float* __restrict__ W2, unsigned short* __restrict__ w2th,
                            unsigned short* __restrict__ w2tl,
                            int* __restrict__ cnt, int n2)
{
    const int b = blockIdx.x, t = threadIdx.x;
    if (b < 1024) {
        for (int i = b * 256 + t; i < n4; i += 1024 * 256) {
            float4 v = ((const float4*)x)[i];
            unsigned short h0 = bfr(v.x), h1 = bfr(v.y), h2 = bfr(v.z), h3 = bfr(v.w);
            unsigned short l0 = bfr(v.x - bf2f(h0)), l1 = bfr(v.y - bf2f(h1));
            unsigned short l2 = bfr(v.z - bf2f(h2)), l3 = bfr(v.w - bf2f(h3));
            ((uint2*)xhi)[i] = make_uint2((unsigned)h0 | ((unsigned)h1 << 16),
                                          (unsigned)h2 | ((unsigned)h3 << 16));
            ((uint2*)xlo)[i] = make_uint2((unsigned)l0 | ((unsigned)l1 << 16),
                                          (unsigned)l2 | ((unsigned)l3 << 16));
        }
    } else if (b < 1024 + 128) {
        int idx = (b - 1024) * 256 + t;          // W1: K=128, N=256
        const int K = 128, Nc = 256;
        int k = idx / Nc, n = idx - k * Nc;
        float v = W1[idx];
        unsigned short h = bfr(v);
        w1th[(size_t)n * K + k] = h;
        w1tl[(size_t)n * K + k] = bfr(v - bf2f(h));
    } else if (b < 1024 + 128 + 64) {
        int idx = (b - 1152) * 256 + t;          // W2: K=256, N=64
        const int K = 256, Nc = 64;
        int k = idx / Nc, n = idx - k * Nc;
        float v = W2[idx];
        unsigned short h = bfr(v);
        w2th[(size_t)n * K + k] = h;
        w2tl[(size_t)n * K + k] = bfr(v - bf2f(h));
    } else {
        int idx = (b - 1216) * 256 + t;          // zero cnt[2N] via int4
        if (idx < (n2 >> 2)) ((int4*)cnt)[idx] = make_int4(0, 0, 0, 0);
    }
}

// ---------------- FUSED + INTERLEAVED: layer-1 GEMM || bucket build --------------
// Blocks processed in groups of 24: offsets 0-7 = GEMM blocks, 8-23 = bucket
// blocks (1:2 ratio). 24 % 8 == 0 keeps blockIdx%8 stable within a group, so
// bucket partition (= blockIdx&7) retains XCD affinity while both populations
// are co-resident from the start (bucket scatter latency hides under MFMA).
__global__ __launch_bounds__(256, 2)
void gemm1_bucket_kernel(const unsigned short* __restrict__ Ahi, const unsigned short* __restrict__ Alo,
                         const unsigned short* __restrict__ BThi, const unsigned short* __restrict__ BTlo,
                         unsigned short* __restrict__ Cb,
                         const float* __restrict__ avec_s, const float* __restrict__ avec_d,
                         float* __restrict__ alpha_s, float* __restrict__ alpha_d,
                         int M, int N, int GX, int NCHUNK,
                         const int* __restrict__ src1, const int* __restrict__ dst1,
                         const int* __restrict__ src2, const int* __restrict__ dst2,
                         int* __restrict__ cnt, int* __restrict__ csr, int NN, int E)
{
    constexpr int BM = 64, BN = 128, KDIM = 128, WC = 2, CPH = 64;
    constexpr int BK    = 32;
    constexpr int WROWS = 32;           // BM/WR
    constexpr int WCOLS = 64;           // BN/WC
    constexpr int FR    = 2;            // WROWS/16
    constexpr int FC    = 4;            // WCOLS/16
    constexpr int AP    = 1;            // BM*(BK/8)/256
    constexpr int BP    = 2;            // BN*(BK/8)/256

    __shared__ short As_hi[BM * BK], As_lo[BM * BK];
    __shared__ short Bs_hi[BN * BK], Bs_lo[BN * BK];

    const int group = blockIdx.x / 24;
    const int off   = blockIdx.x % 24;
    const int GEMM_CNT = GX * 2;

    if (off >= 8) {
        // ---------------- bucket block ----------------
        const int part  = blockIdx.x & 7;            // == off&7 (24*group ≡ 0 mod 8)
        const int chunk = group * 2 + (off >= 16);
        if (chunk >= NCHUNK) return;
        const int base = chunk * 2048 + threadIdx.x;
#pragma unroll
        for (int k = 0; k < 8; ++k) {
            int e = base + k * 256;
            if (e < E) {
                int d = dst1[e];
                if ((d & 7) == part) {
                    int p = atomicAdd(&cnt[d], 1);
                    if (p < CAP) csr[(size_t)d * CAP + p] = src1[e];
                }
            } else if (e < 2 * E) {
                int d = dst2[e - E];
                if ((d & 7) == part) {
                    int p = atomicAdd(&cnt[NN + d], 1);
                    if (p < CAP) csr[((size_t)NN + d) * CAP + p] = src2[e - E];
                }
            }
        }
        return;
    }

    // ---------------- GEMM block ----------------
    const int gid = group * 8 + off;
    if (gid >= GEMM_CNT) return;
    const int bx = gid % GX, by = gid / GX;
    const int tid  = threadIdx.x;
    const int w    = tid >> 6, lane = tid & 63;
    const int wr   = w / WC, wc = w % WC;
    const int lrow = lane & 15, lk = lane >> 4;
    const int m0   = bx * BM, n0 = by * BN;

    f32x4 acc[FR][FC];
#pragma unroll
    for (int i = 0; i < FR; ++i)
#pragma unroll
        for (int j = 0; j < FC; ++j) acc[i][j] = (f32x4){0.f, 0.f, 0.f, 0.f};

    short8 rAh[AP], rAl[AP], rBh[BP], rBl[BP];

    auto LOAD = [&](int kb) {
#pragma unroll
        for (int p = 0; p < AP; ++p) {
            int id = p * 256 + tid;
            int r = id >> 2, c = id & 3;
            int row = m0 + r; row = row < M ? row : M - 1;
            size_t offb = (size_t)row * KDIM + kb + c * 8;
            rAh[p] = *(const short8*)(Ahi + offb);
            rAl[p] = *(const short8*)(Alo + offb);
        }
#pragma unroll
        for (int p = 0; p < BP; ++p) {
            int id = p * 256 + tid;
            int r = id >> 2, c = id & 3;
            size_t offb = (size_t)(n0 + r) * KDIM + kb + c * 8;
            rBh[p] = *(const short8*)(BThi + offb);
            rBl[p] = *(const short8*)(BTlo + offb);
        }
    };
    auto STORE = [&]() {
#pragma unroll
        for (int p = 0; p < AP; ++p) {
            int id = p * 256 + tid;
            int r = id >> 2, c = id & 3;
            *(short8*)(&As_hi[r * BK + c * 8]) = rAh[p];
            *(short8*)(&As_lo[r * BK + c * 8]) = rAl[p];
        }
#pragma unroll
        for (int p = 0; p < BP; ++p) {
            int id = p * 256 + tid;
            int r = id >> 2, c = id & 3;
            *(short8*)(&Bs_hi[r * BK + c * 8]) = rBh[p];
            *(short8*)(&Bs_lo[r * BK + c * 8]) = rBl[p];
        }
    };

    constexpr int NT = KDIM / BK;
    LOAD(0);
    for (int t = 0; t < NT; ++t) {
        STORE();
        __syncthreads();
        if (t + 1 < NT) LOAD((t + 1) * BK);

        short8 afh[FR], afl[FR], bfh[FC], bfl[FC];
#pragma unroll
        for (int fr = 0; fr < FR; ++fr) {
            int r = wr * WROWS + fr * 16 + lrow;
            afh[fr] = *(const short8*)(&As_hi[r * BK + lk * 8]);
            afl[fr] = *(const short8*)(&As_lo[r * BK + lk * 8]);
        }
#pragma unroll
        for (int fc = 0; fc < FC; ++fc) {
            int r = wc * WCOLS + fc * 16 + lrow;
            bfh[fc] = *(const short8*)(&Bs_hi[r * BK + lk * 8]);
            bfl[fc] = *(const short8*)(&Bs_lo[r * BK + lk * 8]);
        }
#pragma unroll
        for (int fr = 0; fr < FR; ++fr)
#pragma unroll
            for (int fc = 0; fc < FC; ++fc) {
                acc[fr][fc] = __builtin_amdgcn_mfma_f32_16x16x32_bf16(afh[fr], bfh[fc], acc[fr][fc], 0, 0, 0);
                acc[fr][fc] = __builtin_amdgcn_mfma_f32_16x16x32_bf16(afh[fr], bfl[fc], acc[fr][fc], 0, 0, 0);
                acc[fr][fc] = __builtin_amdgcn_mfma_f32_16x16x32_bf16(afl[fr], bfh[fc], acc[fr][fc], 0, 0, 0);
            }
        __syncthreads();
    }

#pragma unroll
    for (int fr = 0; fr < FR; ++fr) {
        const int rbase = m0 + wr * WROWS + fr * 16 + lk * 4;
        float ps[4] = {0.f, 0.f, 0.f, 0.f}, pd[4] = {0.f, 0.f, 0.f, 0.f};
#pragma unroll
        for (int fc = 0; fc < FC; ++fc) {
            const int gc   = n0 + wc * WCOLS + fc * 16 + lrow;
            const int head = gc / CPH, ci = gc % CPH;
            const float asv = avec_s[head * CPH + ci];
            const float adv = avec_d[head * CPH + ci];
#pragma unroll
            for (int rg = 0; rg < 4; ++rg) {
                int row = rbase + rg;
                float v = acc[fr][fc][rg];
                unsigned short uh = bfr(v);
                unsigned up = (unsigned)__shfl_xor((int)(unsigned)uh, 1);
                if (!(lrow & 1) && row < M)
                    *(unsigned*)(Cb + (size_t)row * N + gc) = (unsigned)uh | (up << 16);
                ps[rg] += v * asv;
                pd[rg] += v * adv;
            }
        }
        const int head = (n0 + wc * WCOLS) / CPH;
#pragma unroll
        for (int rg = 0; rg < 4; ++rg) {
            float s = ps[rg], d = pd[rg];
#pragma unroll
            for (int m = 1; m <= 8; m <<= 1) {
                s += __shfl_xor(s, m);
                d += __shfl_xor(d, m);
            }
            if (lrow == 0 && rbase + rg < M) {
                alpha_s[(size_t)(rbase + rg) * HEADS + head] = s;
                alpha_d[(size_t)(rbase + rg) * HEADS + head] = d;
            }
        }
    }
}

// ---------------- MFMA GEMM template (layer 2) ----------------
template<int BM, int BN, int KDIM, int WR, int WC, int CPH, bool ALO>
__global__ __launch_bounds__(256, 2)
void mfma_gemm_gat(const unsigned short* __restrict__ Ahi, const unsigned short* __restrict__ Alo,
                   const unsigned short* __restrict__ BThi, const unsigned short* __restrict__ BTlo,
                   unsigned short* __restrict__ Cb,
                   const float* __restrict__ avec_s, const float* __restrict__ avec_d,
                   float* __restrict__ alpha_s, float* __restrict__ alpha_d,
                   int M, int N)
{
    constexpr int BK    = 32;
    constexpr int WROWS = BM / WR;
    constexpr int WCOLS = BN / WC;
    constexpr int FR    = WROWS / 16;
    constexpr int FC    = WCOLS / 16;
    constexpr int AP    = (BM * (BK / 8)) / 256;
    constexpr int BP    = (BN * (BK / 8)) / 256;
    static_assert(AP >= 1 && BP >= 1, "tile too small");

    __shared__ short As_hi[BM * BK], As_lo[ALO ? BM * BK : 64];
    __shared__ short Bs_hi[BN * BK], Bs_lo[BN * BK];

    const int tid  = threadIdx.x;
    const int w    = tid >> 6, lane = tid & 63;
    const int wr   = w / WC, wc = w % WC;
    const int lrow = lane & 15, lk = lane >> 4;
    const int m0   = blockIdx.x * BM, n0 = blockIdx.y * BN;

    f32x4 acc[FR][FC];
#pragma unroll
    for (int i = 0; i < FR; ++i)
#pragma unroll
        for (int j = 0; j < FC; ++j) acc[i][j] = (f32x4){0.f, 0.f, 0.f, 0.f};

    short8 rAh[AP], rAl[AP], rBh[BP], rBl[BP];

    auto LOAD = [&](int kb) {
#pragma unroll
        for (int p = 0; p < AP; ++p) {
            int id = p * 256 + tid;
            int r = id >> 2, c = id & 3;
            int row = m0 + r; row = row < M ? row : M - 1;
            size_t off = (size_t)row * KDIM + kb + c * 8;
            rAh[p] = *(const short8*)(Ahi + off);
            if constexpr (ALO) rAl[p] = *(const short8*)(Alo + off);
        }
#pragma unroll
        for (int p = 0; p < BP; ++p) {
            int id = p * 256 + tid;
            int r = id >> 2, c = id & 3;
            size_t off = (size_t)(n0 + r) * KDIM + kb + c * 8;
            rBh[p] = *(const short8*)(BThi + off);
            rBl[p] = *(const short8*)(BTlo + off);
        }
    };
    auto STORE = [&]() {
#pragma unroll
        for (int p = 0; p < AP; ++p) {
            int id = p * 256 + tid;
            int r = id >> 2, c = id & 3;
            *(short8*)(&As_hi[r * BK + c * 8]) = rAh[p];
            if constexpr (ALO) *(short8*)(&As_lo[r * BK + c * 8]) = rAl[p];
        }
#pragma unroll
        for (int p = 0; p < BP; ++p) {
            int id = p * 256 + tid;
            int r = id >> 2, c = id & 3;
            *(short8*)(&Bs_hi[r * BK + c * 8]) = rBh[p];
            *(short8*)(&Bs_lo[r * BK + c * 8]) = rBl[p];
        }
    };

    constexpr int NT = KDIM / BK;
    LOAD(0);
    for (int t = 0; t < NT; ++t) {
        STORE();
        __syncthreads();
        if (t + 1 < NT) LOAD((t + 1) * BK);

        short8 afh[FR], afl[FR], bfh[FC], bfl[FC];
#pragma unroll
        for (int fr = 0; fr < FR; ++fr) {
            int r = wr * WROWS + fr * 16 + lrow;
            afh[fr] = *(const short8*)(&As_hi[r * BK + lk * 8]);
            if constexpr (ALO) afl[fr] = *(const short8*)(&As_lo[r * BK + lk * 8]);
        }
#pragma unroll
        for (int fc = 0; fc < FC; ++fc) {
            int r = wc * WCOLS + fc * 16 + lrow;
            bfh[fc] = *(const short8*)(&Bs_hi[r * BK + lk * 8]);
            bfl[fc] = *(const short8*)(&Bs_lo[r * BK + lk * 8]);
        }
#pragma unroll
        for (int fr = 0; fr < FR; ++fr)
#pragma unroll
            for (int fc = 0; fc < FC; ++fc) {
                acc[fr][fc] = __builtin_amdgcn_mfma_f32_16x16x32_bf16(afh[fr], bfh[fc], acc[fr][fc], 0, 0, 0);
                acc[fr][fc] = __builtin_amdgcn_mfma_f32_16x16x32_bf16(afh[fr], bfl[fc], acc[fr][fc], 0, 0, 0);
                if constexpr (ALO)
                    acc[fr][fc] = __builtin_amdgcn_mfma_f32_16x16x32_bf16(afl[fr], bfh[fc], acc[fr][fc], 0, 0, 0);
            }
        __syncthreads();
    }

#pragma unroll
    for (int fr = 0; fr < FR; ++fr) {
        const int rbase = m0 + wr * WROWS + fr * 16 + lk * 4;
        float ps[4] = {0.f, 0.f, 0.f, 0.f}, pd[4] = {0.f, 0.f, 0.f, 0.f};
#pragma unroll
        for (int fc = 0; fc < FC; ++fc) {
            const int gc   = n0 + wc * WCOLS + fc * 16 + lrow;
            const int head = gc / CPH, ci = gc % CPH;
            const float asv = avec_s[head * CPH + ci];
            const float adv = avec_d[head * CPH + ci];
#pragma unroll
            for (int rg = 0; rg < 4; ++rg) {
                int row = rbase + rg;
                float v = acc[fr][fc][rg];
                unsigned short uh = bfr(v);
                unsigned up = (unsigned)__shfl_xor((int)(unsigned)uh, 1);
                if (!(lrow & 1) && row < M)
                    *(unsigned*)(Cb + (size_t)row * N + gc) = (unsigned)uh | (up << 16);
                ps[rg] += v * asv;
                pd[rg] += v * adv;
            }
            if constexpr (CPH == 16) {
#pragma unroll
                for (int rg = 0; rg < 4; ++rg) {
                    float s = ps[rg], d = pd[rg];
#pragma unroll
                    for (int m = 1; m <= 8; m <<= 1) {
                        s += __shfl_xor(s, m);
                        d += __shfl_xor(d, m);
                    }
                    if (lrow == 0 && rbase + rg < M) {
                        alpha_s[(size_t)(rbase + rg) * HEADS + head] = s;
                        alpha_d[(size_t)(rbase + rg) * HEADS + head] = d;
                    }
                    ps[rg] = 0.f; pd[rg] = 0.f;
                }
            }
        }
        if constexpr (CPH != 16) {
            const int head = (n0 + wc * WCOLS) / CPH;
#pragma unroll
            for (int rg = 0; rg < 4; ++rg) {
                float s = ps[rg], d = pd[rg];
#pragma unroll
                for (int m = 1; m <= 8; m <<= 1) {
                    s += __shfl_xor(s, m);
                    d += __shfl_xor(d, m);
                }
                if (lrow == 0 && rbase + rg < M) {
                    alpha_s[(size_t)(rbase + rg) * HEADS + head] = s;
                    alpha_d[(size_t)(rbase + rg) * HEADS + head] = d;
                }
            }
        }
    }
}

// ---------------- GAT softmax + aggregation (bucket CSR) ----------------
template<int CH, int S, bool OUTF32>
__global__ __launch_bounds__(256)
void gat_agg(const unsigned short* __restrict__ hb, const float* __restrict__ alpha_s,
             const float* __restrict__ alpha_d, const int* __restrict__ cnt,
             const int* __restrict__ csr, const float* __restrict__ bias,
             float* __restrict__ out, unsigned short* __restrict__ out_hi, int n)
{
    constexpr int CPL = CH / S;
    constexpr int NSG = 256 / S;
    static_assert(CPL == 8, "lane owns one uint4");
    __shared__ float wls[NSG][S * 5];
    const int tid    = threadIdx.x;
    const int sub    = tid / S;
    const int i      = tid % S;
    const int lane64 = tid & 63;
    const int base   = lane64 & ~(S - 1);
    const int node   = blockIdx.x * NSG + sub;
    if (node >= n) return;
    const int head = (i * CPL) / (CH / 4);
    const int deg = min(cnt[node], CAP);
    const size_t ebase = (size_t)node * CAP;

    const float4 asn = *(const float4*)(alpha_s + (size_t)node * 4);
    const float4 adn = *(const float4*)(alpha_d + (size_t)node * 4);
    float4 den = f4exp(f4lrelu(f4add(asn, adn)));
    const float wse = pickh(den, head);

    float acc[8];
    {
        uint4 hv = *(const uint4*)(hb + (size_t)node * CH + i * 8);
        float2 q0 = bfpair(hv.x), q1 = bfpair(hv.y), q2 = bfpair(hv.z), q3 = bfpair(hv.w);
        acc[0] = wse * q0.x; acc[1] = wse * q0.y; acc[2] = wse * q1.x; acc[3] = wse * q1.y;
        acc[4] = wse * q2.x; acc[5] = wse * q2.y; acc[6] = wse * q3.x; acc[7] = wse * q3.y;
    }

    for (int ch = 0; ch < deg; ch += S) {
        const int cntc = min(S, deg - ch);
        float4 w4 = make_float4(0.f, 0.f, 0.f, 0.f);
        int sl = 0;
        if (i < cntc) {
            sl = csr[ebase + ch + i];
            float4 al = *(const float4*)(alpha_s + (size_t)sl * 4);
            w4 = f4exp(f4lrelu(f4add(al, adn)));
        }
        float4 t = w4;
#pragma unroll
        for (int d = S / 2; d >= 1; d >>= 1) {
            t.x += __shfl_xor(t.x, d);
            t.y += __shfl_xor(t.y, d);
            t.z += __shfl_xor(t.z, d);
            t.w += __shfl_xor(t.w, d);
        }
        den = f4add(den, t);
        wls[sub][i * 5 + 0] = w4.x;
        wls[sub][i * 5 + 1] = w4.y;
        wls[sub][i * 5 + 2] = w4.z;
        wls[sub][i * 5 + 3] = w4.w;

        const int padded = (cntc + 7) & ~7;
        for (int j = 0; j < padded; j += 8) {
            int   sk[8];
            float wk[8];
#pragma unroll
            for (int k = 0; k < 8; ++k) {
                sk[k] = __shfl(sl, base + ((j + k) < S ? (j + k) : 0));
                wk[k] = wls[sub][(j + k) * 5 + head];
            }
            uint4 v[8];
#pragma unroll
            for (int k = 0; k < 8; ++k)
                v[k] = *(const uint4*)(hb + (size_t)sk[k] * CH + i * 8);
#pragma unroll
            for (int k = 0; k < 8; ++k) {
                float2 q0 = bfpair(v[k].x), q1 = bfpair(v[k].y);
                float2 q2 = bfpair(v[k].z), q3 = bfpair(v[k].w);
                acc[0] += wk[k] * q0.x; acc[1] += wk[k] * q0.y;
                acc[2] += wk[k] * q1.x; acc[3] += wk[k] * q1.y;
                acc[4] += wk[k] * q2.x; acc[5] += wk[k] * q2.y;
                acc[6] += wk[k] * q3.x; acc[7] += wk[k] * q3.y;
            }
        }
    }

    const float invd = 1.0f / (pickh(den, head) + 1e-16f);
    const int c0 = i * CPL;
    float o[8];
#pragma unroll
    for (int k = 0; k < 8; ++k)
        o[k] = fmaxf(acc[k] * invd + bias[c0 + k], 0.f);
    if constexpr (OUTF32) {
        *(float4*)(out + (size_t)node * CH + c0)     = make_float4(o[0], o[1], o[2], o[3]);
        *(float4*)(out + (size_t)node * CH + c0 + 4) = make_float4(o[4], o[5], o[6], o[7]);
    } else {
        unsigned short oh[8];
#pragma unroll
        for (int k = 0; k < 8; ++k) oh[k] = bfr(o[k]);
        uint4 ph;
        ph.x = (unsigned)oh[0] | ((unsigned)oh[1] << 16);
        ph.y = (unsigned)oh[2] | ((unsigned)oh[3] << 16);
        ph.z = (unsigned)oh[4] | ((unsigned)oh[5] << 16);
        ph.w = (unsigned)oh[6] | ((unsigned)oh[7] << 16);
        *(uint4*)(out_hi + (size_t)node * CH + c0) = ph;
    }
}

// ---------------- fused mean-pool/FC (per-block binary search) ----------------
__global__ __launch_bounds__(256)
void pool_fc_kernel(const float* __restrict__ feat, const int* __restrict__ batch,
                    const float* __restrict__ Wfc, const float* __restrict__ bfc,
                    float* __restrict__ out, int n)
{
    __shared__ float4 part[16][16];
    __shared__ float pooled[64];
    __shared__ int sb[2];
    const int g = blockIdx.x;
    const int t = threadIdx.x;
    if (t < 2) {
        int target = g + t;
        int lo = 0, hi = n;
        while (lo < hi) {
            int mid = (lo + hi) >> 1;
            if (batch[mid] < target) lo = mid + 1; else hi = mid;
        }
        sb[t] = lo;
    }
    __syncthreads();
    const int s0 = sb[0], s1 = sb[1];
    const int q = t & 15, ns = t >> 4;
    float4 acc = make_float4(0.f, 0.f, 0.f, 0.f);
    for (int i = s0 + ns; i < s1; i += 16)
        acc = f4add(acc, *(const float4*)(feat + (size_t)i * 64 + q * 4));
    part[ns][q] = acc;
    __syncthreads();
    if (t < 16) {
        float4 s = part[0][t];
#pragma unroll
        for (int k = 1; k < 16; ++k) s = f4add(s, part[k][t]);
        float inv = 1.0f / fmaxf((float)(s1 - s0), 1.0f);
        pooled[t * 4 + 0] = s.x * inv;
        pooled[t * 4 + 1] = s.y * inv;
        pooled[t * 4 + 2] = s.z * inv;
        pooled[t * 4 + 3] = s.w * inv;
    }
    __syncthreads();
    if (t < 2) {
        float a = bfc[t];
        for (int c = 0; c < 64; ++c) a += pooled[c] * Wfc[c * 2 + t];
        out[g * 2 + t] = a;
    }
}

// ---------------- launch ----------------
extern "C" void kernel_launch(void* const* d_in, const int* in_sizes, int n_in,
                              void* d_out, int out_size, void* d_ws, size_t ws_size,
                              hipStream_t stream)
{
    const float* x    = (const float*)d_in[0];
    const int*   ei   = (const int*)d_in[1];
    const int*   batch= (const int*)d_in[2];
    const float* W1   = (const float*)d_in[3];
    const float* as1  = (const float*)d_in[4];
    const float* ad1  = (const float*)d_in[5];
    const float* b1   = (const float*)d_in[6];
    const float* W2   = (const float*)d_in[7];
    const float* as2  = (const float*)d_in[8];
    const float* ad2  = (const float*)d_in[9];
    const float* b2   = (const float*)d_in[10];
    const float* Wfc  = (const float*)d_in[11];
    const float* bfc  = (const float*)d_in[12];
    float* out = (float*)d_out;

    const int N = in_sizes[2];          // 50000 nodes
    const int E = in_sizes[1] / 27;     // 400000 edges
    const int F = in_sizes[0] / N;      // 128

    char* ws = (char*)d_ws;
    unsigned short* h1b   = (unsigned short*)(ws + OFF_H1B);
    unsigned short* h2b   = (unsigned short*)(ws + OFF_H2B);
    float*          out2  = (float*)(ws + OFF_OUT2);
    unsigned short* xhi   = (unsigned short*)(ws + OFF_XHI);
    unsigned short* xlo   = (unsigned short*)(ws + OFF_XLO);
    unsigned short* o1hi  = (unsigned short*)(ws + OFF_O1HI);
    unsigned short* w1th  = (unsigned short*)(ws + OFF_W1TH);
    unsigned short* w1tl  = (unsigned short*)(ws + OFF_W1TL);
    unsigned short* w2th  = (unsigned short*)(ws + OFF_W2TH);
    unsigned short* w2tl  = (unsigned short*)(ws + OFF_W2TL);
    float* al_s  = (float*)(ws + OFF_AS);
    float* al_d  = (float*)(ws + OFF_AD);
    int*   cnt   = (int*)(ws + OFF_CNT);    // 2N counts (layer2 view = cnt+N)
    int*   csr   = (int*)(ws + OFF_CSR);    // 2N*CAP bucket table

    const int NCH = (2 * E + 2047) / 2048;         // 391 edge chunks
    const int ZB  = ((2 * N / 4) + 255) / 256;     // 98 zero-blocks in prep
    const int GX  = (N + 63) / 64;                 // 782 gemm1 blocks per col-half
    const int GROUPS = ((GX * 2 + 7) / 8 > (NCH + 1) / 2) ? (GX * 2 + 7) / 8
                                                          : (NCH + 1) / 2;   // 196

    // ---- 1: fused prep (x split + W splits + cnt zero) ----
    prep_kernel<<<1216 + ZB, 256, 0, stream>>>(x, xhi, xlo, N * F / 4,
                                               W1, w1th, w1tl, W2, w2th, w2tl,
                                               cnt, 2 * N);

    // ---- 2: FUSED+interleaved layer-1 GEMM || bucket build ----
    gemm1_bucket_kernel<<<GROUPS * 24, 256, 0, stream>>>(
        xhi, xlo, w1th, w1tl, h1b, as1, ad1, al_s, al_d, N, HEADS * 64, GX, NCH,
        ei + 17 * (size_t)E, ei + 26 * (size_t)E,
        ei + 15 * (size_t)E, ei + 16 * (size_t)E,
        cnt, csr, N, E);

    // ---- 3: layer-1 aggregation (S=32, bf16 hi out) ----
    gat_agg<256, 32, false><<<(N + 7) / 8, 256, 0, stream>>>(h1b, al_s, al_d, cnt, csr, b1,
                                                             nullptr, o1hi, N);

    // ---- 4: layer-2 MFMA GEMM (bf16 A, 2-pass) -> bf16 h2 ----
    {
        dim3 g((N + 63) / 64, 1);
        mfma_gemm_gat<64, 64, 256, 2, 2, 16, false><<<g, 256, 0, stream>>>(
            o1hi, nullptr, w2th, w2tl, h2b, as2, ad2, al_s, al_d, N, HEADS * 16);
    }
    // ---- 5: layer-2 aggregation (S=8, 16B gathers, f32 out) ----
    gat_agg<64, 8, true><<<(N + 31) / 32, 256, 0, stream>>>(h2b, al_s, al_d, cnt + N,
                                                            csr + (size_t)N * CAP, b2,
                                                            out2, nullptr, N);

    // ---- 6: fused mean-pool + FC ----
    pool_fc_kernel<<<64, 256, 0, stream>>>(out2, batch, Wfc, bfc, out, N);
}